// Round 3
// baseline (1743.004 us; speedup 1.0000x reference)
//
#include <hip/hip_runtime.h>
#include <stdint.h>

#define NN 4096
#define SS 16

// fixed ws float offsets
#define OFF_XYZ1F 0          // 4*3*4096 f32
#define OFF_XYZ2F 49152      // 4*3*4096 f32
#define OFF_N1    98304      // 4*4096 f32
#define OFF_N2    114688     // 4*4096 f32
#define OFF_F2T   131072     // feat2 transpose [b][n][c]: u16 (0.5M f) or f32 (1M f)
// off_p2n / off_idx12 / off_idx11 are host-computed (depend on ws_size)
#define WS_MIN_FLOATS 1966080ull   // compact layout end (proven to fit in round 2)

typedef const uint16_t* u16p;

__device__ __forceinline__ float bf2f(uint16_t u) {
  return __uint_as_float(((uint32_t)u) << 16);
}
__device__ __forceinline__ uint16_t f2bf(float f) {
  uint32_t x = __float_as_uint(f);
  uint32_t r = (x + 0x7FFFu + ((x >> 16) & 1u)) >> 16;
  return (uint16_t)r;
}
// dtype-adaptive input load
__device__ __forceinline__ float ldi(const void* p, int i, int f32m) {
  return f32m ? ((const float*)p)[i] : bf2f(((const uint16_t*)p)[i]);
}
// detect f32 inputs: probe first 128 u16 of feat1 as bf16; f32 data's random
// low-mantissa halves produce |v|>1e4 or NaN with overwhelming probability.
__device__ __forceinline__ int detect_f32(const uint16_t* probe) {
  int lane = threadIdx.x & 63;
  float a = bf2f(probe[lane]);
  float b = bf2f(probe[lane + 64]);
  int bad = (!(fabsf(a) <= 1e4f)) || (!(fabsf(b) <= 1e4f));
  return __any(bad) ? 1 : 0;
}

// ---------------- prep: upconvert xyz, precompute point norms ----------------
__global__ __launch_bounds__(256) void k_prep_xyz(const void* xyz1, const void* xyz2,
                                                  u16p probe, float* ws) {
  int f32m = detect_f32(probe);
  int t = blockIdx.x * 256 + threadIdx.x;   // 0..16383 = b*4096+n
  int b = t >> 12, n = t & (NN - 1);
  int base = b * 3 * NN + n;
  float x1 = ldi(xyz1, base, f32m), y1 = ldi(xyz1, base + NN, f32m), z1 = ldi(xyz1, base + 2 * NN, f32m);
  float x2 = ldi(xyz2, base, f32m), y2 = ldi(xyz2, base + NN, f32m), z2 = ldi(xyz2, base + 2 * NN, f32m);
  float* x1f = ws + OFF_XYZ1F;
  float* x2f = ws + OFF_XYZ2F;
  x1f[base] = x1; x1f[base + NN] = y1; x1f[base + 2 * NN] = z1;
  x2f[base] = x2; x2f[base + NN] = y2; x2f[base + 2 * NN] = z2;
  // exact np order: (x*x + y*y) + z*z, no fma contraction
  ws[OFF_N1 + t] = __fadd_rn(__fadd_rn(__fmul_rn(x1, x1), __fmul_rn(y1, y1)), __fmul_rn(z1, z1));
  ws[OFF_N2 + t] = __fadd_rn(__fadd_rn(__fmul_rn(x2, x2), __fmul_rn(y2, y2)), __fmul_rn(z2, z2));
}

// ---------------- transpose feat2 to point-major ----------------
__global__ __launch_bounds__(256) void k_transpose(const void* feat2, u16p probe,
                                                   float* ws, int f2cap) {
  __shared__ float tile[64][65];
  int f32m = detect_f32(probe);
  int b = blockIdx.x >> 6;
  int n0 = (blockIdx.x & 63) * 64;
  int tx = threadIdx.x & 63, ty = threadIdx.x >> 6;
#pragma unroll
  for (int i = 0; i < 16; ++i) {
    int c = i * 4 + ty;
    tile[c][tx] = ldi(feat2, (b * 64 + c) * NN + n0 + tx, f32m);
  }
  __syncthreads();
#pragma unroll
  for (int i = 0; i < 16; ++i) {
    int nl = i * 4 + ty;
    size_t di = (size_t)(b * NN + n0 + nl) * 64 + tx;
    float v = tile[tx][nl];
    if (f2cap) ((float*)(ws + OFF_F2T))[di] = v;
    else       ((uint16_t*)(ws + OFF_F2T))[di] = f2bf(v);
  }
}

// ---------------- KNN: one thread per query, top-16 by (dist, idx) ----------------
#define CHUNK 2048
__global__ __launch_bounds__(256) void k_knn(float* ws, int off_i12, int off_i11) {
  __shared__ float4 cand[CHUNK];
  __shared__ int needmore;
  int bx = blockIdx.x;
  int which = bx >> 6;          // 0: candidates=xyz2 -> idx12 ; 1: candidates=xyz1 -> idx11
  int r = bx & 63;
  int b = r >> 4;
  int n = (r & 15) * 256 + threadIdx.x;

  const float* cx = ws + (which ? OFF_XYZ1F : OFF_XYZ2F) + b * 3 * NN;
  const float* cn = ws + (which ? OFF_N1 : OFF_N2) + b * NN;
  const float* qp = ws + OFF_XYZ1F + b * 3 * NN;
  float qx = qp[n], qy = qp[NN + n], qz = qp[2 * NN + n];
  float q2 = ws[OFF_N1 + b * NN + n];
  if (threadIdx.x == 0) needmore = 0;

  float bd[16];
#pragma unroll
  for (int t = 0; t < 16; ++t) bd[t] = __builtin_inff();

  // pass A: 16 smallest distance VALUES
  for (int half = 0; half < 2; ++half) {
    int j0 = half * CHUNK;
    __syncthreads();
    for (int j = threadIdx.x; j < CHUNK; j += 256)
      cand[j] = make_float4(cx[j0 + j], cx[NN + j0 + j], cx[2 * NN + j0 + j], cn[j0 + j]);
    __syncthreads();
    for (int j = 0; j < CHUNK; ++j) {
      float4 c = cand[j];
      float cross = __fadd_rn(__fadd_rn(__fmul_rn(qx, c.x), __fmul_rn(qy, c.y)), __fmul_rn(qz, c.z));
      float d = __fsub_rn(__fadd_rn(q2, c.w), __fmul_rn(2.0f, cross));
      if (d < bd[15]) {
        float x = d;
#pragma unroll
        for (int t = 0; t < 16; ++t) {
          float lo = fminf(bd[t], x);
          x = fmaxf(bd[t], x);
          bd[t] = lo;
        }
      }
    }
  }
  float tau = bd[15];

  // pass B: collect set = {d<tau} + first equals by ascending index
  uint16_t* out = (uint16_t*)(ws + (which ? off_i11 : off_i12)) + (size_t)(b * NN + n) * SS;
  int c1 = 0;
  int e0 = -1, e1 = -1, e2 = -1, e3 = -1;
  int m = 0;
  for (int half = 0; half < 2; ++half) {
    int j0 = half * CHUNK;
    __syncthreads();
    for (int j = threadIdx.x; j < CHUNK; j += 256)
      cand[j] = make_float4(cx[j0 + j], cx[NN + j0 + j], cx[2 * NN + j0 + j], cn[j0 + j]);
    __syncthreads();
    for (int j = 0; j < CHUNK; ++j) {
      float4 c = cand[j];
      float cross = __fadd_rn(__fadd_rn(__fmul_rn(qx, c.x), __fmul_rn(qy, c.y)), __fmul_rn(qz, c.z));
      float d = __fsub_rn(__fadd_rn(q2, c.w), __fmul_rn(2.0f, cross));
      int jj = j0 + j;
      if (d < tau) {
        if (c1 < 16) out[c1] = (uint16_t)jj;
        ++c1;
      } else if (d == tau) {
        if (m == 0) e0 = jj; else if (m == 1) e1 = jj; else if (m == 2) e2 = jj; else if (m == 3) e3 = jj;
        ++m;
      }
    }
  }
  if (c1 < 16 && 0 < m) { out[c1] = (uint16_t)e0; ++c1; }
  if (c1 < 16 && 1 < m) { out[c1] = (uint16_t)e1; ++c1; }
  if (c1 < 16 && 2 < m) { out[c1] = (uint16_t)e2; ++c1; }
  if (c1 < 16 && 3 < m) { out[c1] = (uint16_t)e3; ++c1; }
  if (c1 < 16) atomicOr(&needmore, 1);
  __syncthreads();
  if (needmore) {   // >4-way boundary tie, block-uniform fallback
    int seen = 0;
    for (int half = 0; half < 2; ++half) {
      int j0 = half * CHUNK;
      __syncthreads();
      for (int j = threadIdx.x; j < CHUNK; j += 256)
        cand[j] = make_float4(cx[j0 + j], cx[NN + j0 + j], cx[2 * NN + j0 + j], cn[j0 + j]);
      __syncthreads();
      if (c1 < 16) {
        for (int j = 0; j < CHUNK; ++j) {
          float4 c = cand[j];
          float cross = __fadd_rn(__fadd_rn(__fmul_rn(qx, c.x), __fmul_rn(qy, c.y)), __fmul_rn(qz, c.z));
          float d = __fsub_rn(__fadd_rn(q2, c.w), __fmul_rn(2.0f, cross));
          if (d == tau) {
            if (seen >= 4 && c1 < 16) { out[c1] = (uint16_t)(j0 + j); ++c1; }
            ++seen;
          }
        }
      }
    }
  }
}

// ---------------- group1: cross attention, one wave per query ----------------
__global__ __launch_bounds__(256) void k_group1(
    const void* feat1, const void* w_q1, const void* w_k1, const void* w_v1,
    const void* w_mlp1, const void* w_mlp2, const void* w_pos1, const void* b_pos1,
    u16p probe, float* ws, int off_p2n, int off_i12, int f2cap) {
  __shared__ float s_A[64 * 64];       // phased: w_q1 -> w_v1[:, :64] -> w_k1 (all [c][o])
  __shared__ float s_wv1b[64 * 64];    // w_v1[:,64+c] -> [c][o]
  __shared__ float s_wv1x[3 * 64];
  __shared__ float s_wp1[5 * 64];
  __shared__ float s_bp1[64];
  __shared__ float s_wm1[64 * 16];     // [c][h]
  __shared__ float s_wm2[16];
  __shared__ float f1s[4][64];
  __shared__ float nbs[4][64];
  __shared__ float xs[4][64];
  __shared__ float xds[4][64];         // per s: dx,dy,dz,norm
  __shared__ float attns[4][16];
  __shared__ int idxs[4][16];

  int f32m = detect_f32(probe);
  int tid = threadIdx.x;
  for (int i = tid; i < 64 * 64; i += 256) {
    int c = i >> 6, o = i & 63;
    s_A[i] = ldi(w_q1, o * 64 + c, f32m);
    s_wv1b[i] = ldi(w_v1, o * 131 + 64 + c, f32m);
  }
  for (int i = tid; i < 64 * 16; i += 256) {
    int c = i >> 4, h = i & 15;
    s_wm1[i] = ldi(w_mlp1, h * 64 + c, f32m);
  }
  if (tid < 192) { int j = tid >> 6, o = tid & 63; s_wv1x[tid] = ldi(w_v1, o * 131 + 128 + j, f32m); }
  for (int i = tid; i < 320; i += 256) { int p = i >> 6, o = i & 63; s_wp1[i] = ldi(w_pos1, o * 5 + p, f32m); }
  if (tid < 64) s_bp1[tid] = ldi(b_pos1, tid, f32m);
  if (tid < 16) s_wm2[tid] = ldi(w_mlp2, tid, f32m);

  int w = tid >> 6, o = tid & 63;
  int g = blockIdx.x * 4 + w;
  int b = g >> 12, n = g & (NN - 1);
  const float* x1f = ws + OFF_XYZ1F + b * 3 * NN;
  const float* x2f = ws + OFF_XYZ2F + b * 3 * NN;
  const uint16_t* idx12 = (const uint16_t*)(ws + off_i12) + (size_t)(b * NN + n) * SS;

  float f1o = ldi(feat1, (b * 64 + o) * NN + n, f32m);   // own feature, channel o
  f1s[w][o] = f1o;
  float qx = x1f[n], qy = x1f[NN + n], qz = x1f[2 * NN + n];
  if (o < 16) {
    int j = (int)idx12[o];
    idxs[w][o] = j;
    float dx = __fsub_rn(qx, x2f[j]);
    float dy = __fsub_rn(qy, x2f[NN + j]);
    float dz = __fsub_rn(qz, x2f[2 * NN + j]);
    xds[w][o * 4 + 0] = dx; xds[w][o * 4 + 1] = dy; xds[w][o * 4 + 2] = dz;
    xds[w][o * 4 + 3] = sqrtf(dx * dx + dy * dy + dz * dz);
  }
  __syncthreads();

  // phase 1: q = w_q1 . f1
  float q = 0.f;
#pragma unroll
  for (int c = 0; c < 64; ++c) q = fmaf(s_A[c * 64 + o], f1s[w][c], q);
  __syncthreads();
  // phase 2: restage A = w_v1[:, :64], vb = . f1
  for (int i = tid; i < 64 * 64; i += 256) {
    int c = i >> 6, oo = i & 63;
    s_A[i] = ldi(w_v1, oo * 131 + c, f32m);
  }
  __syncthreads();
  float vb = 0.f;
#pragma unroll
  for (int c = 0; c < 64; ++c) vb = fmaf(s_A[c * 64 + o], f1s[w][c], vb);
  __syncthreads();
  // phase 3: restage A = w_k1 (resident for s-loop)
  for (int i = tid; i < 64 * 64; i += 256) {
    int c = i >> 6, oo = i & 63;
    s_A[i] = ldi(w_k1, oo * 64 + c, f32m);
  }
  __syncthreads();

  float vreg[16];
#pragma unroll 1
  for (int s = 0; s < SS; ++s) {
    int j = idxs[w][s];
    size_t fi = (size_t)(b * NN + j) * 64 + o;
    float nb = f2cap ? ((const float*)(ws + OFF_F2T))[fi]
                     : bf2f(((const uint16_t*)(ws + OFF_F2T))[fi]);
    nbs[w][o] = nb;
    float df = __fsub_rn(f1o, nb);
    float ssq = df * df;
#pragma unroll
    for (int msk = 1; msk < 64; msk <<= 1) ssq += __shfl_xor(ssq, msk);
    float fn = sqrtf(ssq);
    float dx = xds[w][s * 4 + 0], dy = xds[w][s * 4 + 1], dz = xds[w][s * 4 + 2], xn = xds[w][s * 4 + 3];
    __syncthreads();
    float v = vb;
#pragma unroll
    for (int c = 0; c < 64; ++c) v = fmaf(s_wv1b[c * 64 + o], nbs[w][c], v);
    v = fmaf(s_wv1x[o], dx, v);
    v = fmaf(s_wv1x[64 + o], dy, v);
    v = fmaf(s_wv1x[128 + o], dz, v);
    float pe = s_bp1[o];
    pe = fmaf(s_wp1[o], fn, pe);
    pe = fmaf(s_wp1[64 + o], xn, pe);
    pe = fmaf(s_wp1[128 + o], dx, pe);
    pe = fmaf(s_wp1[192 + o], dy, pe);
    pe = fmaf(s_wp1[256 + o], dz, pe);
    xs[w][o] = v + pe;
    __syncthreads();
    float kk = 0.f;
#pragma unroll
    for (int c = 0; c < 64; ++c) kk = fmaf(s_A[c * 64 + o], xs[w][c], kk);
    float qk = q - kk;
    __syncthreads();
    xs[w][o] = qk;
    __syncthreads();
    int h = o & 15, part = o >> 4;
    float hs = 0.f;
#pragma unroll
    for (int i = 0; i < 16; ++i) {
      int c = part * 16 + i;
      hs = fmaf(s_wm1[c * 16 + h], xs[w][c], hs);
    }
    hs += __shfl_xor(hs, 16);
    hs += __shfl_xor(hs, 32);
    float att = fmaxf(hs, 0.f) * s_wm2[h];
    att += __shfl_xor(att, 1);
    att += __shfl_xor(att, 2);
    att += __shfl_xor(att, 4);
    att += __shfl_xor(att, 8);
    if (o == 0) attns[w][s] = att;
    vreg[s] = v;
    __syncthreads();
  }
  {
    float a = attns[w][o & 15];
    float mx = a;
    mx = fmaxf(mx, __shfl_xor(mx, 1));
    mx = fmaxf(mx, __shfl_xor(mx, 2));
    mx = fmaxf(mx, __shfl_xor(mx, 4));
    mx = fmaxf(mx, __shfl_xor(mx, 8));
    float e = __expf(a - mx);
    float ssum = e;
    ssum += __shfl_xor(ssum, 1);
    ssum += __shfl_xor(ssum, 2);
    ssum += __shfl_xor(ssum, 4);
    ssum += __shfl_xor(ssum, 8);
    if (o < 16) attns[w][o] = e / ssum;
  }
  __syncthreads();
  float acc = 0.f;
#pragma unroll
  for (int s = 0; s < SS; ++s) acc = fmaf(attns[w][s], vreg[s], acc);
  float res = acc >= 0.f ? acc : 0.1f * acc;   // leaky_relu 0.1
  ws[off_p2n + (size_t)(b * NN + n) * 64 + o] = res;
}

// ---------------- group2: self attention, one wave per query ----------------
__global__ __launch_bounds__(256) void k_group2(
    const void* w_q2, const void* w_k2, const void* w_v2, const void* w_pos2, const void* b_pos2,
    u16p probe, float* ws, void* outp, int off_p2n, int off_i11) {
  __shared__ float s_wk2[64 * 64];
  __shared__ float s_wv2[64 * 64];
  __shared__ float s_wq2[64 * 64];
  __shared__ float s_wp2[4 * 64];
  __shared__ float s_bp2[64];
  __shared__ float f1s[4][64];
  __shared__ float nbs[4][64];
  __shared__ float xs[4][64];
  __shared__ float xds[4][64];
  __shared__ float attns[4][16];
  __shared__ int idxs[4][16];
  __shared__ float souts[4][64];

  int f32m = detect_f32(probe);
  int tid = threadIdx.x;
  for (int i = tid; i < 64 * 64; i += 256) {
    int c = i >> 6, o = i & 63;
    s_wk2[i] = ldi(w_k2, o * 64 + c, f32m);
    s_wv2[i] = ldi(w_v2, o * 64 + c, f32m);
    s_wq2[i] = ldi(w_q2, o * 64 + c, f32m);
  }
  { int p = tid >> 6, o = tid & 63; s_wp2[tid] = ldi(w_pos2, o * 4 + p, f32m); }
  if (tid < 64) s_bp2[tid] = ldi(b_pos2, tid, f32m);

  int w = tid >> 6, o = tid & 63;
  int g = blockIdx.x * 4 + w;
  int b = g >> 12, n = g & (NN - 1);
  const float* p2t = ws + off_p2n;
  const float* x1f = ws + OFF_XYZ1F + b * 3 * NN;
  const uint16_t* idx11 = (const uint16_t*)(ws + off_i11) + (size_t)(b * NN + n) * SS;

  float p1o = p2t[(size_t)(b * NN + n) * 64 + o];
  f1s[w][o] = p1o;
  float qx = x1f[n], qy = x1f[NN + n], qz = x1f[2 * NN + n];
  if (o < 16) {
    int j = (int)idx11[o];
    idxs[w][o] = j;
    float dx = __fsub_rn(qx, x1f[j]);
    float dy = __fsub_rn(qy, x1f[NN + j]);
    float dz = __fsub_rn(qz, x1f[2 * NN + j]);
    xds[w][o * 4 + 0] = dx; xds[w][o * 4 + 1] = dy; xds[w][o * 4 + 2] = dz;
    xds[w][o * 4 + 3] = sqrtf(dx * dx + dy * dy + dz * dz);
  }
  __syncthreads();

  float q = 0.f;
#pragma unroll
  for (int c = 0; c < 64; ++c) q = fmaf(s_wq2[c * 64 + o], f1s[w][c], q);
  float qs = q * 0.125f;    // 64^-0.5 exact

  float vreg[16];
#pragma unroll 1
  for (int s = 0; s < SS; ++s) {
    int j = idxs[w][s];
    float nb = p2t[(size_t)(b * NN + j) * 64 + o];
    nbs[w][o] = nb;
    float dx = xds[w][s * 4 + 0], dy = xds[w][s * 4 + 1], dz = xds[w][s * 4 + 2], xn = xds[w][s * 4 + 3];
    float pe = s_bp2[o];                 // pos order: dx,dy,dz,norm
    pe = fmaf(s_wp2[o], dx, pe);
    pe = fmaf(s_wp2[64 + o], dy, pe);
    pe = fmaf(s_wp2[128 + o], dz, pe);
    pe = fmaf(s_wp2[192 + o], xn, pe);
    xs[w][o] = nb + pe;
    __syncthreads();
    float kk = 0.f, vv = 0.f;
#pragma unroll
    for (int c = 0; c < 64; ++c) {
      kk = fmaf(s_wk2[c * 64 + o], xs[w][c], kk);
      vv = fmaf(s_wv2[c * 64 + o], nbs[w][c], vv);
    }
    float t = qs * kk;
#pragma unroll
    for (int msk = 1; msk < 64; msk <<= 1) t += __shfl_xor(t, msk);
    if (o == 0) attns[w][s] = t;
    vreg[s] = vv;
    __syncthreads();
  }
  {
    float a = attns[w][o & 15];
    float mx = a;
    mx = fmaxf(mx, __shfl_xor(mx, 1));
    mx = fmaxf(mx, __shfl_xor(mx, 2));
    mx = fmaxf(mx, __shfl_xor(mx, 4));
    mx = fmaxf(mx, __shfl_xor(mx, 8));
    float e = __expf(a - mx);
    float ssum = e;
    ssum += __shfl_xor(ssum, 1);
    ssum += __shfl_xor(ssum, 2);
    ssum += __shfl_xor(ssum, 4);
    ssum += __shfl_xor(ssum, 8);
    if (o < 16) attns[w][o] = e / ssum;
  }
  __syncthreads();
  float acc = 0.f;
#pragma unroll
  for (int s = 0; s < SS; ++s) acc = fmaf(attns[w][s], vreg[s], acc);
  float res = acc >= 0.f ? acc : 0.1f * acc;
  souts[w][o] = res;
  __syncthreads();
  // staged transposed write: out[b][c][n]
  int c = tid >> 2, nr = tid & 3;
  int n0 = (blockIdx.x * 4) & (NN - 1);
  int b0 = (blockIdx.x * 4) >> 12;
  size_t oi = (size_t)(b0 * 64 + c) * NN + n0 + nr;
  float ov = souts[nr][c];
  if (f32m) ((float*)outp)[oi] = ov;
  else      ((uint16_t*)outp)[oi] = f2bf(ov);
}

extern "C" void kernel_launch(void* const* d_in, const int* in_sizes, int n_in,
                              void* d_out, int out_size, void* d_ws, size_t ws_size,
                              hipStream_t stream) {
  const void* xyz1 = d_in[0];
  const void* feat1 = d_in[1];
  const void* xyz2 = d_in[2];
  const void* feat2 = d_in[3];
  const void* w_q1 = d_in[4];
  const void* w_k1 = d_in[5];
  const void* w_v1 = d_in[6];
  const void* w_mlp1 = d_in[7];
  const void* w_mlp2 = d_in[8];
  const void* w_pos1 = d_in[9];
  const void* b_pos1 = d_in[10];
  const void* w_q2 = d_in[11];
  const void* w_k2 = d_in[12];
  const void* w_v2 = d_in[13];
  const void* w_pos2 = d_in[14];
  const void* b_pos2 = d_in[15];
  u16p probe = (u16p)d_in[1];   // feat1 bytes, used for dtype detection
  float* ws = (float*)d_ws;

  if (ws_size < WS_MIN_FLOATS * 4ull) return;  // proven false in round 2

  // layout select (launch-constant): big layout stores feat2-transpose as f32
  int big = (ws_size >= 2490368ull * 4ull) ? 1 : 0;
  int f2cap   = big;
  int off_p2n = big ? 1179648 : 655360;
  int off_i12 = big ? 2228224 : 1703936;
  int off_i11 = big ? 2359296 : 1835008;

  hipLaunchKernelGGL(k_prep_xyz, dim3(64), dim3(256), 0, stream, xyz1, xyz2, probe, ws);
  hipLaunchKernelGGL(k_transpose, dim3(256), dim3(256), 0, stream, feat2, probe, ws, f2cap);
  hipLaunchKernelGGL(k_knn, dim3(128), dim3(256), 0, stream, ws, off_i12, off_i11);
  hipLaunchKernelGGL(k_group1, dim3(4096), dim3(256), 0, stream,
                     feat1, w_q1, w_k1, w_v1, w_mlp1, w_mlp2, w_pos1, b_pos1,
                     probe, ws, off_p2n, off_i12, f2cap);
  hipLaunchKernelGGL(k_group2, dim3(4096), dim3(256), 0, stream,
                     w_q2, w_k2, w_v2, w_pos2, b_pos2,
                     probe, ws, d_out, off_p2n, off_i11);
}

// Round 4
// 966.293 us; speedup vs baseline: 1.8038x; 1.8038x over previous
//
#include <hip/hip_runtime.h>
#include <stdint.h>

#define NN 4096
#define SS 16

// fixed ws float offsets
#define OFF_XYZ1F 0          // 4*3*4096 f32
#define OFF_XYZ2F 49152      // 4*3*4096 f32
#define OFF_N1    98304      // 4*4096 f32
#define OFF_N2    114688     // 4*4096 f32
#define OFF_F2T   131072     // feat2 transpose [b][n][c]: u16 (0.5M f) or f32 (1M f)
#define WS_MIN_FLOATS 1966080ull

typedef const uint16_t* u16p;

__device__ __forceinline__ float bf2f(uint16_t u) {
  return __uint_as_float(((uint32_t)u) << 16);
}
__device__ __forceinline__ uint16_t f2bf(float f) {
  uint32_t x = __float_as_uint(f);
  uint32_t r = (x + 0x7FFFu + ((x >> 16) & 1u)) >> 16;
  return (uint16_t)r;
}
__device__ __forceinline__ float ldi(const void* p, int i, int f32m) {
  return f32m ? ((const float*)p)[i] : bf2f(((const uint16_t*)p)[i]);
}
__device__ __forceinline__ int detect_f32(const uint16_t* probe) {
  int lane = threadIdx.x & 63;
  float a = bf2f(probe[lane]);
  float b = bf2f(probe[lane + 64]);
  int bad = (!(fabsf(a) <= 1e4f)) || (!(fabsf(b) <= 1e4f));
  return __any(bad) ? 1 : 0;
}
__device__ __forceinline__ void wbar() { __builtin_amdgcn_wave_barrier(); }

// ---------------- prep: upconvert xyz, precompute point norms ----------------
__global__ __launch_bounds__(256) void k_prep_xyz(const void* xyz1, const void* xyz2,
                                                  u16p probe, float* ws) {
  int f32m = detect_f32(probe);
  int t = blockIdx.x * 256 + threadIdx.x;
  int b = t >> 12, n = t & (NN - 1);
  int base = b * 3 * NN + n;
  float x1 = ldi(xyz1, base, f32m), y1 = ldi(xyz1, base + NN, f32m), z1 = ldi(xyz1, base + 2 * NN, f32m);
  float x2 = ldi(xyz2, base, f32m), y2 = ldi(xyz2, base + NN, f32m), z2 = ldi(xyz2, base + 2 * NN, f32m);
  float* x1f = ws + OFF_XYZ1F;
  float* x2f = ws + OFF_XYZ2F;
  x1f[base] = x1; x1f[base + NN] = y1; x1f[base + 2 * NN] = z1;
  x2f[base] = x2; x2f[base + NN] = y2; x2f[base + 2 * NN] = z2;
  ws[OFF_N1 + t] = __fadd_rn(__fadd_rn(__fmul_rn(x1, x1), __fmul_rn(y1, y1)), __fmul_rn(z1, z1));
  ws[OFF_N2 + t] = __fadd_rn(__fadd_rn(__fmul_rn(x2, x2), __fmul_rn(y2, y2)), __fmul_rn(z2, z2));
}

// ---------------- transpose feat2 to point-major ----------------
__global__ __launch_bounds__(256) void k_transpose(const void* feat2, u16p probe,
                                                   float* ws, int f2cap) {
  __shared__ float tile[64][65];
  int f32m = detect_f32(probe);
  int b = blockIdx.x >> 6;
  int n0 = (blockIdx.x & 63) * 64;
  int tx = threadIdx.x & 63, ty = threadIdx.x >> 6;
#pragma unroll
  for (int i = 0; i < 16; ++i) {
    int c = i * 4 + ty;
    tile[c][tx] = ldi(feat2, (b * 64 + c) * NN + n0 + tx, f32m);
  }
  __syncthreads();
#pragma unroll
  for (int i = 0; i < 16; ++i) {
    int nl = i * 4 + ty;
    size_t di = (size_t)(b * NN + n0 + nl) * 64 + tx;
    float v = tile[tx][nl];
    if (f2cap) ((float*)(ws + OFF_F2T))[di] = v;
    else       ((uint16_t*)(ws + OFF_F2T))[di] = f2bf(v);
  }
}

// ---------------- KNN: one WAVE per query ----------------
// 512-thr blocks = 8 waves = 8 queries; candidates staged in 2x 32KB LDS chunks.
// Lane l scans j = i*64+l (64 cands/lane): per-lane sorted top-16 VALUE chain,
// wave pop-merge -> tau (exact multiset 16th), ballot-compaction pass B.
#define KCHUNK 2048
__global__ __launch_bounds__(512) void k_knn(float* ws, int off_i12, int off_i11) {
  __shared__ float4 cand[KCHUNK];
  __shared__ int eqbuf[8][16];

  int tid = threadIdx.x;
  int wv = tid >> 6, lane = tid & 63;
  int q = blockIdx.x * 8 + wv;            // 0..32767; all waves of a block share (which,b)
  int which = q >> 14;
  int b = (q >> 12) & 3;
  int n = q & (NN - 1);

  const float* cx = ws + (which ? OFF_XYZ1F : OFF_XYZ2F) + b * 3 * NN;
  const float* cn = ws + (which ? OFF_N1 : OFF_N2) + b * NN;
  const float* qp = ws + OFF_XYZ1F + b * 3 * NN;
  float qx = qp[n], qy = qp[NN + n], qz = qp[2 * NN + n];
  float q2 = ws[OFF_N1 + b * NN + n];

  float bd[16];
#pragma unroll
  for (int t = 0; t < 16; ++t) bd[t] = __builtin_inff();

  // ---- pass A: per-lane top-16 values over strided subset ----
  for (int half = 0; half < 2; ++half) {
    int j0 = half * KCHUNK;
    __syncthreads();
    for (int j = tid; j < KCHUNK; j += 512)
      cand[j] = make_float4(cx[j0 + j], cx[NN + j0 + j], cx[2 * NN + j0 + j], cn[j0 + j]);
    __syncthreads();
#pragma unroll 2
    for (int i = 0; i < KCHUNK / 64; ++i) {
      float4 c = cand[i * 64 + lane];
      float cross = __fadd_rn(__fadd_rn(__fmul_rn(qx, c.x), __fmul_rn(qy, c.y)), __fmul_rn(qz, c.z));
      float d = __fsub_rn(__fadd_rn(q2, c.w), __fmul_rn(2.0f, cross));
      if (d < bd[15]) {
        float x = d;
#pragma unroll
        for (int t = 0; t < 16; ++t) {
          float lo = fminf(bd[t], x);
          x = fmaxf(bd[t], x);
          bd[t] = lo;
        }
      }
    }
  }

  // ---- wave pop-merge: 16 rounds of min-of-heads; tau = 16th popped ----
  float tau = 0.f;
  float h = bd[0];
#pragma unroll 1
  for (int r = 0; r < 16; ++r) {
    float m = h;
#pragma unroll
    for (int msk = 1; msk < 64; msk <<= 1) m = fminf(m, __shfl_xor(m, msk));
    unsigned long long win = __ballot(h == m);
    int winner = __ffsll(win) - 1;
    if (r == 15) tau = m;
    if (lane == winner) {
#pragma unroll
      for (int t = 0; t < 15; ++t) bd[t] = bd[t + 1];
      bd[15] = __builtin_inff();
      h = bd[0];
    }
  }

  // ---- pass B: collect {d<tau} (ballot compaction) + earliest equals ----
  uint16_t* outp = (uint16_t*)(ws + (which ? off_i11 : off_i12)) + (size_t)(b * NN + n) * SS;
  unsigned long long below = (1ull << lane) - 1ull;
  int c1 = 0, eqc = 0;
  for (int half = 0; half < 2; ++half) {
    int j0 = half * KCHUNK;
    __syncthreads();
    for (int j = tid; j < KCHUNK; j += 512)
      cand[j] = make_float4(cx[j0 + j], cx[NN + j0 + j], cx[2 * NN + j0 + j], cn[j0 + j]);
    __syncthreads();
    for (int i = 0; i < KCHUNK / 64; ++i) {
      int jj = j0 + i * 64 + lane;
      float4 c = cand[i * 64 + lane];
      float cross = __fadd_rn(__fadd_rn(__fmul_rn(qx, c.x), __fmul_rn(qy, c.y)), __fmul_rn(qz, c.z));
      float d = __fsub_rn(__fadd_rn(q2, c.w), __fmul_rn(2.0f, cross));
      bool lt = (d < tau), eq = (d == tau);
      unsigned long long mlt = __ballot(lt);
      unsigned long long meq = __ballot(eq);
      int pl = __popcll(mlt & below);
      if (lt && (c1 + pl) < 16) outp[c1 + pl] = (uint16_t)jj;   // #<tau <= 15 always
      int pe = __popcll(meq & below);
      if (eq && (eqc + pe) < 16) eqbuf[wv][eqc + pe] = jj;      // ascending-j order
      c1 += __popcll(mlt);
      eqc += __popcll(meq);
    }
  }
  wbar();
  int need = 16 - c1;        // >=0; equals count >= need by definition of tau
  if (lane < need) outp[c1 + lane] = (uint16_t)eqbuf[wv][lane];
}

// ---------------- group1: cross attention, one wave per query ----------------
__global__ __launch_bounds__(256) void k_group1(
    const void* feat1, const void* w_q1, const void* w_k1, const void* w_v1,
    const void* w_mlp1, const void* w_mlp2, const void* w_pos1, const void* b_pos1,
    u16p probe, float* ws, int off_p2n, int off_i12, int f2cap) {
  __shared__ float s_A[64 * 64];       // phased: w_q1 -> w_v1[:, :64] -> w_k1 (all [c][o])
  __shared__ float s_wv1b[64 * 64];    // w_v1[:,64+c] -> [c][o]
  __shared__ float s_wv1x[3 * 64];
  __shared__ float s_wp1[5 * 64];
  __shared__ float s_bp1[64];
  __shared__ float s_wm1[64 * 16];     // [c][h]
  __shared__ float s_wm2[16];
  __shared__ float f1s[4][64];
  __shared__ float nbs[4][64];
  __shared__ float xs[4][64];
  __shared__ float xds[4][64];         // per s: dx,dy,dz,norm
  __shared__ float attns[4][16];
  __shared__ int idxs[4][16];

  int f32m = detect_f32(probe);
  int tid = threadIdx.x;
  for (int i = tid; i < 64 * 64; i += 256) {
    int c = i >> 6, o = i & 63;
    s_A[i] = ldi(w_q1, o * 64 + c, f32m);
    s_wv1b[i] = ldi(w_v1, o * 131 + 64 + c, f32m);
  }
  for (int i = tid; i < 64 * 16; i += 256) {
    int c = i >> 4, h = i & 15;
    s_wm1[i] = ldi(w_mlp1, h * 64 + c, f32m);
  }
  if (tid < 192) { int j = tid >> 6, o = tid & 63; s_wv1x[tid] = ldi(w_v1, o * 131 + 128 + j, f32m); }
  for (int i = tid; i < 320; i += 256) { int p = i >> 6, o = i & 63; s_wp1[i] = ldi(w_pos1, o * 5 + p, f32m); }
  if (tid < 64) s_bp1[tid] = ldi(b_pos1, tid, f32m);
  if (tid < 16) s_wm2[tid] = ldi(w_mlp2, tid, f32m);

  int w = tid >> 6, o = tid & 63;
  int g = blockIdx.x * 4 + w;
  int b = g >> 12, n = g & (NN - 1);
  const float* x1f = ws + OFF_XYZ1F + b * 3 * NN;
  const float* x2f = ws + OFF_XYZ2F + b * 3 * NN;
  const uint16_t* idx12 = (const uint16_t*)(ws + off_i12) + (size_t)(b * NN + n) * SS;

  float f1o = ldi(feat1, (b * 64 + o) * NN + n, f32m);
  f1s[w][o] = f1o;
  float qx = x1f[n], qy = x1f[NN + n], qz = x1f[2 * NN + n];
  if (o < 16) {
    int j = (int)idx12[o];
    idxs[w][o] = j;
    float dx = __fsub_rn(qx, x2f[j]);
    float dy = __fsub_rn(qy, x2f[NN + j]);
    float dz = __fsub_rn(qz, x2f[2 * NN + j]);
    xds[w][o * 4 + 0] = dx; xds[w][o * 4 + 1] = dy; xds[w][o * 4 + 2] = dz;
    xds[w][o * 4 + 3] = sqrtf(dx * dx + dy * dy + dz * dz);
  }
  __syncthreads();

  // phase 1: q = w_q1 . f1
  float q = 0.f;
#pragma unroll
  for (int c = 0; c < 64; ++c) q = fmaf(s_A[c * 64 + o], f1s[w][c], q);
  __syncthreads();
  // phase 2: restage A = w_v1[:, :64], vb = . f1
  for (int i = tid; i < 64 * 64; i += 256) {
    int c = i >> 6, oo = i & 63;
    s_A[i] = ldi(w_v1, oo * 131 + c, f32m);
  }
  __syncthreads();
  float vb = 0.f;
#pragma unroll
  for (int c = 0; c < 64; ++c) vb = fmaf(s_A[c * 64 + o], f1s[w][c], vb);
  __syncthreads();
  // phase 3: restage A = w_k1 (resident for s-loop)
  for (int i = tid; i < 64 * 64; i += 256) {
    int c = i >> 6, oo = i & 63;
    s_A[i] = ldi(w_k1, oo * 64 + c, f32m);
  }
  __syncthreads();

  // s-loop touches only [w]-indexed (wave-private) LDS + read-only weights:
  // DS ops are in-order per wave -> wave_barrier (compiler pin) suffices.
  float vreg[16];
#pragma unroll 1
  for (int s = 0; s < SS; ++s) {
    int j = idxs[w][s];
    size_t fi = (size_t)(b * NN + j) * 64 + o;
    float nb = f2cap ? ((const float*)(ws + OFF_F2T))[fi]
                     : bf2f(((const uint16_t*)(ws + OFF_F2T))[fi]);
    nbs[w][o] = nb;
    float df = __fsub_rn(f1o, nb);
    float ssq = df * df;
#pragma unroll
    for (int msk = 1; msk < 64; msk <<= 1) ssq += __shfl_xor(ssq, msk);
    float fn = sqrtf(ssq);
    float dx = xds[w][s * 4 + 0], dy = xds[w][s * 4 + 1], dz = xds[w][s * 4 + 2], xn = xds[w][s * 4 + 3];
    wbar();
    float v = vb;
#pragma unroll
    for (int c = 0; c < 64; ++c) v = fmaf(s_wv1b[c * 64 + o], nbs[w][c], v);
    v = fmaf(s_wv1x[o], dx, v);
    v = fmaf(s_wv1x[64 + o], dy, v);
    v = fmaf(s_wv1x[128 + o], dz, v);
    float pe = s_bp1[o];
    pe = fmaf(s_wp1[o], fn, pe);
    pe = fmaf(s_wp1[64 + o], xn, pe);
    pe = fmaf(s_wp1[128 + o], dx, pe);
    pe = fmaf(s_wp1[192 + o], dy, pe);
    pe = fmaf(s_wp1[256 + o], dz, pe);
    xs[w][o] = v + pe;
    wbar();
    float kk = 0.f;
#pragma unroll
    for (int c = 0; c < 64; ++c) kk = fmaf(s_A[c * 64 + o], xs[w][c], kk);
    float qk = q - kk;
    wbar();
    xs[w][o] = qk;
    wbar();
    int h = o & 15, part = o >> 4;
    float hs = 0.f;
#pragma unroll
    for (int i = 0; i < 16; ++i) {
      int c = part * 16 + i;
      hs = fmaf(s_wm1[c * 16 + h], xs[w][c], hs);
    }
    hs += __shfl_xor(hs, 16);
    hs += __shfl_xor(hs, 32);
    float att = fmaxf(hs, 0.f) * s_wm2[h];
    att += __shfl_xor(att, 1);
    att += __shfl_xor(att, 2);
    att += __shfl_xor(att, 4);
    att += __shfl_xor(att, 8);
    if (o == 0) attns[w][s] = att;
    vreg[s] = v;
    wbar();
  }
  {
    float a = attns[w][o & 15];
    float mx = a;
    mx = fmaxf(mx, __shfl_xor(mx, 1));
    mx = fmaxf(mx, __shfl_xor(mx, 2));
    mx = fmaxf(mx, __shfl_xor(mx, 4));
    mx = fmaxf(mx, __shfl_xor(mx, 8));
    float e = __expf(a - mx);
    float ssum = e;
    ssum += __shfl_xor(ssum, 1);
    ssum += __shfl_xor(ssum, 2);
    ssum += __shfl_xor(ssum, 4);
    ssum += __shfl_xor(ssum, 8);
    if (o < 16) attns[w][o] = e / ssum;
  }
  wbar();
  float acc = 0.f;
#pragma unroll
  for (int s = 0; s < SS; ++s) acc = fmaf(attns[w][s], vreg[s], acc);
  float res = acc >= 0.f ? acc : 0.1f * acc;   // leaky_relu 0.1
  ws[off_p2n + (size_t)(b * NN + n) * 64 + o] = res;
}

// ---------------- group2: self attention, one wave per query ----------------
__global__ __launch_bounds__(256) void k_group2(
    const void* w_q2, const void* w_k2, const void* w_v2, const void* w_pos2, const void* b_pos2,
    u16p probe, float* ws, void* outp, int off_p2n, int off_i11) {
  __shared__ float s_wk2[64 * 64];
  __shared__ float s_wv2[64 * 64];
  __shared__ float s_wq2[64 * 64];
  __shared__ float s_wp2[4 * 64];
  __shared__ float s_bp2[64];
  __shared__ float f1s[4][64];
  __shared__ float nbs[4][64];
  __shared__ float xs[4][64];
  __shared__ float xds[4][64];
  __shared__ float attns[4][16];
  __shared__ int idxs[4][16];
  __shared__ float souts[4][64];

  int f32m = detect_f32(probe);
  int tid = threadIdx.x;
  for (int i = tid; i < 64 * 64; i += 256) {
    int c = i >> 6, o = i & 63;
    s_wk2[i] = ldi(w_k2, o * 64 + c, f32m);
    s_wv2[i] = ldi(w_v2, o * 64 + c, f32m);
    s_wq2[i] = ldi(w_q2, o * 64 + c, f32m);
  }
  { int p = tid >> 6, o = tid & 63; s_wp2[tid] = ldi(w_pos2, o * 4 + p, f32m); }
  if (tid < 64) s_bp2[tid] = ldi(b_pos2, tid, f32m);

  int w = tid >> 6, o = tid & 63;
  int g = blockIdx.x * 4 + w;
  int b = g >> 12, n = g & (NN - 1);
  const float* p2t = ws + off_p2n;
  const float* x1f = ws + OFF_XYZ1F + b * 3 * NN;
  const uint16_t* idx11 = (const uint16_t*)(ws + off_i11) + (size_t)(b * NN + n) * SS;

  float p1o = p2t[(size_t)(b * NN + n) * 64 + o];
  f1s[w][o] = p1o;
  float qx = x1f[n], qy = x1f[NN + n], qz = x1f[2 * NN + n];
  if (o < 16) {
    int j = (int)idx11[o];
    idxs[w][o] = j;
    float dx = __fsub_rn(qx, x1f[j]);
    float dy = __fsub_rn(qy, x1f[NN + j]);
    float dz = __fsub_rn(qz, x1f[2 * NN + j]);
    xds[w][o * 4 + 0] = dx; xds[w][o * 4 + 1] = dy; xds[w][o * 4 + 2] = dz;
    xds[w][o * 4 + 3] = sqrtf(dx * dx + dy * dy + dz * dz);
  }
  __syncthreads();

  float q = 0.f;
#pragma unroll
  for (int c = 0; c < 64; ++c) q = fmaf(s_wq2[c * 64 + o], f1s[w][c], q);
  float qs = q * 0.125f;

  float vreg[16];
#pragma unroll 1
  for (int s = 0; s < SS; ++s) {
    int j = idxs[w][s];
    float nb = p2t[(size_t)(b * NN + j) * 64 + o];
    nbs[w][o] = nb;
    float dx = xds[w][s * 4 + 0], dy = xds[w][s * 4 + 1], dz = xds[w][s * 4 + 2], xn = xds[w][s * 4 + 3];
    float pe = s_bp2[o];
    pe = fmaf(s_wp2[o], dx, pe);
    pe = fmaf(s_wp2[64 + o], dy, pe);
    pe = fmaf(s_wp2[128 + o], dz, pe);
    pe = fmaf(s_wp2[192 + o], xn, pe);
    xs[w][o] = nb + pe;
    wbar();
    float kk = 0.f, vv = 0.f;
#pragma unroll
    for (int c = 0; c < 64; ++c) {
      kk = fmaf(s_wk2[c * 64 + o], xs[w][c], kk);
      vv = fmaf(s_wv2[c * 64 + o], nbs[w][c], vv);
    }
    float t = qs * kk;
#pragma unroll
    for (int msk = 1; msk < 64; msk <<= 1) t += __shfl_xor(t, msk);
    if (o == 0) attns[w][s] = t;
    vreg[s] = vv;
    wbar();
  }
  {
    float a = attns[w][o & 15];
    float mx = a;
    mx = fmaxf(mx, __shfl_xor(mx, 1));
    mx = fmaxf(mx, __shfl_xor(mx, 2));
    mx = fmaxf(mx, __shfl_xor(mx, 4));
    mx = fmaxf(mx, __shfl_xor(mx, 8));
    float e = __expf(a - mx);
    float ssum = e;
    ssum += __shfl_xor(ssum, 1);
    ssum += __shfl_xor(ssum, 2);
    ssum += __shfl_xor(ssum, 4);
    ssum += __shfl_xor(ssum, 8);
    if (o < 16) attns[w][o] = e / ssum;
  }
  wbar();
  float acc = 0.f;
#pragma unroll
  for (int s = 0; s < SS; ++s) acc = fmaf(attns[w][s], vreg[s], acc);
  float res = acc >= 0.f ? acc : 0.1f * acc;
  souts[w][o] = res;
  __syncthreads();   // cross-wave transpose staging
  int c = tid >> 2, nr = tid & 3;
  int n0 = (blockIdx.x * 4) & (NN - 1);
  int b0 = (blockIdx.x * 4) >> 12;
  size_t oi = (size_t)(b0 * 64 + c) * NN + n0 + nr;
  float ov = souts[nr][c];
  if (f32m) ((float*)outp)[oi] = ov;
  else      ((uint16_t*)outp)[oi] = f2bf(ov);
}

extern "C" void kernel_launch(void* const* d_in, const int* in_sizes, int n_in,
                              void* d_out, int out_size, void* d_ws, size_t ws_size,
                              hipStream_t stream) {
  const void* xyz1 = d_in[0];
  const void* feat1 = d_in[1];
  const void* xyz2 = d_in[2];
  const void* feat2 = d_in[3];
  const void* w_q1 = d_in[4];
  const void* w_k1 = d_in[5];
  const void* w_v1 = d_in[6];
  const void* w_mlp1 = d_in[7];
  const void* w_mlp2 = d_in[8];
  const void* w_pos1 = d_in[9];
  const void* b_pos1 = d_in[10];
  const void* w_q2 = d_in[11];
  const void* w_k2 = d_in[12];
  const void* w_v2 = d_in[13];
  const void* w_pos2 = d_in[14];
  const void* b_pos2 = d_in[15];
  u16p probe = (u16p)d_in[1];
  float* ws = (float*)d_ws;

  if (ws_size < WS_MIN_FLOATS * 4ull) return;

  int big = (ws_size >= 2490368ull * 4ull) ? 1 : 0;
  int f2cap   = big;
  int off_p2n = big ? 1179648 : 655360;
  int off_i12 = big ? 2228224 : 1703936;
  int off_i11 = big ? 2359296 : 1835008;

  hipLaunchKernelGGL(k_prep_xyz, dim3(64), dim3(256), 0, stream, xyz1, xyz2, probe, ws);
  hipLaunchKernelGGL(k_transpose, dim3(256), dim3(256), 0, stream, feat2, probe, ws, f2cap);
  hipLaunchKernelGGL(k_knn, dim3(4096), dim3(512), 0, stream, ws, off_i12, off_i11);
  hipLaunchKernelGGL(k_group1, dim3(4096), dim3(256), 0, stream,
                     feat1, w_q1, w_k1, w_v1, w_mlp1, w_mlp2, w_pos1, b_pos1,
                     probe, ws, off_p2n, off_i12, f2cap);
  hipLaunchKernelGGL(k_group2, dim3(4096), dim3(256), 0, stream,
                     w_q2, w_k2, w_v2, w_pos2, b_pos2,
                     probe, ws, d_out, off_p2n, off_i11);
}

// Round 6
// 783.615 us; speedup vs baseline: 2.2243x; 1.2331x over previous
//
#include <hip/hip_runtime.h>
#include <stdint.h>

#define NN 4096
#define SS 16

// fixed ws float offsets
#define OFF_XYZ1F 0          // 4*3*4096 f32
#define OFF_XYZ2F 49152      // 4*3*4096 f32
#define OFF_N1    98304      // 4*4096 f32
#define OFF_N2    114688     // 4*4096 f32 (dead after knn -> reused for folds)
#define OFF_F2T   131072     // feat2 transpose [b][n][c]: u16 (compact) or f32 (big)
#define WS_MIN_FLOATS 1966080ull

// fold matrices (inside dead N2 region, written by k_fold AFTER k_knn)
#define OFF_A2  114688   // (W1Wq - M*Wva)  [c][h] 1024
#define OFF_G   115712   // (M*Wvb)         [c][h] 1024
#define OFF_P5  116736   // [p][h] 80
#define OFF_MBP 116816   // M*bp1 [h] 16
#define OFF_C2  116832   // Wk2^T*Wq2 [c][o] 4096

typedef const uint16_t* u16p;

__device__ __forceinline__ float bf2f(uint16_t u) {
  return __uint_as_float(((uint32_t)u) << 16);
}
__device__ __forceinline__ uint16_t f2bf(float f) {
  uint32_t x = __float_as_uint(f);
  uint32_t r = (x + 0x7FFFu + ((x >> 16) & 1u)) >> 16;
  return (uint16_t)r;
}
__device__ __forceinline__ float ldi(const void* p, int i, int f32m) {
  return f32m ? ((const float*)p)[i] : bf2f(((const uint16_t*)p)[i]);
}
__device__ __forceinline__ int detect_f32(const uint16_t* probe) {
  int lane = threadIdx.x & 63;
  float a = bf2f(probe[lane]);
  float b = bf2f(probe[lane + 64]);
  int bad = (!(fabsf(a) <= 1e4f)) || (!(fabsf(b) <= 1e4f));
  return __any(bad) ? 1 : 0;
}

// ---------------- prep ----------------
__global__ __launch_bounds__(256) void k_prep_xyz(const void* xyz1, const void* xyz2,
                                                  u16p probe, float* ws) {
  int f32m = detect_f32(probe);
  int t = blockIdx.x * 256 + threadIdx.x;
  int b = t >> 12, n = t & (NN - 1);
  int base = b * 3 * NN + n;
  float x1 = ldi(xyz1, base, f32m), y1 = ldi(xyz1, base + NN, f32m), z1 = ldi(xyz1, base + 2 * NN, f32m);
  float x2 = ldi(xyz2, base, f32m), y2 = ldi(xyz2, base + NN, f32m), z2 = ldi(xyz2, base + 2 * NN, f32m);
  float* x1f = ws + OFF_XYZ1F;
  float* x2f = ws + OFF_XYZ2F;
  x1f[base] = x1; x1f[base + NN] = y1; x1f[base + 2 * NN] = z1;
  x2f[base] = x2; x2f[base + NN] = y2; x2f[base + 2 * NN] = z2;
  ws[OFF_N1 + t] = __fadd_rn(__fadd_rn(__fmul_rn(x1, x1), __fmul_rn(y1, y1)), __fmul_rn(z1, z1));
  ws[OFF_N2 + t] = __fadd_rn(__fadd_rn(__fmul_rn(x2, x2), __fmul_rn(y2, y2)), __fmul_rn(z2, z2));
}

// ---------------- transpose feat2 ----------------
__global__ __launch_bounds__(256) void k_transpose(const void* feat2, u16p probe,
                                                   float* ws, int f2cap) {
  __shared__ float tile[64][65];
  int f32m = detect_f32(probe);
  int b = blockIdx.x >> 6;
  int n0 = (blockIdx.x & 63) * 64;
  int tx = threadIdx.x & 63, ty = threadIdx.x >> 6;
#pragma unroll
  for (int i = 0; i < 16; ++i) {
    int c = i * 4 + ty;
    tile[c][tx] = ldi(feat2, (b * 64 + c) * NN + n0 + tx, f32m);
  }
  __syncthreads();
#pragma unroll
  for (int i = 0; i < 16; ++i) {
    int nl = i * 4 + ty;
    size_t di = (size_t)(b * NN + n0 + nl) * 64 + tx;
    float v = tile[tx][nl];
    if (f2cap) ((float*)(ws + OFF_F2T))[di] = v;
    else       ((uint16_t*)(ws + OFF_F2T))[di] = f2bf(v);
  }
}

// ---------------- KNN: wave-per-query ----------------
__global__ __launch_bounds__(256) void k_knn(float* ws, int off_i12, int off_i11) {
  __shared__ int eqbuf[4][16];
  int tid = threadIdx.x;
  int wv = tid >> 6, lane = tid & 63;
  int q = blockIdx.x * 4 + wv;
  int which = q >> 14;
  int b = (q >> 12) & 3;
  int n = q & (NN - 1);

  const float* cx = ws + (which ? OFF_XYZ1F : OFF_XYZ2F) + b * 3 * NN;
  const float* cn = ws + (which ? OFF_N1 : OFF_N2) + b * NN;
  const float* qp = ws + OFF_XYZ1F + b * 3 * NN;
  float qx = qp[n], qy = qp[NN + n], qz = qp[2 * NN + n];
  float q2 = ws[OFF_N1 + b * NN + n];

  float bd[16];
#pragma unroll
  for (int t = 0; t < 16; ++t) bd[t] = __builtin_inff();

#pragma unroll 2
  for (int i = 0; i < 64; ++i) {
    int j = i * 64 + lane;
    float cxv = cx[j], cyv = cx[NN + j], czv = cx[2 * NN + j], cw = cn[j];
    float cross = __fadd_rn(__fadd_rn(__fmul_rn(qx, cxv), __fmul_rn(qy, cyv)), __fmul_rn(qz, czv));
    float d = __fsub_rn(__fadd_rn(q2, cw), __fmul_rn(2.0f, cross));
    if (d < bd[15]) {
      float x = d;
#pragma unroll
      for (int t = 0; t < 16; ++t) {
        float lo = fminf(bd[t], x);
        x = fmaxf(bd[t], x);
        bd[t] = lo;
      }
    }
  }

  // wave pop-merge -> tau (exact multiset 16th smallest)
  float tau = 0.f;
  float h = bd[0];
#pragma unroll 1
  for (int r = 0; r < 16; ++r) {
    float m = h;
#pragma unroll
    for (int msk = 1; msk < 64; msk <<= 1) m = fminf(m, __shfl_xor(m, msk));
    unsigned long long win = __ballot(h == m);
    int winner = __ffsll(win) - 1;
    if (r == 15) tau = m;
    if (lane == winner) {
#pragma unroll
      for (int t = 0; t < 15; ++t) bd[t] = bd[t + 1];
      bd[15] = __builtin_inff();
      h = bd[0];
    }
  }

  // pass B: {d<tau} via ballot compaction + earliest equals
  uint16_t* outp = (uint16_t*)(ws + (which ? off_i11 : off_i12)) + (size_t)(b * NN + n) * SS;
  unsigned long long below = (1ull << lane) - 1ull;
  int c1 = 0, eqc = 0;
  for (int i = 0; i < 64; ++i) {
    int j = i * 64 + lane;
    float cxv = cx[j], cyv = cx[NN + j], czv = cx[2 * NN + j], cw = cn[j];
    float cross = __fadd_rn(__fadd_rn(__fmul_rn(qx, cxv), __fmul_rn(qy, cyv)), __fmul_rn(qz, czv));
    float d = __fsub_rn(__fadd_rn(q2, cw), __fmul_rn(2.0f, cross));
    bool lt = (d < tau), eq = (d == tau);
    unsigned long long mlt = __ballot(lt);
    unsigned long long meq = __ballot(eq);
    int pl = __popcll(mlt & below);
    if (lt && (c1 + pl) < 16) outp[c1 + pl] = (uint16_t)j;
    int pe = __popcll(meq & below);
    if (eq && (eqc + pe) < 16) eqbuf[wv][eqc + pe] = j;
    c1 += __popcll(mlt);
    eqc += __popcll(meq);
  }
  __syncthreads();   // hard barrier before eqbuf consumption (uniform flow)
  int need = 16 - c1;
  if (lane < need) outp[c1 + lane] = (uint16_t)eqbuf[wv][lane];
}

// ---------------- fold: precompute algebraic reductions (2 blocks) ----------------
__global__ __launch_bounds__(256) void k_fold(
    const void* w_q1, const void* w_k1, const void* w_v1, const void* w_mlp1,
    const void* w_pos1, const void* b_pos1, const void* w_q2, const void* w_k2,
    u16p probe, float* ws) {
  __shared__ float lA[4096];
  __shared__ float lB[2048];   // lW1[0:1024], lM[1024:2048]
  int f32m = detect_f32(probe);
  int tid = threadIdx.x;

  if (blockIdx.x == 1) {
    __shared__ float lQ[4096];
    for (int i = tid; i < 4096; i += 256) { lA[i] = ldi(w_k2, i, f32m); lQ[i] = ldi(w_q2, i, f32m); }
    __syncthreads();
    for (int i = tid; i < 4096; i += 256) {
      int c = i >> 6, o = i & 63;
      float a0 = 0.f, a1 = 0.f, a2 = 0.f, a3 = 0.f;
      for (int a = 0; a < 64; a += 4) {
        a0 = fmaf(lA[a * 64 + o],       lQ[a * 64 + c],       a0);
        a1 = fmaf(lA[(a + 1) * 64 + o], lQ[(a + 1) * 64 + c], a1);
        a2 = fmaf(lA[(a + 2) * 64 + o], lQ[(a + 2) * 64 + c], a2);
        a3 = fmaf(lA[(a + 3) * 64 + o], lQ[(a + 3) * 64 + c], a3);
      }
      ws[OFF_C2 + i] = (a0 + a1) + (a2 + a3);
    }
    return;
  }

  float* lW1 = lB;
  float* lM  = lB + 1024;
  for (int i = tid; i < 1024; i += 256) lW1[i] = ldi(w_mlp1, i, f32m);   // [h][m]
  for (int i = tid; i < 4096; i += 256) lA[i] = ldi(w_k1, i, f32m);      // [m][o]
  __syncthreads();
  for (int i = tid; i < 1024; i += 256) {       // M[h][o] = W1.Wk
    int hh = i >> 6, o = i & 63;
    float acc = 0.f;
    for (int m = 0; m < 64; ++m) acc = fmaf(lW1[hh * 64 + m], lA[m * 64 + o], acc);
    lM[i] = acc;
  }
  __syncthreads();
  float a2acc[4];
  for (int i = tid; i < 4096; i += 256) lA[i] = ldi(w_q1, i, f32m);      // [o][c]
  __syncthreads();
  for (int k = 0; k < 4; ++k) {
    int i = tid + k * 256;
    int c = i >> 4, hh = i & 15;
    float acc = 0.f;
    for (int o = 0; o < 64; ++o) acc = fmaf(lW1[hh * 64 + o], lA[o * 64 + c], acc);
    a2acc[k] = acc;
  }
  __syncthreads();
  for (int i = tid; i < 4096; i += 256) { int o = i >> 6, c = i & 63; lA[o * 64 + c] = ldi(w_v1, o * 131 + c, f32m); }
  __syncthreads();
  for (int k = 0; k < 4; ++k) {
    int i = tid + k * 256;
    int c = i >> 4, hh = i & 15;
    float acc = 0.f;
    for (int o = 0; o < 64; ++o) acc = fmaf(lM[hh * 64 + o], lA[o * 64 + c], acc);
    ws[OFF_A2 + i] = a2acc[k] - acc;
  }
  __syncthreads();
  for (int i = tid; i < 4096; i += 256) { int o = i >> 6, c = i & 63; lA[o * 64 + c] = ldi(w_v1, o * 131 + 64 + c, f32m); }
  __syncthreads();
  for (int i = tid; i < 1024; i += 256) {       // G[c][h] = M*Wvb
    int c = i >> 4, hh = i & 15;
    float acc = 0.f;
    for (int o = 0; o < 64; ++o) acc = fmaf(lM[hh * 64 + o], lA[o * 64 + c], acc);
    ws[OFF_G + i] = acc;
  }
  if (tid < 16) {
    int hh = tid;
    float p0 = 0.f, p1 = 0.f, p2 = 0.f, p3 = 0.f, p4 = 0.f, pb = 0.f;
    for (int o = 0; o < 64; ++o) {
      float m = lM[hh * 64 + o];
      p0 = fmaf(m, ldi(w_pos1, o * 5 + 0, f32m), p0);
      p1 = fmaf(m, ldi(w_pos1, o * 5 + 1, f32m), p1);
      p2 = fmaf(m, ldi(w_v1, o * 131 + 128, f32m) + ldi(w_pos1, o * 5 + 2, f32m), p2);
      p3 = fmaf(m, ldi(w_v1, o * 131 + 129, f32m) + ldi(w_pos1, o * 5 + 3, f32m), p3);
      p4 = fmaf(m, ldi(w_v1, o * 131 + 130, f32m) + ldi(w_pos1, o * 5 + 4, f32m), p4);
      pb = fmaf(m, ldi(b_pos1, o, f32m), pb);
    }
    ws[OFF_P5 + hh] = p0; ws[OFF_P5 + 16 + hh] = p1; ws[OFF_P5 + 32 + hh] = p2;
    ws[OFF_P5 + 48 + hh] = p3; ws[OFF_P5 + 64 + hh] = p4;
    ws[OFF_MBP + hh] = pb;
  }
}

// ---------------- group1 (folded, shuffle-only dataflow) ----------------
__global__ __launch_bounds__(512) void k_group1(
    const void* feat1, const void* w_v1, const void* w_mlp2,
    u16p probe, float* ws, int off_p2n, int off_i12, int f2cap) {
  __shared__ float s_wva[4096];    // [c][o]
  __shared__ float s_wvb[4096];    // [c][o]
  __shared__ float s_wvx[192];
  __shared__ float s_A2[1024];     // [c][h]
  __shared__ float s_G[1024];      // [c][h]
  __shared__ float s_P5[80];
  __shared__ float s_MBP[16];
  __shared__ float s_w2[16];
  __shared__ float xds[8][64];     // written pre-barrier, read-only after
  __shared__ int   idxs[8][16];    // written pre-barrier, read-only after

  int f32m = detect_f32(probe);
  int tid = threadIdx.x;
  for (int i = tid; i < 4096; i += 512) {
    int c = i >> 6, o = i & 63;
    s_wva[i] = ldi(w_v1, o * 131 + c, f32m);
    s_wvb[i] = ldi(w_v1, o * 131 + 64 + c, f32m);
  }
  if (tid < 192) { int j = tid >> 6, o = tid & 63; s_wvx[tid] = ldi(w_v1, o * 131 + 128 + j, f32m); }
  for (int i = tid; i < 1024; i += 512) { s_A2[i] = ws[OFF_A2 + i]; s_G[i] = ws[OFF_G + i]; }
  if (tid < 80) s_P5[tid] = ws[OFF_P5 + tid];
  if (tid < 16) { s_MBP[tid] = ws[OFF_MBP + tid]; s_w2[tid] = ldi(w_mlp2, tid, f32m); }

  int w = tid >> 6, o = tid & 63;
  int g = blockIdx.x * 8 + w;
  int b = g >> 12, n = g & (NN - 1);
  const float* x1f = ws + OFF_XYZ1F + b * 3 * NN;
  const float* x2f = ws + OFF_XYZ2F + b * 3 * NN;
  const uint16_t* idx12 = (const uint16_t*)(ws + off_i12) + (size_t)(b * NN + n) * SS;
  const float* f2f32 = (const float*)(ws + OFF_F2T);
  const uint16_t* f2u16 = (const uint16_t*)(ws + OFF_F2T);

  float f1o = ldi(feat1, (b * 64 + o) * NN + n, f32m);
  float qx = x1f[n], qy = x1f[NN + n], qz = x1f[2 * NN + n];
  if (o < 16) {
    int j = (int)idx12[o];
    idxs[w][o] = j;
    float dx = __fsub_rn(qx, x2f[j]);
    float dy = __fsub_rn(qy, x2f[NN + j]);
    float dz = __fsub_rn(qz, x2f[2 * NN + j]);
    xds[w][o * 4 + 0] = dx; xds[w][o * 4 + 1] = dy; xds[w][o * 4 + 2] = dz;
    xds[w][o * 4 + 3] = sqrtf(dx * dx + dy * dy + dz * dz);
  }
  __syncthreads();   // the ONLY barrier: everything below is registers/shfl/read-only LDS

  int h = o & 15, part = o >> 4;
  // vb[o] = Wva.pts via broadcast shuffles of f1o
  float v0 = 0.f, v1 = 0.f, v2 = 0.f, v3 = 0.f;
#pragma unroll
  for (int c = 0; c < 64; c += 4) {
    v0 = fmaf(s_wva[c * 64 + o],       __shfl(f1o, c),     v0);
    v1 = fmaf(s_wva[(c + 1) * 64 + o], __shfl(f1o, c + 1), v1);
    v2 = fmaf(s_wva[(c + 2) * 64 + o], __shfl(f1o, c + 2), v2);
    v3 = fmaf(s_wva[(c + 3) * 64 + o], __shfl(f1o, c + 3), v3);
  }
  float vb = (v0 + v1) + (v2 + v3);
  // tb[h] = (A2.pts)[h] - MBP[h]
  float tb = 0.f;
#pragma unroll
  for (int i = 0; i < 16; ++i) {
    int c = part * 16 + i;
    tb = fmaf(s_A2[c * 16 + h], __shfl(f1o, c), tb);
  }
  tb += __shfl_xor(tb, 16);
  tb += __shfl_xor(tb, 32);
  tb -= s_MBP[h];

  float lg[16];
#pragma unroll 1
  for (int s = 0; s < SS; ++s) {
    int j = idxs[w][s];
    size_t fi = (size_t)(b * NN + j) * 64 + o;
    float nb = f2cap ? f2f32[fi] : bf2f(f2u16[fi]);
    float df = __fsub_rn(f1o, nb);
    float ssq = df * df;
#pragma unroll
    for (int msk = 1; msk < 64; msk <<= 1) ssq += __shfl_xor(ssq, msk);
    float fn = sqrtf(ssq);
    float gl = 0.f;
#pragma unroll
    for (int i = 0; i < 16; ++i) {
      int c = part * 16 + i;
      gl = fmaf(s_G[c * 16 + h], __shfl(nb, c), gl);
    }
    gl += __shfl_xor(gl, 16);
    gl += __shfl_xor(gl, 32);
    float dx = xds[w][s * 4 + 0], dy = xds[w][s * 4 + 1], dz = xds[w][s * 4 + 2], xn = xds[w][s * 4 + 3];
    float p5 = s_P5[h] * fn;
    p5 = fmaf(s_P5[16 + h], xn, p5);
    p5 = fmaf(s_P5[32 + h], dx, p5);
    p5 = fmaf(s_P5[48 + h], dy, p5);
    p5 = fmaf(s_P5[64 + h], dz, p5);
    float t = tb - gl - p5;
    float r = fmaxf(t, 0.f) * s_w2[h];
    r += __shfl_xor(r, 1);
    r += __shfl_xor(r, 2);
    r += __shfl_xor(r, 4);
    r += __shfl_xor(r, 8);   // logit identical in ALL lanes
    lg[s] = r;
  }
  // register softmax (identical on all lanes)
  {
    float mx = lg[0];
#pragma unroll
    for (int s = 1; s < SS; ++s) mx = fmaxf(mx, lg[s]);
    float sum = 0.f;
#pragma unroll
    for (int s = 0; s < SS; ++s) { lg[s] = __expf(lg[s] - mx); sum += lg[s]; }
    float inv = 1.f / sum;
#pragma unroll
    for (int s = 0; s < SS; ++s) lg[s] *= inv;
  }
  // weighted aggregates
  float nbacc = 0.f, xa = 0.f, ya = 0.f, za = 0.f;
#pragma unroll 1
  for (int s = 0; s < SS; ++s) {
    float a = lg[s];
    int j = idxs[w][s];
    size_t fi = (size_t)(b * NN + j) * 64 + o;
    float nb = f2cap ? f2f32[fi] : bf2f(f2u16[fi]);
    nbacc = fmaf(a, nb, nbacc);
    xa = fmaf(a, xds[w][s * 4 + 0], xa);
    ya = fmaf(a, xds[w][s * 4 + 1], ya);
    za = fmaf(a, xds[w][s * 4 + 2], za);
  }
  // out = vb + Wvb.nbacc + Wvx.(xa,ya,za)
  float o0 = vb, o1 = 0.f, o2 = 0.f, o3 = 0.f;
#pragma unroll
  for (int c = 0; c < 64; c += 4) {
    o0 = fmaf(s_wvb[c * 64 + o],       __shfl(nbacc, c),     o0);
    o1 = fmaf(s_wvb[(c + 1) * 64 + o], __shfl(nbacc, c + 1), o1);
    o2 = fmaf(s_wvb[(c + 2) * 64 + o], __shfl(nbacc, c + 2), o2);
    o3 = fmaf(s_wvb[(c + 3) * 64 + o], __shfl(nbacc, c + 3), o3);
  }
  float acc = (o0 + o1) + (o2 + o3);
  acc = fmaf(s_wvx[o], xa, acc);
  acc = fmaf(s_wvx[64 + o], ya, acc);
  acc = fmaf(s_wvx[128 + o], za, acc);
  float res = acc >= 0.f ? acc : 0.1f * acc;   // leaky 0.1
  ws[off_p2n + (size_t)(b * NN + n) * 64 + o] = res;
}

// ---------------- group2 (folded, shuffle-only dataflow) ----------------
__global__ __launch_bounds__(512) void k_group2(
    const void* w_v2, const void* w_pos2, const void* b_pos2,
    u16p probe, float* ws, void* outp, int off_p2n, int off_i11) {
  __shared__ float s_C2[4096];    // [c][o]
  __shared__ float s_wv2[4096];   // [c][o]
  __shared__ float s_wp2t[256];   // [p][o]
  __shared__ float s_bp2[64];
  __shared__ float xds[8][64];
  __shared__ int   idxs[8][16];
  __shared__ float souts[8][64];

  int f32m = detect_f32(probe);
  int tid = threadIdx.x;
  for (int i = tid; i < 4096; i += 512) {
    int c = i >> 6, o = i & 63;
    s_C2[i] = ws[OFF_C2 + i];
    s_wv2[i] = ldi(w_v2, o * 64 + c, f32m);
  }
  if (tid < 256) { int p = tid >> 6, o = tid & 63; s_wp2t[p * 64 + o] = ldi(w_pos2, o * 4 + p, f32m); }
  if (tid < 64) s_bp2[tid] = ldi(b_pos2, tid, f32m);

  int w = tid >> 6, o = tid & 63;
  int g = blockIdx.x * 8 + w;
  int b = g >> 12, n = g & (NN - 1);
  const float* p2t = ws + off_p2n;
  const float* x1f = ws + OFF_XYZ1F + b * 3 * NN;
  const uint16_t* idx11 = (const uint16_t*)(ws + off_i11) + (size_t)(b * NN + n) * SS;

  float p1o = p2t[(size_t)(b * NN + n) * 64 + o];
  float qx = x1f[n], qy = x1f[NN + n], qz = x1f[2 * NN + n];
  if (o < 16) {
    int j = (int)idx11[o];
    idxs[w][o] = j;
    float dx = __fsub_rn(qx, x1f[j]);
    float dy = __fsub_rn(qy, x1f[NN + j]);
    float dz = __fsub_rn(qz, x1f[2 * NN + j]);
    xds[w][o * 4 + 0] = dx; xds[w][o * 4 + 1] = dy; xds[w][o * 4 + 2] = dz;
    xds[w][o * 4 + 3] = sqrtf(dx * dx + dy * dy + dz * dz);
  }
  __syncthreads();   // staging barrier; below: registers/shfl/read-only LDS

  // u[o] = (Wk2^T Wq2).pts via broadcast shuffles
  float u0 = 0.f, u1 = 0.f, u2 = 0.f, u3 = 0.f;
#pragma unroll
  for (int c = 0; c < 64; c += 4) {
    u0 = fmaf(s_C2[c * 64 + o],       __shfl(p1o, c),     u0);
    u1 = fmaf(s_C2[(c + 1) * 64 + o], __shfl(p1o, c + 1), u1);
    u2 = fmaf(s_C2[(c + 2) * 64 + o], __shfl(p1o, c + 2), u2);
    u3 = fmaf(s_C2[(c + 3) * 64 + o], __shfl(p1o, c + 3), u3);
  }
  float u = (u0 + u1) + (u2 + u3);
  float w4x = u * s_wp2t[o];
  float w4y = u * s_wp2t[64 + o];
  float w4z = u * s_wp2t[128 + o];
  float w4n = u * s_wp2t[192 + o];
  float ubp = u * s_bp2[o];
#pragma unroll
  for (int msk = 1; msk < 64; msk <<= 1) {
    w4x += __shfl_xor(w4x, msk);
    w4y += __shfl_xor(w4y, msk);
    w4z += __shfl_xor(w4z, msk);
    w4n += __shfl_xor(w4n, msk);
    ubp += __shfl_xor(ubp, msk);
  }

  float lg[16];
#pragma unroll 1
  for (int s = 0; s < SS; ++s) {
    int j = idxs[w][s];
    float nb = p2t[(size_t)(b * NN + j) * 64 + o];
    float t = u * nb;
#pragma unroll
    for (int msk = 1; msk < 64; msk <<= 1) t += __shfl_xor(t, msk);
    float dx = xds[w][s * 4 + 0], dy = xds[w][s * 4 + 1], dz = xds[w][s * 4 + 2], xn = xds[w][s * 4 + 3];
    float logit = t;
    logit = fmaf(w4x, dx, logit);
    logit = fmaf(w4y, dy, logit);
    logit = fmaf(w4z, dz, logit);
    logit = fmaf(w4n, xn, logit);
    lg[s] = (logit + ubp) * 0.125f;   // identical in all lanes
  }
  {
    float mx = lg[0];
#pragma unroll
    for (int s = 1; s < SS; ++s) mx = fmaxf(mx, lg[s]);
    float sum = 0.f;
#pragma unroll
    for (int s = 0; s < SS; ++s) { lg[s] = __expf(lg[s] - mx); sum += lg[s]; }
    float inv = 1.f / sum;
#pragma unroll
    for (int s = 0; s < SS; ++s) lg[s] *= inv;
  }
  float nbacc = 0.f;
#pragma unroll 1
  for (int s = 0; s < SS; ++s) {
    int j = idxs[w][s];
    nbacc = fmaf(lg[s], p2t[(size_t)(b * NN + j) * 64 + o], nbacc);
  }
  float o0 = 0.f, o1 = 0.f, o2 = 0.f, o3 = 0.f;
#pragma unroll
  for (int c = 0; c < 64; c += 4) {
    o0 = fmaf(s_wv2[c * 64 + o],       __shfl(nbacc, c),     o0);
    o1 = fmaf(s_wv2[(c + 1) * 64 + o], __shfl(nbacc, c + 1), o1);
    o2 = fmaf(s_wv2[(c + 2) * 64 + o], __shfl(nbacc, c + 2), o2);
    o3 = fmaf(s_wv2[(c + 3) * 64 + o], __shfl(nbacc, c + 3), o3);
  }
  float acc = (o0 + o1) + (o2 + o3);
  float res = acc >= 0.f ? acc : 0.1f * acc;
  souts[w][o] = res;
  __syncthreads();   // cross-wave transpose staging
  int c = tid >> 3, nr = tid & 7;
  int n0 = (blockIdx.x * 8) & (NN - 1);
  int b0 = (blockIdx.x * 8) >> 12;
  size_t oi = (size_t)(b0 * 64 + c) * NN + n0 + nr;
  float ov = souts[nr][c];
  if (f32m) ((float*)outp)[oi] = ov;
  else      ((uint16_t*)outp)[oi] = f2bf(ov);
}

extern "C" void kernel_launch(void* const* d_in, const int* in_sizes, int n_in,
                              void* d_out, int out_size, void* d_ws, size_t ws_size,
                              hipStream_t stream) {
  const void* xyz1 = d_in[0];
  const void* feat1 = d_in[1];
  const void* xyz2 = d_in[2];
  const void* feat2 = d_in[3];
  const void* w_q1 = d_in[4];
  const void* w_k1 = d_in[5];
  const void* w_v1 = d_in[6];
  const void* w_mlp1 = d_in[7];
  const void* w_mlp2 = d_in[8];
  const void* w_pos1 = d_in[9];
  const void* b_pos1 = d_in[10];
  const void* w_q2 = d_in[11];
  const void* w_k2 = d_in[12];
  const void* w_v2 = d_in[13];
  const void* w_pos2 = d_in[14];
  const void* b_pos2 = d_in[15];
  u16p probe = (u16p)d_in[1];
  float* ws = (float*)d_ws;

  if (ws_size < WS_MIN_FLOATS * 4ull) return;

  int big = (ws_size >= 2490368ull * 4ull) ? 1 : 0;
  int f2cap   = big;
  int off_p2n = big ? 1179648 : 655360;
  int off_i12 = big ? 2228224 : 1703936;
  int off_i11 = big ? 2359296 : 1835008;

  hipLaunchKernelGGL(k_prep_xyz, dim3(64), dim3(256), 0, stream, xyz1, xyz2, probe, ws);
  hipLaunchKernelGGL(k_transpose, dim3(256), dim3(256), 0, stream, feat2, probe, ws, f2cap);
  hipLaunchKernelGGL(k_knn, dim3(8192), dim3(256), 0, stream, ws, off_i12, off_i11);
  hipLaunchKernelGGL(k_fold, dim3(2), dim3(256), 0, stream,
                     w_q1, w_k1, w_v1, w_mlp1, w_pos1, b_pos1, w_q2, w_k2, probe, ws);
  hipLaunchKernelGGL(k_group1, dim3(2048), dim3(512), 0, stream,
                     feat1, w_v1, w_mlp2, probe, ws, off_p2n, off_i12, f2cap);
  hipLaunchKernelGGL(k_group2, dim3(2048), dim3(512), 0, stream,
                     w_v2, w_pos2, b_pos2, probe, ws, d_out, off_p2n, off_i11);
}

// Round 7
// 638.089 us; speedup vs baseline: 2.7316x; 1.2281x over previous
//
#include <hip/hip_runtime.h>
#include <stdint.h>

#define NN 4096
#define SS 16

// fixed ws float offsets
#define OFF_XYZ1F 0          // 4*3*4096 f32
#define OFF_XYZ2F 49152      // 4*3*4096 f32
#define OFF_N1    98304      // 4*4096 f32
#define OFF_N2    114688     // 4*4096 f32 (dead after knn -> reused for folds)
#define OFF_F2T   131072     // feat2 transpose [b][n][c]: u16 (compact) or f32 (big)
#define WS_MIN_FLOATS 1966080ull

// fold matrices (inside dead N2 region, written by k_fold AFTER k_knn)
#define OFF_A2  114688   // (W1Wq - M*Wva)  [c][h] 1024
#define OFF_G   115712   // (M*Wvb)         [c][h] 1024
#define OFF_P5  116736   // [p][h] 80
#define OFF_MBP 116816   // M*bp1 [h] 16
#define OFF_C2  116832   // Wk2^T*Wq2 [c][o] 4096

typedef const uint16_t* u16p;

__device__ __forceinline__ float bf2f(uint16_t u) {
  return __uint_as_float(((uint32_t)u) << 16);
}
__device__ __forceinline__ uint16_t f2bf(float f) {
  uint32_t x = __float_as_uint(f);
  uint32_t r = (x + 0x7FFFu + ((x >> 16) & 1u)) >> 16;
  return (uint16_t)r;
}
__device__ __forceinline__ float ldi(const void* p, int i, int f32m) {
  return f32m ? ((const float*)p)[i] : bf2f(((const uint16_t*)p)[i]);
}
__device__ __forceinline__ int detect_f32(const uint16_t* probe) {
  int lane = threadIdx.x & 63;
  float a = bf2f(probe[lane]);
  float b = bf2f(probe[lane + 64]);
  int bad = (!(fabsf(a) <= 1e4f)) || (!(fabsf(b) <= 1e4f));
  return __any(bad) ? 1 : 0;
}

// ---------------- prep ----------------
__global__ __launch_bounds__(256) void k_prep_xyz(const void* xyz1, const void* xyz2,
                                                  u16p probe, float* ws) {
  int f32m = detect_f32(probe);
  int t = blockIdx.x * 256 + threadIdx.x;
  int b = t >> 12, n = t & (NN - 1);
  int base = b * 3 * NN + n;
  float x1 = ldi(xyz1, base, f32m), y1 = ldi(xyz1, base + NN, f32m), z1 = ldi(xyz1, base + 2 * NN, f32m);
  float x2 = ldi(xyz2, base, f32m), y2 = ldi(xyz2, base + NN, f32m), z2 = ldi(xyz2, base + 2 * NN, f32m);
  float* x1f = ws + OFF_XYZ1F;
  float* x2f = ws + OFF_XYZ2F;
  x1f[base] = x1; x1f[base + NN] = y1; x1f[base + 2 * NN] = z1;
  x2f[base] = x2; x2f[base + NN] = y2; x2f[base + 2 * NN] = z2;
  ws[OFF_N1 + t] = __fadd_rn(__fadd_rn(__fmul_rn(x1, x1), __fmul_rn(y1, y1)), __fmul_rn(z1, z1));
  ws[OFF_N2 + t] = __fadd_rn(__fadd_rn(__fmul_rn(x2, x2), __fmul_rn(y2, y2)), __fmul_rn(z2, z2));
}

// ---------------- transpose feat2 ----------------
__global__ __launch_bounds__(256) void k_transpose(const void* feat2, u16p probe,
                                                   float* ws, int f2cap) {
  __shared__ float tile[64][65];
  int f32m = detect_f32(probe);
  int b = blockIdx.x >> 6;
  int n0 = (blockIdx.x & 63) * 64;
  int tx = threadIdx.x & 63, ty = threadIdx.x >> 6;
#pragma unroll
  for (int i = 0; i < 16; ++i) {
    int c = i * 4 + ty;
    tile[c][tx] = ldi(feat2, (b * 64 + c) * NN + n0 + tx, f32m);
  }
  __syncthreads();
#pragma unroll
  for (int i = 0; i < 16; ++i) {
    int nl = i * 4 + ty;
    size_t di = (size_t)(b * NN + n0 + nl) * 64 + tx;
    float v = tile[tx][nl];
    if (f2cap) ((float*)(ws + OFF_F2T))[di] = v;
    else       ((uint16_t*)(ws + OFF_F2T))[di] = f2bf(v);
  }
}

// ---------------- KNN: wave-per-query, subsample-threshold filter ----------------
// Exact same fp32 distance as np reference; exact top-16 SET (ties by low index).
#define KCAP 320
__device__ __forceinline__ float knn_dist(const float* cx, const float* cn,
                                          float qx, float qy, float qz, float q2, int j) {
  float cross = __fadd_rn(__fadd_rn(__fmul_rn(qx, cx[j]), __fmul_rn(qy, cx[NN + j])),
                          __fmul_rn(qz, cx[2 * NN + j]));
  return __fsub_rn(__fadd_rn(q2, cn[j]), __fmul_rn(2.0f, cross));
}

__global__ __launch_bounds__(256) void k_knn(float* ws, int off_i12, int off_i11) {
  __shared__ float sd[4][KCAP];
  __shared__ int   si[4][KCAP];
  __shared__ int   eqbuf[4][16];

  int tid = threadIdx.x;
  int wv = tid >> 6, lane = tid & 63;
  int q = blockIdx.x * 4 + wv;
  int which = q >> 14;
  int b = (q >> 12) & 3;
  int n = q & (NN - 1);

  const float* cx = ws + (which ? OFF_XYZ1F : OFF_XYZ2F) + b * 3 * NN;
  const float* cn = ws + (which ? OFF_N1 : OFF_N2) + b * NN;
  const float* qp = ws + OFF_XYZ1F + b * 3 * NN;
  float qx = qp[n], qy = qp[NN + n], qz = qp[2 * NN + n];
  float q2 = ws[OFF_N1 + b * NN + n];
  const float INF = __builtin_inff();

  // ---- phase 1: subsample (first 1024 cands) per-lane min ----
  float mn = INF;
#pragma unroll 4
  for (int i = 0; i < 16; ++i) {
    float d = knn_dist(cx, cn, qx, qy, qz, q2, i * 64 + lane);
    mn = fminf(mn, d);
  }
  // tau0 = 16th smallest of the 64 lane minima.
  // The 16 smallest lane-minima are 16 DISTINCT candidates => true 16th <= tau0.
  float tau0 = 0.f;
  {
    float h = mn;
#pragma unroll 1
    for (int r = 0; r < 16; ++r) {
      float m = h;
#pragma unroll
      for (int msk = 1; msk < 64; msk <<= 1) m = fminf(m, __shfl_xor(m, msk));
      if (r == 15) tau0 = m;
      unsigned long long win = __ballot(h == m);
      int winner = __ffsll(win) - 1;
      if (lane == winner) h = INF;
    }
  }

  // ---- phase 2: full scan, collect survivors d <= tau0 (j-ascending order) ----
  unsigned long long below = (1ull << lane) - 1ull;
  int c = 0;
#pragma unroll 2
  for (int i = 0; i < 64; ++i) {
    int j = i * 64 + lane;
    float d = knn_dist(cx, cn, qx, qy, qz, q2, j);
    bool sel = (d <= tau0);
    unsigned long long msk = __ballot(sel);
    int pos = c + __popcll(msk & below);
    if (sel && pos < KCAP) { sd[wv][pos] = d; si[wv][pos] = j; }
    c += __popcll(msk);
  }
  // Overflow needs >KCAP cands within the ~rank-100 bound tau0, i.e. the top-100
  // distances hitting <16 of 64 lanes: probability ~e^-50. Clamp for safety.
  if (c > KCAP) c = KCAP;
  __syncthreads();   // survivor lists visible block-wide (uniform flow)

  // ---- phase 3: exact tau = 16th smallest (multiset) among survivors ----
  float ch[5];
#pragma unroll
  for (int t = 0; t < 5; ++t) ch[t] = INF;
#pragma unroll
  for (int t = 0; t < 5; ++t) {
    int p = t * 64 + lane;
    float x = (p < c) ? sd[wv][p] : INF;
#pragma unroll
    for (int u = 0; u < 5; ++u) {        // insert-sort into ascending chain
      float lo = fminf(ch[u], x);
      x = fmaxf(ch[u], x);
      ch[u] = lo;
    }
  }
  float tau = 0.f;
  {
    float h = ch[0];
#pragma unroll 1
    for (int r = 0; r < 16; ++r) {
      float m = h;
#pragma unroll
      for (int msk = 1; msk < 64; msk <<= 1) m = fminf(m, __shfl_xor(m, msk));
      if (r == 15) tau = m;
      unsigned long long win = __ballot(h == m);
      int winner = __ffsll(win) - 1;
      if (lane == winner) {
        ch[0] = ch[1]; ch[1] = ch[2]; ch[2] = ch[3]; ch[3] = ch[4]; ch[4] = INF;
        h = ch[0];
      }
    }
  }

  // ---- phase 4: select {d<tau} + earliest equals from survivor list ----
  uint16_t* outp = (uint16_t*)(ws + (which ? off_i11 : off_i12)) + (size_t)(b * NN + n) * SS;
  int c1 = 0, eqc = 0;
#pragma unroll
  for (int t = 0; t < 5; ++t) {
    int p = t * 64 + lane;
    bool act = (p < c);
    float d = act ? sd[wv][p] : INF;
    int j = act ? si[wv][p] : 0;
    bool lt = act && (d < tau);
    bool eq = act && (d == tau);
    unsigned long long mlt = __ballot(lt);
    unsigned long long meq = __ballot(eq);
    int pl = __popcll(mlt & below);
    if (lt) outp[c1 + pl] = (uint16_t)j;          // #{d<tau} <= 15 always
    int pe = __popcll(meq & below);
    if (eq && (eqc + pe) < 16) eqbuf[wv][eqc + pe] = j;
    c1 += __popcll(mlt);
    eqc += __popcll(meq);
  }
  __syncthreads();   // eqbuf visible (uniform flow)
  int need = 16 - c1;
  if (lane < need) outp[c1 + lane] = (uint16_t)eqbuf[wv][lane];
}

// ---------------- fold: precompute algebraic reductions (2 blocks) ----------------
__global__ __launch_bounds__(256) void k_fold(
    const void* w_q1, const void* w_k1, const void* w_v1, const void* w_mlp1,
    const void* w_pos1, const void* b_pos1, const void* w_q2, const void* w_k2,
    u16p probe, float* ws) {
  __shared__ float lA[4096];
  __shared__ float lB[2048];   // lW1[0:1024], lM[1024:2048]
  int f32m = detect_f32(probe);
  int tid = threadIdx.x;

  if (blockIdx.x == 1) {
    __shared__ float lQ[4096];
    for (int i = tid; i < 4096; i += 256) { lA[i] = ldi(w_k2, i, f32m); lQ[i] = ldi(w_q2, i, f32m); }
    __syncthreads();
    for (int i = tid; i < 4096; i += 256) {
      int c = i >> 6, o = i & 63;
      float a0 = 0.f, a1 = 0.f, a2 = 0.f, a3 = 0.f;
      for (int a = 0; a < 64; a += 4) {
        a0 = fmaf(lA[a * 64 + o],       lQ[a * 64 + c],       a0);
        a1 = fmaf(lA[(a + 1) * 64 + o], lQ[(a + 1) * 64 + c], a1);
        a2 = fmaf(lA[(a + 2) * 64 + o], lQ[(a + 2) * 64 + c], a2);
        a3 = fmaf(lA[(a + 3) * 64 + o], lQ[(a + 3) * 64 + c], a3);
      }
      ws[OFF_C2 + i] = (a0 + a1) + (a2 + a3);
    }
    return;
  }

  float* lW1 = lB;
  float* lM  = lB + 1024;
  for (int i = tid; i < 1024; i += 256) lW1[i] = ldi(w_mlp1, i, f32m);   // [h][m]
  for (int i = tid; i < 4096; i += 256) lA[i] = ldi(w_k1, i, f32m);      // [m][o]
  __syncthreads();
  for (int i = tid; i < 1024; i += 256) {       // M[h][o] = W1.Wk
    int hh = i >> 6, o = i & 63;
    float acc = 0.f;
    for (int m = 0; m < 64; ++m) acc = fmaf(lW1[hh * 64 + m], lA[m * 64 + o], acc);
    lM[i] = acc;
  }
  __syncthreads();
  float a2acc[4];
  for (int i = tid; i < 4096; i += 256) lA[i] = ldi(w_q1, i, f32m);      // [o][c]
  __syncthreads();
  for (int k = 0; k < 4; ++k) {
    int i = tid + k * 256;
    int c = i >> 4, hh = i & 15;
    float acc = 0.f;
    for (int o = 0; o < 64; ++o) acc = fmaf(lW1[hh * 64 + o], lA[o * 64 + c], acc);
    a2acc[k] = acc;
  }
  __syncthreads();
  for (int i = tid; i < 4096; i += 256) { int o = i >> 6, c = i & 63; lA[o * 64 + c] = ldi(w_v1, o * 131 + c, f32m); }
  __syncthreads();
  for (int k = 0; k < 4; ++k) {
    int i = tid + k * 256;
    int c = i >> 4, hh = i & 15;
    float acc = 0.f;
    for (int o = 0; o < 64; ++o) acc = fmaf(lM[hh * 64 + o], lA[o * 64 + c], acc);
    ws[OFF_A2 + i] = a2acc[k] - acc;
  }
  __syncthreads();
  for (int i = tid; i < 4096; i += 256) { int o = i >> 6, c = i & 63; lA[o * 64 + c] = ldi(w_v1, o * 131 + 64 + c, f32m); }
  __syncthreads();
  for (int i = tid; i < 1024; i += 256) {       // G[c][h] = M*Wvb
    int c = i >> 4, hh = i & 15;
    float acc = 0.f;
    for (int o = 0; o < 64; ++o) acc = fmaf(lM[hh * 64 + o], lA[o * 64 + c], acc);
    ws[OFF_G + i] = acc;
  }
  if (tid < 16) {
    int hh = tid;
    float p0 = 0.f, p1 = 0.f, p2 = 0.f, p3 = 0.f, p4 = 0.f, pb = 0.f;
    for (int o = 0; o < 64; ++o) {
      float m = lM[hh * 64 + o];
      p0 = fmaf(m, ldi(w_pos1, o * 5 + 0, f32m), p0);
      p1 = fmaf(m, ldi(w_pos1, o * 5 + 1, f32m), p1);
      p2 = fmaf(m, ldi(w_v1, o * 131 + 128, f32m) + ldi(w_pos1, o * 5 + 2, f32m), p2);
      p3 = fmaf(m, ldi(w_v1, o * 131 + 129, f32m) + ldi(w_pos1, o * 5 + 3, f32m), p3);
      p4 = fmaf(m, ldi(w_v1, o * 131 + 130, f32m) + ldi(w_pos1, o * 5 + 4, f32m), p4);
      pb = fmaf(m, ldi(b_pos1, o, f32m), pb);
    }
    ws[OFF_P5 + hh] = p0; ws[OFF_P5 + 16 + hh] = p1; ws[OFF_P5 + 32 + hh] = p2;
    ws[OFF_P5 + 48 + hh] = p3; ws[OFF_P5 + 64 + hh] = p4;
    ws[OFF_MBP + hh] = pb;
  }
}

// ---------------- group1 (folded, shuffle-only dataflow) ----------------
__global__ __launch_bounds__(512) void k_group1(
    const void* feat1, const void* w_v1, const void* w_mlp2,
    u16p probe, float* ws, int off_p2n, int off_i12, int f2cap) {
  __shared__ float s_wva[4096];    // [c][o]
  __shared__ float s_wvb[4096];    // [c][o]
  __shared__ float s_wvx[192];
  __shared__ float s_A2[1024];     // [c][h]
  __shared__ float s_G[1024];      // [c][h]
  __shared__ float s_P5[80];
  __shared__ float s_MBP[16];
  __shared__ float s_w2[16];
  __shared__ float xds[8][64];     // written pre-barrier, read-only after
  __shared__ int   idxs[8][16];    // written pre-barrier, read-only after

  int f32m = detect_f32(probe);
  int tid = threadIdx.x;
  for (int i = tid; i < 4096; i += 512) {
    int c = i >> 6, o = i & 63;
    s_wva[i] = ldi(w_v1, o * 131 + c, f32m);
    s_wvb[i] = ldi(w_v1, o * 131 + 64 + c, f32m);
  }
  if (tid < 192) { int j = tid >> 6, o = tid & 63; s_wvx[tid] = ldi(w_v1, o * 131 + 128 + j, f32m); }
  for (int i = tid; i < 1024; i += 512) { s_A2[i] = ws[OFF_A2 + i]; s_G[i] = ws[OFF_G + i]; }
  if (tid < 80) s_P5[tid] = ws[OFF_P5 + tid];
  if (tid < 16) { s_MBP[tid] = ws[OFF_MBP + tid]; s_w2[tid] = ldi(w_mlp2, tid, f32m); }

  int w = tid >> 6, o = tid & 63;
  int g = blockIdx.x * 8 + w;
  int b = g >> 12, n = g & (NN - 1);
  const float* x1f = ws + OFF_XYZ1F + b * 3 * NN;
  const float* x2f = ws + OFF_XYZ2F + b * 3 * NN;
  const uint16_t* idx12 = (const uint16_t*)(ws + off_i12) + (size_t)(b * NN + n) * SS;
  const float* f2f32 = (const float*)(ws + OFF_F2T);
  const uint16_t* f2u16 = (const uint16_t*)(ws + OFF_F2T);

  float f1o = ldi(feat1, (b * 64 + o) * NN + n, f32m);
  float qx = x1f[n], qy = x1f[NN + n], qz = x1f[2 * NN + n];
  if (o < 16) {
    int j = (int)idx12[o];
    idxs[w][o] = j;
    float dx = __fsub_rn(qx, x2f[j]);
    float dy = __fsub_rn(qy, x2f[NN + j]);
    float dz = __fsub_rn(qz, x2f[2 * NN + j]);
    xds[w][o * 4 + 0] = dx; xds[w][o * 4 + 1] = dy; xds[w][o * 4 + 2] = dz;
    xds[w][o * 4 + 3] = sqrtf(dx * dx + dy * dy + dz * dz);
  }
  __syncthreads();   // the ONLY barrier: everything below is registers/shfl/read-only LDS

  int h = o & 15, part = o >> 4;
  // vb[o] = Wva.pts via broadcast shuffles of f1o
  float v0 = 0.f, v1 = 0.f, v2 = 0.f, v3 = 0.f;
#pragma unroll
  for (int c = 0; c < 64; c += 4) {
    v0 = fmaf(s_wva[c * 64 + o],       __shfl(f1o, c),     v0);
    v1 = fmaf(s_wva[(c + 1) * 64 + o], __shfl(f1o, c + 1), v1);
    v2 = fmaf(s_wva[(c + 2) * 64 + o], __shfl(f1o, c + 2), v2);
    v3 = fmaf(s_wva[(c + 3) * 64 + o], __shfl(f1o, c + 3), v3);
  }
  float vb = (v0 + v1) + (v2 + v3);
  // tb[h] = (A2.pts)[h] - MBP[h]
  float tb = 0.f;
#pragma unroll
  for (int i = 0; i < 16; ++i) {
    int c = part * 16 + i;
    tb = fmaf(s_A2[c * 16 + h], __shfl(f1o, c), tb);
  }
  tb += __shfl_xor(tb, 16);
  tb += __shfl_xor(tb, 32);
  tb -= s_MBP[h];

  float lg[16];
#pragma unroll 1
  for (int s = 0; s < SS; ++s) {
    int j = idxs[w][s];
    size_t fi = (size_t)(b * NN + j) * 64 + o;
    float nb = f2cap ? f2f32[fi] : bf2f(f2u16[fi]);
    float df = __fsub_rn(f1o, nb);
    float ssq = df * df;
#pragma unroll
    for (int msk = 1; msk < 64; msk <<= 1) ssq += __shfl_xor(ssq, msk);
    float fn = sqrtf(ssq);
    float gl = 0.f;
#pragma unroll
    for (int i = 0; i < 16; ++i) {
      int c = part * 16 + i;
      gl = fmaf(s_G[c * 16 + h], __shfl(nb, c), gl);
    }
    gl += __shfl_xor(gl, 16);
    gl += __shfl_xor(gl, 32);
    float dx = xds[w][s * 4 + 0], dy = xds[w][s * 4 + 1], dz = xds[w][s * 4 + 2], xn = xds[w][s * 4 + 3];
    float p5 = s_P5[h] * fn;
    p5 = fmaf(s_P5[16 + h], xn, p5);
    p5 = fmaf(s_P5[32 + h], dx, p5);
    p5 = fmaf(s_P5[48 + h], dy, p5);
    p5 = fmaf(s_P5[64 + h], dz, p5);
    float t = tb - gl - p5;
    float r = fmaxf(t, 0.f) * s_w2[h];
    r += __shfl_xor(r, 1);
    r += __shfl_xor(r, 2);
    r += __shfl_xor(r, 4);
    r += __shfl_xor(r, 8);   // logit identical in ALL lanes
    lg[s] = r;
  }
  // register softmax (identical on all lanes)
  {
    float mx = lg[0];
#pragma unroll
    for (int s = 1; s < SS; ++s) mx = fmaxf(mx, lg[s]);
    float sum = 0.f;
#pragma unroll
    for (int s = 0; s < SS; ++s) { lg[s] = __expf(lg[s] - mx); sum += lg[s]; }
    float inv = 1.f / sum;
#pragma unroll
    for (int s = 0; s < SS; ++s) lg[s] *= inv;
  }
  // weighted aggregates
  float nbacc = 0.f, xa = 0.f, ya = 0.f, za = 0.f;
#pragma unroll 1
  for (int s = 0; s < SS; ++s) {
    float a = lg[s];
    int j = idxs[w][s];
    size_t fi = (size_t)(b * NN + j) * 64 + o;
    float nb = f2cap ? f2f32[fi] : bf2f(f2u16[fi]);
    nbacc = fmaf(a, nb, nbacc);
    xa = fmaf(a, xds[w][s * 4 + 0], xa);
    ya = fmaf(a, xds[w][s * 4 + 1], ya);
    za = fmaf(a, xds[w][s * 4 + 2], za);
  }
  // out = vb + Wvb.nbacc + Wvx.(xa,ya,za)
  float o0 = vb, o1 = 0.f, o2 = 0.f, o3 = 0.f;
#pragma unroll
  for (int c = 0; c < 64; c += 4) {
    o0 = fmaf(s_wvb[c * 64 + o],       __shfl(nbacc, c),     o0);
    o1 = fmaf(s_wvb[(c + 1) * 64 + o], __shfl(nbacc, c + 1), o1);
    o2 = fmaf(s_wvb[(c + 2) * 64 + o], __shfl(nbacc, c + 2), o2);
    o3 = fmaf(s_wvb[(c + 3) * 64 + o], __shfl(nbacc, c + 3), o3);
  }
  float acc = (o0 + o1) + (o2 + o3);
  acc = fmaf(s_wvx[o], xa, acc);
  acc = fmaf(s_wvx[64 + o], ya, acc);
  acc = fmaf(s_wvx[128 + o], za, acc);
  float res = acc >= 0.f ? acc : 0.1f * acc;   // leaky 0.1
  ws[off_p2n + (size_t)(b * NN + n) * 64 + o] = res;
}

// ---------------- group2 (folded, shuffle-only dataflow) ----------------
__global__ __launch_bounds__(512) void k_group2(
    const void* w_v2, const void* w_pos2, const void* b_pos2,
    u16p probe, float* ws, void* outp, int off_p2n, int off_i11) {
  __shared__ float s_C2[4096];    // [c][o]
  __shared__ float s_wv2[4096];   // [c][o]
  __shared__ float s_wp2t[256];   // [p][o]
  __shared__ float s_bp2[64];
  __shared__ float xds[8][64];
  __shared__ int   idxs[8][16];
  __shared__ float souts[8][64];

  int f32m = detect_f32(probe);
  int tid = threadIdx.x;
  for (int i = tid; i < 4096; i += 512) {
    int c = i >> 6, o = i & 63;
    s_C2[i] = ws[OFF_C2 + i];
    s_wv2[i] = ldi(w_v2, o * 64 + c, f32m);
  }
  if (tid < 256) { int p = tid >> 6, o = tid & 63; s_wp2t[p * 64 + o] = ldi(w_pos2, o * 4 + p, f32m); }
  if (tid < 64) s_bp2[tid] = ldi(b_pos2, tid, f32m);

  int w = tid >> 6, o = tid & 63;
  int g = blockIdx.x * 8 + w;
  int b = g >> 12, n = g & (NN - 1);
  const float* p2t = ws + off_p2n;
  const float* x1f = ws + OFF_XYZ1F + b * 3 * NN;
  const uint16_t* idx11 = (const uint16_t*)(ws + off_i11) + (size_t)(b * NN + n) * SS;

  float p1o = p2t[(size_t)(b * NN + n) * 64 + o];
  float qx = x1f[n], qy = x1f[NN + n], qz = x1f[2 * NN + n];
  if (o < 16) {
    int j = (int)idx11[o];
    idxs[w][o] = j;
    float dx = __fsub_rn(qx, x1f[j]);
    float dy = __fsub_rn(qy, x1f[NN + j]);
    float dz = __fsub_rn(qz, x1f[2 * NN + j]);
    xds[w][o * 4 + 0] = dx; xds[w][o * 4 + 1] = dy; xds[w][o * 4 + 2] = dz;
    xds[w][o * 4 + 3] = sqrtf(dx * dx + dy * dy + dz * dz);
  }
  __syncthreads();   // staging barrier; below: registers/shfl/read-only LDS

  // u[o] = (Wk2^T Wq2).pts via broadcast shuffles
  float u0 = 0.f, u1 = 0.f, u2 = 0.f, u3 = 0.f;
#pragma unroll
  for (int c = 0; c < 64; c += 4) {
    u0 = fmaf(s_C2[c * 64 + o],       __shfl(p1o, c),     u0);
    u1 = fmaf(s_C2[(c + 1) * 64 + o], __shfl(p1o, c + 1), u1);
    u2 = fmaf(s_C2[(c + 2) * 64 + o], __shfl(p1o, c + 2), u2);
    u3 = fmaf(s_C2[(c + 3) * 64 + o], __shfl(p1o, c + 3), u3);
  }
  float u = (u0 + u1) + (u2 + u3);
  float w4x = u * s_wp2t[o];
  float w4y = u * s_wp2t[64 + o];
  float w4z = u * s_wp2t[128 + o];
  float w4n = u * s_wp2t[192 + o];
  float ubp = u * s_bp2[o];
#pragma unroll
  for (int msk = 1; msk < 64; msk <<= 1) {
    w4x += __shfl_xor(w4x, msk);
    w4y += __shfl_xor(w4y, msk);
    w4z += __shfl_xor(w4z, msk);
    w4n += __shfl_xor(w4n, msk);
    ubp += __shfl_xor(ubp, msk);
  }

  float lg[16];
#pragma unroll 1
  for (int s = 0; s < SS; ++s) {
    int j = idxs[w][s];
    float nb = p2t[(size_t)(b * NN + j) * 64 + o];
    float t = u * nb;
#pragma unroll
    for (int msk = 1; msk < 64; msk <<= 1) t += __shfl_xor(t, msk);
    float dx = xds[w][s * 4 + 0], dy = xds[w][s * 4 + 1], dz = xds[w][s * 4 + 2], xn = xds[w][s * 4 + 3];
    float logit = t;
    logit = fmaf(w4x, dx, logit);
    logit = fmaf(w4y, dy, logit);
    logit = fmaf(w4z, dz, logit);
    logit = fmaf(w4n, xn, logit);
    lg[s] = (logit + ubp) * 0.125f;   // identical in all lanes
  }
  {
    float mx = lg[0];
#pragma unroll
    for (int s = 1; s < SS; ++s) mx = fmaxf(mx, lg[s]);
    float sum = 0.f;
#pragma unroll
    for (int s = 0; s < SS; ++s) { lg[s] = __expf(lg[s] - mx); sum += lg[s]; }
    float inv = 1.f / sum;
#pragma unroll
    for (int s = 0; s < SS; ++s) lg[s] *= inv;
  }
  float nbacc = 0.f;
#pragma unroll 1
  for (int s = 0; s < SS; ++s) {
    int j = idxs[w][s];
    nbacc = fmaf(lg[s], p2t[(size_t)(b * NN + j) * 64 + o], nbacc);
  }
  float o0 = 0.f, o1 = 0.f, o2 = 0.f, o3 = 0.f;
#pragma unroll
  for (int c = 0; c < 64; c += 4) {
    o0 = fmaf(s_wv2[c * 64 + o],       __shfl(nbacc, c),     o0);
    o1 = fmaf(s_wv2[(c + 1) * 64 + o], __shfl(nbacc, c + 1), o1);
    o2 = fmaf(s_wv2[(c + 2) * 64 + o], __shfl(nbacc, c + 2), o2);
    o3 = fmaf(s_wv2[(c + 3) * 64 + o], __shfl(nbacc, c + 3), o3);
  }
  float acc = (o0 + o1) + (o2 + o3);
  float res = acc >= 0.f ? acc : 0.1f * acc;
  souts[w][o] = res;
  __syncthreads();   // cross-wave transpose staging
  int c = tid >> 3, nr = tid & 7;
  int n0 = (blockIdx.x * 8) & (NN - 1);
  int b0 = (blockIdx.x * 8) >> 12;
  size_t oi = (size_t)(b0 * 64 + c) * NN + n0 + nr;
  float ov = souts[nr][c];
  if (f32m) ((float*)outp)[oi] = ov;
  else      ((uint16_t*)outp)[oi] = f2bf(ov);
}

extern "C" void kernel_launch(void* const* d_in, const int* in_sizes, int n_in,
                              void* d_out, int out_size, void* d_ws, size_t ws_size,
                              hipStream_t stream) {
  const void* xyz1 = d_in[0];
  const void* feat1 = d_in[1];
  const void* xyz2 = d_in[2];
  const void* feat2 = d_in[3];
  const void* w_q1 = d_in[4];
  const void* w_k1 = d_in[5];
  const void* w_v1 = d_in[6];
  const void* w_mlp1 = d_in[7];
  const void* w_mlp2 = d_in[8];
  const void* w_pos1 = d_in[9];
  const void* b_pos1 = d_in[10];
  const void* w_q2 = d_in[11];
  const void* w_k2 = d_in[12];
  const void* w_v2 = d_in[13];
  const void* w_pos2 = d_in[14];
  const void* b_pos2 = d_in[15];
  u16p probe = (u16p)d_in[1];
  float* ws = (float*)d_ws;

  if (ws_size < WS_MIN_FLOATS * 4ull) return;

  int big = (ws_size >= 2490368ull * 4ull) ? 1 : 0;
  int f2cap   = big;
  int off_p2n = big ? 1179648 : 655360;
  int off_i12 = big ? 2228224 : 1703936;
  int off_i11 = big ? 2359296 : 1835008;

  hipLaunchKernelGGL(k_prep_xyz, dim3(64), dim3(256), 0, stream, xyz1, xyz2, probe, ws);
  hipLaunchKernelGGL(k_transpose, dim3(256), dim3(256), 0, stream, feat2, probe, ws, f2cap);
  hipLaunchKernelGGL(k_knn, dim3(8192), dim3(256), 0, stream, ws, off_i12, off_i11);
  hipLaunchKernelGGL(k_fold, dim3(2), dim3(256), 0, stream,
                     w_q1, w_k1, w_v1, w_mlp1, w_pos1, b_pos1, w_q2, w_k2, probe, ws);
  hipLaunchKernelGGL(k_group1, dim3(2048), dim3(512), 0, stream,
                     feat1, w_v1, w_mlp2, probe, ws, off_p2n, off_i12, f2cap);
  hipLaunchKernelGGL(k_group2, dim3(2048), dim3(512), 0, stream,
                     w_v2, w_pos2, b_pos2, probe, ws, d_out, off_p2n, off_i11);
}

// Round 8
// 600.475 us; speedup vs baseline: 2.9027x; 1.0626x over previous
//
#include <hip/hip_runtime.h>
#include <stdint.h>

#define NN 4096
#define SS 16

// fixed ws float offsets
#define OFF_XYZ1F 0          // 4*3*4096 f32
#define OFF_XYZ2F 49152      // 4*3*4096 f32
#define OFF_N1    98304      // 4*4096 f32 (dead after knn -> nb2 of feat2 points)
#define OFF_N2    114688     // 4*4096 f32 (dead after knn -> folds)
#define OFF_F2T   131072     // feat2 transpose [b][n][c]: u16 (compact) or f32 (big)
#define WS_MIN_FLOATS 1966080ull

// fold outputs (dead-after-knn regions, written by k_fold AFTER k_knn)
#define OFF_NB2 98304    // ||feat2[b][:,n]||^2, 16384 floats (over N1)
#define OFF_A2  114688   // (W1Wq - M*Wva)  [c][h] 1024
#define OFF_G   115712   // (M*Wvb)         [c][h] 1024
#define OFF_P5  116736   // [p][h] 80
#define OFF_MBP 116816   // M*bp1 [h] 16
#define OFF_C2  116832   // Wk2^T*Wq2 [c][o] 4096

typedef const uint16_t* u16p;

__device__ __forceinline__ float bf2f(uint16_t u) {
  return __uint_as_float(((uint32_t)u) << 16);
}
__device__ __forceinline__ uint16_t f2bf(float f) {
  uint32_t x = __float_as_uint(f);
  uint32_t r = (x + 0x7FFFu + ((x >> 16) & 1u)) >> 16;
  return (uint16_t)r;
}
__device__ __forceinline__ float ldi(const void* p, int i, int f32m) {
  return f32m ? ((const float*)p)[i] : bf2f(((const uint16_t*)p)[i]);
}
__device__ __forceinline__ int detect_f32(const uint16_t* probe) {
  int lane = threadIdx.x & 63;
  float a = bf2f(probe[lane]);
  float b = bf2f(probe[lane + 64]);
  int bad = (!(fabsf(a) <= 1e4f)) || (!(fabsf(b) <= 1e4f));
  return __any(bad) ? 1 : 0;
}

// ---------------- prep ----------------
__global__ __launch_bounds__(256) void k_prep_xyz(const void* xyz1, const void* xyz2,
                                                  u16p probe, float* ws) {
  int f32m = detect_f32(probe);
  int t = blockIdx.x * 256 + threadIdx.x;
  int b = t >> 12, n = t & (NN - 1);
  int base = b * 3 * NN + n;
  float x1 = ldi(xyz1, base, f32m), y1 = ldi(xyz1, base + NN, f32m), z1 = ldi(xyz1, base + 2 * NN, f32m);
  float x2 = ldi(xyz2, base, f32m), y2 = ldi(xyz2, base + NN, f32m), z2 = ldi(xyz2, base + 2 * NN, f32m);
  float* x1f = ws + OFF_XYZ1F;
  float* x2f = ws + OFF_XYZ2F;
  x1f[base] = x1; x1f[base + NN] = y1; x1f[base + 2 * NN] = z1;
  x2f[base] = x2; x2f[base + NN] = y2; x2f[base + 2 * NN] = z2;
  ws[OFF_N1 + t] = __fadd_rn(__fadd_rn(__fmul_rn(x1, x1), __fmul_rn(y1, y1)), __fmul_rn(z1, z1));
  ws[OFF_N2 + t] = __fadd_rn(__fadd_rn(__fmul_rn(x2, x2), __fmul_rn(y2, y2)), __fmul_rn(z2, z2));
}

// ---------------- transpose feat2 ----------------
__global__ __launch_bounds__(256) void k_transpose(const void* feat2, u16p probe,
                                                   float* ws, int f2cap) {
  __shared__ float tile[64][65];
  int f32m = detect_f32(probe);
  int b = blockIdx.x >> 6;
  int n0 = (blockIdx.x & 63) * 64;
  int tx = threadIdx.x & 63, ty = threadIdx.x >> 6;
#pragma unroll
  for (int i = 0; i < 16; ++i) {
    int c = i * 4 + ty;
    tile[c][tx] = ldi(feat2, (b * 64 + c) * NN + n0 + tx, f32m);
  }
  __syncthreads();
#pragma unroll
  for (int i = 0; i < 16; ++i) {
    int nl = i * 4 + ty;
    size_t di = (size_t)(b * NN + n0 + nl) * 64 + tx;
    float v = tile[tx][nl];
    if (f2cap) ((float*)(ws + OFF_F2T))[di] = v;
    else       ((uint16_t*)(ws + OFF_F2T))[di] = f2bf(v);
  }
}

// ---------------- KNN: wave-per-query, subsample-threshold filter ----------------
#define KCAP 320
__device__ __forceinline__ float knn_dist(const float* cx, const float* cn,
                                          float qx, float qy, float qz, float q2, int j) {
  float cross = __fadd_rn(__fadd_rn(__fmul_rn(qx, cx[j]), __fmul_rn(qy, cx[NN + j])),
                          __fmul_rn(qz, cx[2 * NN + j]));
  return __fsub_rn(__fadd_rn(q2, cn[j]), __fmul_rn(2.0f, cross));
}

__global__ __launch_bounds__(256) void k_knn(float* ws, int off_i12, int off_i11) {
  __shared__ float sd[4][KCAP];
  __shared__ int   si[4][KCAP];
  __shared__ int   eqbuf[4][16];

  int tid = threadIdx.x;
  int wv = tid >> 6, lane = tid & 63;
  int q = blockIdx.x * 4 + wv;
  int which = q >> 14;
  int b = (q >> 12) & 3;
  int n = q & (NN - 1);

  const float* cx = ws + (which ? OFF_XYZ1F : OFF_XYZ2F) + b * 3 * NN;
  const float* cn = ws + (which ? OFF_N1 : OFF_N2) + b * NN;
  const float* qp = ws + OFF_XYZ1F + b * 3 * NN;
  float qx = qp[n], qy = qp[NN + n], qz = qp[2 * NN + n];
  float q2 = ws[OFF_N1 + b * NN + n];
  const float INF = __builtin_inff();

  float mn = INF;
#pragma unroll 4
  for (int i = 0; i < 16; ++i) {
    float d = knn_dist(cx, cn, qx, qy, qz, q2, i * 64 + lane);
    mn = fminf(mn, d);
  }
  float tau0 = 0.f;
  {
    float h = mn;
#pragma unroll 1
    for (int r = 0; r < 16; ++r) {
      float m = h;
#pragma unroll
      for (int msk = 1; msk < 64; msk <<= 1) m = fminf(m, __shfl_xor(m, msk));
      if (r == 15) tau0 = m;
      unsigned long long win = __ballot(h == m);
      int winner = __ffsll(win) - 1;
      if (lane == winner) h = INF;
    }
  }

  unsigned long long below = (1ull << lane) - 1ull;
  int c = 0;
#pragma unroll 2
  for (int i = 0; i < 64; ++i) {
    int j = i * 64 + lane;
    float d = knn_dist(cx, cn, qx, qy, qz, q2, j);
    bool sel = (d <= tau0);
    unsigned long long msk = __ballot(sel);
    int pos = c + __popcll(msk & below);
    if (sel && pos < KCAP) { sd[wv][pos] = d; si[wv][pos] = j; }
    c += __popcll(msk);
  }
  if (c > KCAP) c = KCAP;   // ~e^-50 event; clamp for safety
  __syncthreads();

  float ch[5];
#pragma unroll
  for (int t = 0; t < 5; ++t) ch[t] = INF;
#pragma unroll
  for (int t = 0; t < 5; ++t) {
    int p = t * 64 + lane;
    float x = (p < c) ? sd[wv][p] : INF;
#pragma unroll
    for (int u = 0; u < 5; ++u) {
      float lo = fminf(ch[u], x);
      x = fmaxf(ch[u], x);
      ch[u] = lo;
    }
  }
  float tau = 0.f;
  {
    float h = ch[0];
#pragma unroll 1
    for (int r = 0; r < 16; ++r) {
      float m = h;
#pragma unroll
      for (int msk = 1; msk < 64; msk <<= 1) m = fminf(m, __shfl_xor(m, msk));
      if (r == 15) tau = m;
      unsigned long long win = __ballot(h == m);
      int winner = __ffsll(win) - 1;
      if (lane == winner) {
        ch[0] = ch[1]; ch[1] = ch[2]; ch[2] = ch[3]; ch[3] = ch[4]; ch[4] = INF;
        h = ch[0];
      }
    }
  }

  uint16_t* outp = (uint16_t*)(ws + (which ? off_i11 : off_i12)) + (size_t)(b * NN + n) * SS;
  int c1 = 0, eqc = 0;
#pragma unroll
  for (int t = 0; t < 5; ++t) {
    int p = t * 64 + lane;
    bool act = (p < c);
    float d = act ? sd[wv][p] : INF;
    int j = act ? si[wv][p] : 0;
    bool lt = act && (d < tau);
    bool eq = act && (d == tau);
    unsigned long long mlt = __ballot(lt);
    unsigned long long meq = __ballot(eq);
    int pl = __popcll(mlt & below);
    if (lt) outp[c1 + pl] = (uint16_t)j;
    int pe = __popcll(meq & below);
    if (eq && (eqc + pe) < 16) eqbuf[wv][eqc + pe] = j;
    c1 += __popcll(mlt);
    eqc += __popcll(meq);
  }
  __syncthreads();
  int need = 16 - c1;
  if (lane < need) outp[c1 + lane] = (uint16_t)eqbuf[wv][lane];
}

// ---------------- fold: algebraic precomputes + feat2 norms (66 blocks) ----------------
__global__ __launch_bounds__(256) void k_fold(
    const void* w_q1, const void* w_k1, const void* w_v1, const void* w_mlp1,
    const void* w_pos1, const void* b_pos1, const void* w_q2, const void* w_k2,
    u16p probe, float* ws, int f2cap) {
  int f32m = detect_f32(probe);
  int tid = threadIdx.x;

  if (blockIdx.x >= 2) {
    // nb2[p] = sum_c feat2T[p][c]^2  (p = b*4096+n), over dead N1 region
    int p = (blockIdx.x - 2) * 256 + tid;
    const float* f2f32 = (const float*)(ws + OFF_F2T);
    const uint16_t* f2u16 = (const uint16_t*)(ws + OFF_F2T);
    size_t row = (size_t)p * 64;
    float acc = 0.f;
#pragma unroll 8
    for (int c = 0; c < 64; ++c) {
      float v = f2cap ? f2f32[row + c] : bf2f(f2u16[row + c]);
      acc = fmaf(v, v, acc);
    }
    ws[OFF_NB2 + p] = acc;
    return;
  }

  __shared__ float lA[4096];
  __shared__ float lB[2048];   // lW1[0:1024], lM[1024:2048]
  if (blockIdx.x == 1) {
    __shared__ float lQ[4096];
    for (int i = tid; i < 4096; i += 256) { lA[i] = ldi(w_k2, i, f32m); lQ[i] = ldi(w_q2, i, f32m); }
    __syncthreads();
    for (int i = tid; i < 4096; i += 256) {
      int c = i >> 6, o = i & 63;
      float a0 = 0.f, a1 = 0.f, a2 = 0.f, a3 = 0.f;
      for (int a = 0; a < 64; a += 4) {
        a0 = fmaf(lA[a * 64 + o],       lQ[a * 64 + c],       a0);
        a1 = fmaf(lA[(a + 1) * 64 + o], lQ[(a + 1) * 64 + c], a1);
        a2 = fmaf(lA[(a + 2) * 64 + o], lQ[(a + 2) * 64 + c], a2);
        a3 = fmaf(lA[(a + 3) * 64 + o], lQ[(a + 3) * 64 + c], a3);
      }
      ws[OFF_C2 + i] = (a0 + a1) + (a2 + a3);
    }
    return;
  }

  float* lW1 = lB;
  float* lM  = lB + 1024;
  for (int i = tid; i < 1024; i += 256) lW1[i] = ldi(w_mlp1, i, f32m);   // [h][m]
  for (int i = tid; i < 4096; i += 256) lA[i] = ldi(w_k1, i, f32m);      // [m][o]
  __syncthreads();
  for (int i = tid; i < 1024; i += 256) {       // M[h][o] = W1.Wk
    int hh = i >> 6, o = i & 63;
    float acc = 0.f;
    for (int m = 0; m < 64; ++m) acc = fmaf(lW1[hh * 64 + m], lA[m * 64 + o], acc);
    lM[i] = acc;
  }
  __syncthreads();
  float a2acc[4];
  for (int i = tid; i < 4096; i += 256) lA[i] = ldi(w_q1, i, f32m);      // [o][c]
  __syncthreads();
  for (int k = 0; k < 4; ++k) {
    int i = tid + k * 256;
    int c = i >> 4, hh = i & 15;
    float acc = 0.f;
    for (int o = 0; o < 64; ++o) acc = fmaf(lW1[hh * 64 + o], lA[o * 64 + c], acc);
    a2acc[k] = acc;
  }
  __syncthreads();
  for (int i = tid; i < 4096; i += 256) { int o = i >> 6, c = i & 63; lA[o * 64 + c] = ldi(w_v1, o * 131 + c, f32m); }
  __syncthreads();
  for (int k = 0; k < 4; ++k) {
    int i = tid + k * 256;
    int c = i >> 4, hh = i & 15;
    float acc = 0.f;
    for (int o = 0; o < 64; ++o) acc = fmaf(lM[hh * 64 + o], lA[o * 64 + c], acc);
    ws[OFF_A2 + i] = a2acc[k] - acc;
  }
  __syncthreads();
  for (int i = tid; i < 4096; i += 256) { int o = i >> 6, c = i & 63; lA[o * 64 + c] = ldi(w_v1, o * 131 + 64 + c, f32m); }
  __syncthreads();
  for (int i = tid; i < 1024; i += 256) {       // G[c][h] = M*Wvb
    int c = i >> 4, hh = i & 15;
    float acc = 0.f;
    for (int o = 0; o < 64; ++o) acc = fmaf(lM[hh * 64 + o], lA[o * 64 + c], acc);
    ws[OFF_G + i] = acc;
  }
  if (tid < 16) {
    int hh = tid;
    float p0 = 0.f, p1 = 0.f, p2 = 0.f, p3 = 0.f, p4 = 0.f, pb = 0.f;
    for (int o = 0; o < 64; ++o) {
      float m = lM[hh * 64 + o];
      p0 = fmaf(m, ldi(w_pos1, o * 5 + 0, f32m), p0);
      p1 = fmaf(m, ldi(w_pos1, o * 5 + 1, f32m), p1);
      p2 = fmaf(m, ldi(w_v1, o * 131 + 128, f32m) + ldi(w_pos1, o * 5 + 2, f32m), p2);
      p3 = fmaf(m, ldi(w_v1, o * 131 + 129, f32m) + ldi(w_pos1, o * 5 + 3, f32m), p3);
      p4 = fmaf(m, ldi(w_v1, o * 131 + 130, f32m) + ldi(w_pos1, o * 5 + 4, f32m), p4);
      pb = fmaf(m, ldi(b_pos1, o, f32m), pb);
    }
    ws[OFF_P5 + hh] = p0; ws[OFF_P5 + 16 + hh] = p1; ws[OFF_P5 + 32 + hh] = p2;
    ws[OFF_P5 + 48 + hh] = p3; ws[OFF_P5 + 64 + hh] = p4;
    ws[OFF_MBP + hh] = pb;
  }
}

// ---------------- group1: folded + online softmax + expanded feat-norm ----------------
__global__ __launch_bounds__(512, 4) void k_group1(
    const void* feat1, const void* w_v1, const void* w_mlp2,
    u16p probe, float* ws, int off_p2n, int off_i12, int f2cap) {
  __shared__ float s_wva[4096];    // [c][o]
  __shared__ float s_wvb[4096];    // [c][o]
  __shared__ float s_wvx[192];
  __shared__ float s_A2[1088];     // [c*17+h] padded (kills 4-way bank conflict)
  __shared__ float s_G[1088];      // [c*17+h] padded
  __shared__ float s_P5[80];
  __shared__ float s_MBP[16];
  __shared__ float s_w2[16];
  __shared__ float f1s[8][64];     // pre-barrier write, read-only after
  __shared__ float xds[8][64];
  __shared__ float snb2[8][16];
  __shared__ int   idxs[8][16];

  int f32m = detect_f32(probe);
  int tid = threadIdx.x;
  for (int i = tid; i < 4096; i += 512) {
    int c = i >> 6, o = i & 63;
    s_wva[i] = ldi(w_v1, o * 131 + c, f32m);
    s_wvb[i] = ldi(w_v1, o * 131 + 64 + c, f32m);
  }
  if (tid < 192) { int j = tid >> 6, o = tid & 63; s_wvx[tid] = ldi(w_v1, o * 131 + 128 + j, f32m); }
  for (int i = tid; i < 1024; i += 512) {
    int c = i >> 4, h = i & 15;
    s_A2[c * 17 + h] = ws[OFF_A2 + i];
    s_G[c * 17 + h] = ws[OFF_G + i];
  }
  if (tid < 80) s_P5[tid] = ws[OFF_P5 + tid];
  if (tid < 16) { s_MBP[tid] = ws[OFF_MBP + tid]; s_w2[tid] = ldi(w_mlp2, tid, f32m); }

  int w = tid >> 6, o = tid & 63;
  int g = blockIdx.x * 8 + w;
  int b = g >> 12, n = g & (NN - 1);
  const float* x1f = ws + OFF_XYZ1F + b * 3 * NN;
  const float* x2f = ws + OFF_XYZ2F + b * 3 * NN;
  const uint16_t* idx12 = (const uint16_t*)(ws + off_i12) + (size_t)(b * NN + n) * SS;
  const float* f2f32 = (const float*)(ws + OFF_F2T);
  const uint16_t* f2u16 = (const uint16_t*)(ws + OFF_F2T);

  float f1o = ldi(feat1, (b * 64 + o) * NN + n, f32m);
  f1s[w][o] = f1o;
  float qx = x1f[n], qy = x1f[NN + n], qz = x1f[2 * NN + n];
  if (o < 16) {
    int j = (int)idx12[o];
    idxs[w][o] = j;
    float dx = __fsub_rn(qx, x2f[j]);
    float dy = __fsub_rn(qy, x2f[NN + j]);
    float dz = __fsub_rn(qz, x2f[2 * NN + j]);
    xds[w][o * 4 + 0] = dx; xds[w][o * 4 + 1] = dy; xds[w][o * 4 + 2] = dz;
    xds[w][o * 4 + 3] = sqrtf(dx * dx + dy * dy + dz * dz);
    snb2[w][o] = ws[OFF_NB2 + b * NN + j];
  }
  __syncthreads();   // only block barrier; below: regs/shfl/read-only LDS

  int h = o & 15, part = o >> 4;
  // f1n2 = ||f1||^2 (once per query)
  float f1n2 = f1o * f1o;
#pragma unroll
  for (int msk = 1; msk < 64; msk <<= 1) f1n2 += __shfl_xor(f1n2, msk);
  // vb[o] = Wva.pts (LDS-broadcast reads of f1)
  float v0 = 0.f, v1 = 0.f, v2 = 0.f, v3 = 0.f;
#pragma unroll
  for (int c = 0; c < 64; c += 4) {
    v0 = fmaf(s_wva[c * 64 + o],       f1s[w][c],     v0);
    v1 = fmaf(s_wva[(c + 1) * 64 + o], f1s[w][c + 1], v1);
    v2 = fmaf(s_wva[(c + 2) * 64 + o], f1s[w][c + 2], v2);
    v3 = fmaf(s_wva[(c + 3) * 64 + o], f1s[w][c + 3], v3);
  }
  float vb = (v0 + v1) + (v2 + v3);
  // tb[h] = (A2.pts)[h] - MBP[h]
  float tb = 0.f;
#pragma unroll
  for (int i = 0; i < 16; ++i) {
    int c = part * 16 + i;
    tb = fmaf(s_A2[c * 17 + h], f1s[w][c], tb);
  }
  tb += __shfl_xor(tb, 16);
  tb += __shfl_xor(tb, 32);
  tb -= s_MBP[h];

  // online softmax state
  float m = -__builtin_inff(), l = 0.f;
  float anb = 0.f, axa = 0.f, aya = 0.f, aza = 0.f;
#pragma unroll 2
  for (int s = 0; s < SS; ++s) {
    int j = idxs[w][s];
    size_t fi = (size_t)(b * NN + j) * 64 + o;
    float nb = f2cap ? f2f32[fi] : bf2f(f2u16[fi]);
    float gl = 0.f, dp = 0.f;
#pragma unroll
    for (int i = 0; i < 16; ++i) {
      int c = part * 16 + i;
      float nbb = __shfl(nb, c);
      gl = fmaf(s_G[c * 17 + h], nbb, gl);
      dp = fmaf(f1s[w][c], nbb, dp);
    }
    gl += __shfl_xor(gl, 16); dp += __shfl_xor(dp, 16);
    gl += __shfl_xor(gl, 32); dp += __shfl_xor(dp, 32);
    float ssq = fmaxf(f1n2 - 2.f * dp + snb2[w][s], 0.f);
    float fn = sqrtf(ssq);
    float dx = xds[w][s * 4 + 0], dy = xds[w][s * 4 + 1], dz = xds[w][s * 4 + 2], xn = xds[w][s * 4 + 3];
    float p5 = s_P5[h] * fn;
    p5 = fmaf(s_P5[16 + h], xn, p5);
    p5 = fmaf(s_P5[32 + h], dx, p5);
    p5 = fmaf(s_P5[48 + h], dy, p5);
    p5 = fmaf(s_P5[64 + h], dz, p5);
    float t = tb - gl - p5;
    float r = fmaxf(t, 0.f) * s_w2[h];
    r += __shfl_xor(r, 1);
    r += __shfl_xor(r, 2);
    r += __shfl_xor(r, 4);
    r += __shfl_xor(r, 8);   // logit, identical in all lanes
    // online update
    float mn = fmaxf(m, r);
    float sc = __expf(m - mn);
    float e = __expf(r - mn);
    l = l * sc + e;
    anb = anb * sc + e * nb;
    axa = axa * sc + e * dx;
    aya = aya * sc + e * dy;
    aza = aza * sc + e * dz;
    m = mn;
  }
  float invl = 1.f / l;
  anb *= invl; axa *= invl; aya *= invl; aza *= invl;
  // out = vb + Wvb.anb + Wvx.(axa,aya,aza)
  float o0 = vb, o1 = 0.f, o2 = 0.f, o3 = 0.f;
#pragma unroll
  for (int c = 0; c < 64; c += 4) {
    o0 = fmaf(s_wvb[c * 64 + o],       __shfl(anb, c),     o0);
    o1 = fmaf(s_wvb[(c + 1) * 64 + o], __shfl(anb, c + 1), o1);
    o2 = fmaf(s_wvb[(c + 2) * 64 + o], __shfl(anb, c + 2), o2);
    o3 = fmaf(s_wvb[(c + 3) * 64 + o], __shfl(anb, c + 3), o3);
  }
  float acc = (o0 + o1) + (o2 + o3);
  acc = fmaf(s_wvx[o], axa, acc);
  acc = fmaf(s_wvx[64 + o], aya, acc);
  acc = fmaf(s_wvx[128 + o], aza, acc);
  float res = acc >= 0.f ? acc : 0.1f * acc;   // leaky 0.1
  ws[off_p2n + (size_t)(b * NN + n) * 64 + o] = res;
}

// ---------------- group2: folded + online softmax, part-slice dot ----------------
__global__ __launch_bounds__(512, 4) void k_group2(
    const void* w_v2, const void* w_pos2, const void* b_pos2,
    u16p probe, float* ws, void* outp, int off_p2n, int off_i11) {
  __shared__ float s_C2[4096];    // [c][o]
  __shared__ float s_wv2[4096];   // [c][o]
  __shared__ float s_wp2t[256];   // [p][o]
  __shared__ float s_bp2[64];
  __shared__ float xds[8][64];
  __shared__ int   idxs[8][16];
  __shared__ float souts[8][64];

  int f32m = detect_f32(probe);
  int tid = threadIdx.x;
  for (int i = tid; i < 4096; i += 512) {
    int c = i >> 6, o = i & 63;
    s_C2[i] = ws[OFF_C2 + i];
    s_wv2[i] = ldi(w_v2, o * 64 + c, f32m);
  }
  if (tid < 256) { int p = tid >> 6, o = tid & 63; s_wp2t[p * 64 + o] = ldi(w_pos2, o * 4 + p, f32m); }
  if (tid < 64) s_bp2[tid] = ldi(b_pos2, tid, f32m);

  int w = tid >> 6, o = tid & 63;
  int g = blockIdx.x * 8 + w;
  int b = g >> 12, n = g & (NN - 1);
  const float* p2t = ws + off_p2n;
  const float* x1f = ws + OFF_XYZ1F + b * 3 * NN;
  const uint16_t* idx11 = (const uint16_t*)(ws + off_i11) + (size_t)(b * NN + n) * SS;

  float p1o = p2t[(size_t)(b * NN + n) * 64 + o];
  float qx = x1f[n], qy = x1f[NN + n], qz = x1f[2 * NN + n];
  if (o < 16) {
    int j = (int)idx11[o];
    idxs[w][o] = j;
    float dx = __fsub_rn(qx, x1f[j]);
    float dy = __fsub_rn(qy, x1f[NN + j]);
    float dz = __fsub_rn(qz, x1f[2 * NN + j]);
    xds[w][o * 4 + 0] = dx; xds[w][o * 4 + 1] = dy; xds[w][o * 4 + 2] = dz;
    xds[w][o * 4 + 3] = sqrtf(dx * dx + dy * dy + dz * dz);
  }
  __syncthreads();

  int part = o >> 4;
  // u[o] = (Wk2^T Wq2).pts  via shfl broadcasts of p1o
  float u0 = 0.f, u1 = 0.f, u2 = 0.f, u3 = 0.f;
#pragma unroll
  for (int c = 0; c < 64; c += 4) {
    u0 = fmaf(s_C2[c * 64 + o],       __shfl(p1o, c),     u0);
    u1 = fmaf(s_C2[(c + 1) * 64 + o], __shfl(p1o, c + 1), u1);
    u2 = fmaf(s_C2[(c + 2) * 64 + o], __shfl(p1o, c + 2), u2);
    u3 = fmaf(s_C2[(c + 3) * 64 + o], __shfl(p1o, c + 3), u3);
  }
  float u = (u0 + u1) + (u2 + u3);
  float w4x = u * s_wp2t[o];
  float w4y = u * s_wp2t[64 + o];
  float w4z = u * s_wp2t[128 + o];
  float w4n = u * s_wp2t[192 + o];
  float ubp = u * s_bp2[o];
#pragma unroll
  for (int msk = 1; msk < 64; msk <<= 1) {
    w4x += __shfl_xor(w4x, msk);
    w4y += __shfl_xor(w4y, msk);
    w4z += __shfl_xor(w4z, msk);
    w4n += __shfl_xor(w4n, msk);
    ubp += __shfl_xor(ubp, msk);
  }
  // pre-shuffle u into this lane's c-slice (16 regs, reused all s)
  float u16r[16];
#pragma unroll
  for (int i = 0; i < 16; ++i) u16r[i] = __shfl(u, part * 16 + i);

  float m = -__builtin_inff(), l = 0.f, anb = 0.f;
#pragma unroll 2
  for (int s = 0; s < SS; ++s) {
    int j = idxs[w][s];
    float nb = p2t[(size_t)(b * NN + j) * 64 + o];
    float tp = 0.f;
#pragma unroll
    for (int i = 0; i < 16; ++i) tp = fmaf(u16r[i], __shfl(nb, part * 16 + i), tp);
    tp += __shfl_xor(tp, 16);
    tp += __shfl_xor(tp, 32);   // full dot, all lanes
    float dx = xds[w][s * 4 + 0], dy = xds[w][s * 4 + 1], dz = xds[w][s * 4 + 2], xn = xds[w][s * 4 + 3];
    float logit = tp;
    logit = fmaf(w4x, dx, logit);
    logit = fmaf(w4y, dy, logit);
    logit = fmaf(w4z, dz, logit);
    logit = fmaf(w4n, xn, logit);
    logit = (logit + ubp) * 0.125f;
    float mn = fmaxf(m, logit);
    float sc = __expf(m - mn);
    float e = __expf(logit - mn);
    l = l * sc + e;
    anb = anb * sc + e * nb;
    m = mn;
  }
  anb *= 1.f / l;
  float o0 = 0.f, o1 = 0.f, o2 = 0.f, o3 = 0.f;
#pragma unroll
  for (int c = 0; c < 64; c += 4) {
    o0 = fmaf(s_wv2[c * 64 + o],       __shfl(anb, c),     o0);
    o1 = fmaf(s_wv2[(c + 1) * 64 + o], __shfl(anb, c + 1), o1);
    o2 = fmaf(s_wv2[(c + 2) * 64 + o], __shfl(anb, c + 2), o2);
    o3 = fmaf(s_wv2[(c + 3) * 64 + o], __shfl(anb, c + 3), o3);
  }
  float acc = (o0 + o1) + (o2 + o3);
  float res = acc >= 0.f ? acc : 0.1f * acc;
  souts[w][o] = res;
  __syncthreads();   // cross-wave transpose staging
  int c = tid >> 3, nr = tid & 7;
  int n0 = (blockIdx.x * 8) & (NN - 1);
  int b0 = (blockIdx.x * 8) >> 12;
  size_t oi = (size_t)(b0 * 64 + c) * NN + n0 + nr;
  float ov = souts[nr][c];
  if (f32m) ((float*)outp)[oi] = ov;
  else      ((uint16_t*)outp)[oi] = f2bf(ov);
}

extern "C" void kernel_launch(void* const* d_in, const int* in_sizes, int n_in,
                              void* d_out, int out_size, void* d_ws, size_t ws_size,
                              hipStream_t stream) {
  const void* xyz1 = d_in[0];
  const void* feat1 = d_in[1];
  const void* xyz2 = d_in[2];
  const void* feat2 = d_in[3];
  const void* w_q1 = d_in[4];
  const void* w_k1 = d_in[5];
  const void* w_v1 = d_in[6];
  const void* w_mlp1 = d_in[7];
  const void* w_mlp2 = d_in[8];
  const void* w_pos1 = d_in[9];
  const void* b_pos1 = d_in[10];
  const void* w_q2 = d_in[11];
  const void* w_k2 = d_in[12];
  const void* w_v2 = d_in[13];
  const void* w_pos2 = d_in[14];
  const void* b_pos2 = d_in[15];
  u16p probe = (u16p)d_in[1];
  float* ws = (float*)d_ws;

  if (ws_size < WS_MIN_FLOATS * 4ull) return;

  int big = (ws_size >= 2490368ull * 4ull) ? 1 : 0;
  int f2cap   = big;
  int off_p2n = big ? 1179648 : 655360;
  int off_i12 = big ? 2228224 : 1703936;
  int off_i11 = big ? 2359296 : 1835008;

  hipLaunchKernelGGL(k_prep_xyz, dim3(64), dim3(256), 0, stream, xyz1, xyz2, probe, ws);
  hipLaunchKernelGGL(k_transpose, dim3(256), dim3(256), 0, stream, feat2, probe, ws, f2cap);
  hipLaunchKernelGGL(k_knn, dim3(8192), dim3(256), 0, stream, ws, off_i12, off_i11);
  hipLaunchKernelGGL(k_fold, dim3(66), dim3(256), 0, stream,
                     w_q1, w_k1, w_v1, w_mlp1, w_pos1, b_pos1, w_q2, w_k2, probe, ws, f2cap);
  hipLaunchKernelGGL(k_group1, dim3(2048), dim3(512), 0, stream,
                     feat1, w_v1, w_mlp2, probe, ws, off_p2n, off_i12, f2cap);
  hipLaunchKernelGGL(k_group2, dim3(2048), dim3(512), 0, stream,
                     w_v2, w_pos2, b_pos2, probe, ws, d_out, off_p2n, off_i11);
}

// Round 9
// 573.058 us; speedup vs baseline: 3.0416x; 1.0478x over previous
//
#include <hip/hip_runtime.h>
#include <stdint.h>

#define NN 4096
#define SS 16

// fixed ws float offsets
#define OFF_XYZ1F 0          // 4*3*4096 f32
#define OFF_XYZ2F 49152      // 4*3*4096 f32
#define OFF_N1    98304      // 4*4096 f32 (dead after knn -> nb2 of feat2 points)
#define OFF_N2    114688     // 4*4096 f32 (dead after knn -> folds)
#define OFF_F2T   131072     // feat2 transpose [b][n][c]: u16 (compact) or f32 (big)
#define WS_MIN_FLOATS 1966080ull

// fold outputs (dead-after-knn regions, written by k_fold AFTER k_knn)
#define OFF_NB2 98304    // ||feat2[b][:,n]||^2, 16384 floats (over N1)
#define OFF_A2  114688   // (W1Wq - M*Wva)  [c][h] 1024
#define OFF_G   115712   // (M*Wvb)         [c][h] 1024
#define OFF_P5  116736   // [p][h] 80
#define OFF_MBP 116816   // M*bp1 [h] 16
#define OFF_C2  116832   // Wk2^T*Wq2 [c][o] 4096

typedef const uint16_t* u16p;

__device__ __forceinline__ float bf2f(uint16_t u) {
  return __uint_as_float(((uint32_t)u) << 16);
}
__device__ __forceinline__ uint16_t f2bf(float f) {
  uint32_t x = __float_as_uint(f);
  uint32_t r = (x + 0x7FFFu + ((x >> 16) & 1u)) >> 16;
  return (uint16_t)r;
}
__device__ __forceinline__ float ldi(const void* p, int i, int f32m) {
  return f32m ? ((const float*)p)[i] : bf2f(((const uint16_t*)p)[i]);
}
__device__ __forceinline__ int detect_f32(const uint16_t* probe) {
  int lane = threadIdx.x & 63;
  float a = bf2f(probe[lane]);
  float b = bf2f(probe[lane + 64]);
  int bad = (!(fabsf(a) <= 1e4f)) || (!(fabsf(b) <= 1e4f));
  return __any(bad) ? 1 : 0;
}

// ---------------- prep ----------------
__global__ __launch_bounds__(256) void k_prep_xyz(const void* xyz1, const void* xyz2,
                                                  u16p probe, float* ws) {
  int f32m = detect_f32(probe);
  int t = blockIdx.x * 256 + threadIdx.x;
  int b = t >> 12, n = t & (NN - 1);
  int base = b * 3 * NN + n;
  float x1 = ldi(xyz1, base, f32m), y1 = ldi(xyz1, base + NN, f32m), z1 = ldi(xyz1, base + 2 * NN, f32m);
  float x2 = ldi(xyz2, base, f32m), y2 = ldi(xyz2, base + NN, f32m), z2 = ldi(xyz2, base + 2 * NN, f32m);
  float* x1f = ws + OFF_XYZ1F;
  float* x2f = ws + OFF_XYZ2F;
  x1f[base] = x1; x1f[base + NN] = y1; x1f[base + 2 * NN] = z1;
  x2f[base] = x2; x2f[base + NN] = y2; x2f[base + 2 * NN] = z2;
  ws[OFF_N1 + t] = __fadd_rn(__fadd_rn(__fmul_rn(x1, x1), __fmul_rn(y1, y1)), __fmul_rn(z1, z1));
  ws[OFF_N2 + t] = __fadd_rn(__fadd_rn(__fmul_rn(x2, x2), __fmul_rn(y2, y2)), __fmul_rn(z2, z2));
}

// ---------------- transpose feat2 ----------------
__global__ __launch_bounds__(256) void k_transpose(const void* feat2, u16p probe,
                                                   float* ws, int f2cap) {
  __shared__ float tile[64][65];
  int f32m = detect_f32(probe);
  int b = blockIdx.x >> 6;
  int n0 = (blockIdx.x & 63) * 64;
  int tx = threadIdx.x & 63, ty = threadIdx.x >> 6;
#pragma unroll
  for (int i = 0; i < 16; ++i) {
    int c = i * 4 + ty;
    tile[c][tx] = ldi(feat2, (b * 64 + c) * NN + n0 + tx, f32m);
  }
  __syncthreads();
#pragma unroll
  for (int i = 0; i < 16; ++i) {
    int nl = i * 4 + ty;
    size_t di = (size_t)(b * NN + n0 + nl) * 64 + tx;
    float v = tile[tx][nl];
    if (f2cap) ((float*)(ws + OFF_F2T))[di] = v;
    else       ((uint16_t*)(ws + OFF_F2T))[di] = f2bf(v);
  }
}

// ---------------- KNN: wave-per-query, subsample-threshold filter ----------------
#define KCAP 320
__device__ __forceinline__ float knn_dist(const float* cx, const float* cn,
                                          float qx, float qy, float qz, float q2, int j) {
  float cross = __fadd_rn(__fadd_rn(__fmul_rn(qx, cx[j]), __fmul_rn(qy, cx[NN + j])),
                          __fmul_rn(qz, cx[2 * NN + j]));
  return __fsub_rn(__fadd_rn(q2, cn[j]), __fmul_rn(2.0f, cross));
}

__global__ __launch_bounds__(256) void k_knn(float* ws, int off_i12, int off_i11) {
  __shared__ float sd[4][KCAP];
  __shared__ int   si[4][KCAP];
  __shared__ int   eqbuf[4][16];

  int tid = threadIdx.x;
  int wv = tid >> 6, lane = tid & 63;
  int q = blockIdx.x * 4 + wv;
  int which = q >> 14;
  int b = (q >> 12) & 3;
  int n = q & (NN - 1);

  const float* cx = ws + (which ? OFF_XYZ1F : OFF_XYZ2F) + b * 3 * NN;
  const float* cn = ws + (which ? OFF_N1 : OFF_N2) + b * NN;
  const float* qp = ws + OFF_XYZ1F + b * 3 * NN;
  float qx = qp[n], qy = qp[NN + n], qz = qp[2 * NN + n];
  float q2 = ws[OFF_N1 + b * NN + n];
  const float INF = __builtin_inff();

  float mn = INF;
#pragma unroll 4
  for (int i = 0; i < 16; ++i) {
    float d = knn_dist(cx, cn, qx, qy, qz, q2, i * 64 + lane);
    mn = fminf(mn, d);
  }
  float tau0 = 0.f;
  {
    float h = mn;
#pragma unroll 1
    for (int r = 0; r < 16; ++r) {
      float m = h;
#pragma unroll
      for (int msk = 1; msk < 64; msk <<= 1) m = fminf(m, __shfl_xor(m, msk));
      if (r == 15) tau0 = m;
      unsigned long long win = __ballot(h == m);
      int winner = __ffsll(win) - 1;
      if (lane == winner) h = INF;
    }
  }

  unsigned long long below = (1ull << lane) - 1ull;
  int c = 0;
#pragma unroll 2
  for (int i = 0; i < 64; ++i) {
    int j = i * 64 + lane;
    float d = knn_dist(cx, cn, qx, qy, qz, q2, j);
    bool sel = (d <= tau0);
    unsigned long long msk = __ballot(sel);
    int pos = c + __popcll(msk & below);
    if (sel && pos < KCAP) { sd[wv][pos] = d; si[wv][pos] = j; }
    c += __popcll(msk);
  }
  if (c > KCAP) c = KCAP;   // ~e^-50 event; clamp for safety
  __syncthreads();

  float ch[5];
#pragma unroll
  for (int t = 0; t < 5; ++t) ch[t] = INF;
#pragma unroll
  for (int t = 0; t < 5; ++t) {
    int p = t * 64 + lane;
    float x = (p < c) ? sd[wv][p] : INF;
#pragma unroll
    for (int u = 0; u < 5; ++u) {
      float lo = fminf(ch[u], x);
      x = fmaxf(ch[u], x);
      ch[u] = lo;
    }
  }
  float tau = 0.f;
  {
    float h = ch[0];
#pragma unroll 1
    for (int r = 0; r < 16; ++r) {
      float m = h;
#pragma unroll
      for (int msk = 1; msk < 64; msk <<= 1) m = fminf(m, __shfl_xor(m, msk));
      if (r == 15) tau = m;
      unsigned long long win = __ballot(h == m);
      int winner = __ffsll(win) - 1;
      if (lane == winner) {
        ch[0] = ch[1]; ch[1] = ch[2]; ch[2] = ch[3]; ch[3] = ch[4]; ch[4] = INF;
        h = ch[0];
      }
    }
  }

  uint16_t* outp = (uint16_t*)(ws + (which ? off_i11 : off_i12)) + (size_t)(b * NN + n) * SS;
  int c1 = 0, eqc = 0;
#pragma unroll
  for (int t = 0; t < 5; ++t) {
    int p = t * 64 + lane;
    bool act = (p < c);
    float d = act ? sd[wv][p] : INF;
    int j = act ? si[wv][p] : 0;
    bool lt = act && (d < tau);
    bool eq = act && (d == tau);
    unsigned long long mlt = __ballot(lt);
    unsigned long long meq = __ballot(eq);
    int pl = __popcll(mlt & below);
    if (lt) outp[c1 + pl] = (uint16_t)j;
    int pe = __popcll(meq & below);
    if (eq && (eqc + pe) < 16) eqbuf[wv][eqc + pe] = j;
    c1 += __popcll(mlt);
    eqc += __popcll(meq);
  }
  __syncthreads();
  int need = 16 - c1;
  if (lane < need) outp[c1 + lane] = (uint16_t)eqbuf[wv][lane];
}

// ---------------- fold: algebraic precomputes + feat2 norms (66 blocks) ----------------
__global__ __launch_bounds__(256) void k_fold(
    const void* w_q1, const void* w_k1, const void* w_v1, const void* w_mlp1,
    const void* w_pos1, const void* b_pos1, const void* w_q2, const void* w_k2,
    u16p probe, float* ws, int f2cap) {
  int f32m = detect_f32(probe);
  int tid = threadIdx.x;

  if (blockIdx.x >= 2) {
    // nb2[p] = sum_c feat2T[p][c]^2  (p = b*4096+n), over dead N1 region
    int p = (blockIdx.x - 2) * 256 + tid;
    const float* f2f32 = (const float*)(ws + OFF_F2T);
    const uint16_t* f2u16 = (const uint16_t*)(ws + OFF_F2T);
    size_t row = (size_t)p * 64;
    float acc = 0.f;
#pragma unroll 8
    for (int c = 0; c < 64; ++c) {
      float v = f2cap ? f2f32[row + c] : bf2f(f2u16[row + c]);
      acc = fmaf(v, v, acc);
    }
    ws[OFF_NB2 + p] = acc;
    return;
  }

  __shared__ float lA[4096];
  __shared__ float lB[2048];   // lW1[0:1024], lM[1024:2048]
  if (blockIdx.x == 1) {
    __shared__ float lQ[4096];
    for (int i = tid; i < 4096; i += 256) { lA[i] = ldi(w_k2, i, f32m); lQ[i] = ldi(w_q2, i, f32m); }
    __syncthreads();
    for (int i = tid; i < 4096; i += 256) {
      int c = i >> 6, o = i & 63;
      float a0 = 0.f, a1 = 0.f, a2 = 0.f, a3 = 0.f;
      for (int a = 0; a < 64; a += 4) {
        a0 = fmaf(lA[a * 64 + o],       lQ[a * 64 + c],       a0);
        a1 = fmaf(lA[(a + 1) * 64 + o], lQ[(a + 1) * 64 + c], a1);
        a2 = fmaf(lA[(a + 2) * 64 + o], lQ[(a + 2) * 64 + c], a2);
        a3 = fmaf(lA[(a + 3) * 64 + o], lQ[(a + 3) * 64 + c], a3);
      }
      ws[OFF_C2 + i] = (a0 + a1) + (a2 + a3);
    }
    return;
  }

  float* lW1 = lB;
  float* lM  = lB + 1024;
  for (int i = tid; i < 1024; i += 256) lW1[i] = ldi(w_mlp1, i, f32m);   // [h][m]
  for (int i = tid; i < 4096; i += 256) lA[i] = ldi(w_k1, i, f32m);      // [m][o]
  __syncthreads();
  for (int i = tid; i < 1024; i += 256) {       // M[h][o] = W1.Wk
    int hh = i >> 6, o = i & 63;
    float acc = 0.f;
    for (int m = 0; m < 64; ++m) acc = fmaf(lW1[hh * 64 + m], lA[m * 64 + o], acc);
    lM[i] = acc;
  }
  __syncthreads();
  float a2acc[4];
  for (int i = tid; i < 4096; i += 256) lA[i] = ldi(w_q1, i, f32m);      // [o][c]
  __syncthreads();
  for (int k = 0; k < 4; ++k) {
    int i = tid + k * 256;
    int c = i >> 4, hh = i & 15;
    float acc = 0.f;
    for (int o = 0; o < 64; ++o) acc = fmaf(lW1[hh * 64 + o], lA[o * 64 + c], acc);
    a2acc[k] = acc;
  }
  __syncthreads();
  for (int i = tid; i < 4096; i += 256) { int o = i >> 6, c = i & 63; lA[o * 64 + c] = ldi(w_v1, o * 131 + c, f32m); }
  __syncthreads();
  for (int k = 0; k < 4; ++k) {
    int i = tid + k * 256;
    int c = i >> 4, hh = i & 15;
    float acc = 0.f;
    for (int o = 0; o < 64; ++o) acc = fmaf(lM[hh * 64 + o], lA[o * 64 + c], acc);
    ws[OFF_A2 + i] = a2acc[k] - acc;
  }
  __syncthreads();
  for (int i = tid; i < 4096; i += 256) { int o = i >> 6, c = i & 63; lA[o * 64 + c] = ldi(w_v1, o * 131 + 64 + c, f32m); }
  __syncthreads();
  for (int i = tid; i < 1024; i += 256) {       // G[c][h] = M*Wvb
    int c = i >> 4, hh = i & 15;
    float acc = 0.f;
    for (int o = 0; o < 64; ++o) acc = fmaf(lM[hh * 64 + o], lA[o * 64 + c], acc);
    ws[OFF_G + i] = acc;
  }
  if (tid < 16) {
    int hh = tid;
    float p0 = 0.f, p1 = 0.f, p2 = 0.f, p3 = 0.f, p4 = 0.f, pb = 0.f;
    for (int o = 0; o < 64; ++o) {
      float m = lM[hh * 64 + o];
      p0 = fmaf(m, ldi(w_pos1, o * 5 + 0, f32m), p0);
      p1 = fmaf(m, ldi(w_pos1, o * 5 + 1, f32m), p1);
      p2 = fmaf(m, ldi(w_v1, o * 131 + 128, f32m) + ldi(w_pos1, o * 5 + 2, f32m), p2);
      p3 = fmaf(m, ldi(w_v1, o * 131 + 129, f32m) + ldi(w_pos1, o * 5 + 3, f32m), p3);
      p4 = fmaf(m, ldi(w_v1, o * 131 + 130, f32m) + ldi(w_pos1, o * 5 + 4, f32m), p4);
      pb = fmaf(m, ldi(b_pos1, o, f32m), pb);
    }
    ws[OFF_P5 + hh] = p0; ws[OFF_P5 + 16 + hh] = p1; ws[OFF_P5 + 32 + hh] = p2;
    ws[OFF_P5 + 48 + hh] = p3; ws[OFF_P5 + 64 + hh] = p4;
    ws[OFF_MBP + hh] = pb;
  }
}

// ---------------- group1: folded + online softmax + expanded feat-norm ----------------
// NOTE: no min-blocks arg in launch_bounds — round 8's (512,4) meant 4 BLOCKS/CU
// (CUDA semantics) -> 64-VGPR cap -> scratch spills (373 MB WRITE_SIZE).
__global__ __launch_bounds__(512) void k_group1(
    const void* feat1, const void* w_v1, const void* w_mlp2,
    u16p probe, float* ws, int off_p2n, int off_i12, int f2cap) {
  __shared__ float s_wva[4096];    // [c][o]
  __shared__ float s_wvb[4096];    // [c][o]
  __shared__ float s_wvx[192];
  __shared__ float s_A2[1088];     // [c*17+h] padded (kills 4-way bank conflict)
  __shared__ float s_G[1088];      // [c*17+h] padded
  __shared__ float s_P5[80];
  __shared__ float s_MBP[16];
  __shared__ float s_w2[16];
  __shared__ float f1s[8][64];     // pre-barrier write, read-only after
  __shared__ float xds[8][64];
  __shared__ float snb2[8][16];
  __shared__ int   idxs[8][16];

  int f32m = detect_f32(probe);
  int tid = threadIdx.x;
  for (int i = tid; i < 4096; i += 512) {
    int c = i >> 6, o = i & 63;
    s_wva[i] = ldi(w_v1, o * 131 + c, f32m);
    s_wvb[i] = ldi(w_v1, o * 131 + 64 + c, f32m);
  }
  if (tid < 192) { int j = tid >> 6, o = tid & 63; s_wvx[tid] = ldi(w_v1, o * 131 + 128 + j, f32m); }
  for (int i = tid; i < 1024; i += 512) {
    int c = i >> 4, h = i & 15;
    s_A2[c * 17 + h] = ws[OFF_A2 + i];
    s_G[c * 17 + h] = ws[OFF_G + i];
  }
  if (tid < 80) s_P5[tid] = ws[OFF_P5 + tid];
  if (tid < 16) { s_MBP[tid] = ws[OFF_MBP + tid]; s_w2[tid] = ldi(w_mlp2, tid, f32m); }

  int w = tid >> 6, o = tid & 63;
  int g = blockIdx.x * 8 + w;
  int b = g >> 12, n = g & (NN - 1);
  const float* x1f = ws + OFF_XYZ1F + b * 3 * NN;
  const float* x2f = ws + OFF_XYZ2F + b * 3 * NN;
  const uint16_t* idx12 = (const uint16_t*)(ws + off_i12) + (size_t)(b * NN + n) * SS;
  const float* f2f32 = (const float*)(ws + OFF_F2T);
  const uint16_t* f2u16 = (const uint16_t*)(ws + OFF_F2T);

  float f1o = ldi(feat1, (b * 64 + o) * NN + n, f32m);
  f1s[w][o] = f1o;
  float qx = x1f[n], qy = x1f[NN + n], qz = x1f[2 * NN + n];
  if (o < 16) {
    int j = (int)idx12[o];
    idxs[w][o] = j;
    float dx = __fsub_rn(qx, x2f[j]);
    float dy = __fsub_rn(qy, x2f[NN + j]);
    float dz = __fsub_rn(qz, x2f[2 * NN + j]);
    xds[w][o * 4 + 0] = dx; xds[w][o * 4 + 1] = dy; xds[w][o * 4 + 2] = dz;
    xds[w][o * 4 + 3] = sqrtf(dx * dx + dy * dy + dz * dz);
    snb2[w][o] = ws[OFF_NB2 + b * NN + j];
  }
  __syncthreads();   // only block barrier; below: regs/shfl/read-only LDS

  int h = o & 15, part = o >> 4;
  // f1n2 = ||f1||^2 (once per query)
  float f1n2 = f1o * f1o;
#pragma unroll
  for (int msk = 1; msk < 64; msk <<= 1) f1n2 += __shfl_xor(f1n2, msk);
  // vb[o] = Wva.pts (LDS-broadcast reads of f1)
  float v0 = 0.f, v1 = 0.f, v2 = 0.f, v3 = 0.f;
#pragma unroll
  for (int c = 0; c < 64; c += 4) {
    v0 = fmaf(s_wva[c * 64 + o],       f1s[w][c],     v0);
    v1 = fmaf(s_wva[(c + 1) * 64 + o], f1s[w][c + 1], v1);
    v2 = fmaf(s_wva[(c + 2) * 64 + o], f1s[w][c + 2], v2);
    v3 = fmaf(s_wva[(c + 3) * 64 + o], f1s[w][c + 3], v3);
  }
  float vb = (v0 + v1) + (v2 + v3);
  // tb[h] = (A2.pts)[h] - MBP[h]
  float tb = 0.f;
#pragma unroll
  for (int i = 0; i < 16; ++i) {
    int c = part * 16 + i;
    tb = fmaf(s_A2[c * 17 + h], f1s[w][c], tb);
  }
  tb += __shfl_xor(tb, 16);
  tb += __shfl_xor(tb, 32);
  tb -= s_MBP[h];

  // online softmax state
  float m = -__builtin_inff(), l = 0.f;
  float anb = 0.f, axa = 0.f, aya = 0.f, aza = 0.f;
#pragma unroll 2
  for (int s = 0; s < SS; ++s) {
    int j = idxs[w][s];
    size_t fi = (size_t)(b * NN + j) * 64 + o;
    float nb = f2cap ? f2f32[fi] : bf2f(f2u16[fi]);
    float gl = 0.f, dp = 0.f;
#pragma unroll
    for (int i = 0; i < 16; ++i) {
      int c = part * 16 + i;
      float nbb = __shfl(nb, c);
      gl = fmaf(s_G[c * 17 + h], nbb, gl);
      dp = fmaf(f1s[w][c], nbb, dp);
    }
    gl += __shfl_xor(gl, 16); dp += __shfl_xor(dp, 16);
    gl += __shfl_xor(gl, 32); dp += __shfl_xor(dp, 32);
    float ssq = fmaxf(f1n2 - 2.f * dp + snb2[w][s], 0.f);
    float fn = sqrtf(ssq);
    float dx = xds[w][s * 4 + 0], dy = xds[w][s * 4 + 1], dz = xds[w][s * 4 + 2], xn = xds[w][s * 4 + 3];
    float p5 = s_P5[h] * fn;
    p5 = fmaf(s_P5[16 + h], xn, p5);
    p5 = fmaf(s_P5[32 + h], dx, p5);
    p5 = fmaf(s_P5[48 + h], dy, p5);
    p5 = fmaf(s_P5[64 + h], dz, p5);
    float t = tb - gl - p5;
    float r = fmaxf(t, 0.f) * s_w2[h];
    r += __shfl_xor(r, 1);
    r += __shfl_xor(r, 2);
    r += __shfl_xor(r, 4);
    r += __shfl_xor(r, 8);   // logit, identical in all lanes
    // online update
    float mn = fmaxf(m, r);
    float sc = __expf(m - mn);
    float e = __expf(r - mn);
    l = l * sc + e;
    anb = anb * sc + e * nb;
    axa = axa * sc + e * dx;
    aya = aya * sc + e * dy;
    aza = aza * sc + e * dz;
    m = mn;
  }
  float invl = 1.f / l;
  anb *= invl; axa *= invl; aya *= invl; aza *= invl;
  // out = vb + Wvb.anb + Wvx.(axa,aya,aza)
  float o0 = vb, o1 = 0.f, o2 = 0.f, o3 = 0.f;
#pragma unroll
  for (int c = 0; c < 64; c += 4) {
    o0 = fmaf(s_wvb[c * 64 + o],       __shfl(anb, c),     o0);
    o1 = fmaf(s_wvb[(c + 1) * 64 + o], __shfl(anb, c + 1), o1);
    o2 = fmaf(s_wvb[(c + 2) * 64 + o], __shfl(anb, c + 2), o2);
    o3 = fmaf(s_wvb[(c + 3) * 64 + o], __shfl(anb, c + 3), o3);
  }
  float acc = (o0 + o1) + (o2 + o3);
  acc = fmaf(s_wvx[o], axa, acc);
  acc = fmaf(s_wvx[64 + o], aya, acc);
  acc = fmaf(s_wvx[128 + o], aza, acc);
  float res = acc >= 0.f ? acc : 0.1f * acc;   // leaky 0.1
  ws[off_p2n + (size_t)(b * NN + n) * 64 + o] = res;
}

// ---------------- group2: folded + online softmax, part-slice dot ----------------
__global__ __launch_bounds__(512) void k_group2(
    const void* w_v2, const void* w_pos2, const void* b_pos2,
    u16p probe, float* ws, void* outp, int off_p2n, int off_i11) {
  __shared__ float s_C2[4096];    // [c][o]
  __shared__ float s_wv2[4096];   // [c][o]
  __shared__ float s_wp2t[256];   // [p][o]
  __shared__ float s_bp2[64];
  __shared__ float xds[8][64];
  __shared__ int   idxs[8][16];
  __shared__ float souts[8][64];

  int f32m = detect_f32(probe);
  int tid = threadIdx.x;
  for (int i = tid; i < 4096; i += 512) {
    int c = i >> 6, o = i & 63;
    s_C2[i] = ws[OFF_C2 + i];
    s_wv2[i] = ldi(w_v2, o * 64 + c, f32m);
  }
  if (tid < 256) { int p = tid >> 6, o = tid & 63; s_wp2t[p * 64 + o] = ldi(w_pos2, o * 4 + p, f32m); }
  if (tid < 64) s_bp2[tid] = ldi(b_pos2, tid, f32m);

  int w = tid >> 6, o = tid & 63;
  int g = blockIdx.x * 8 + w;
  int b = g >> 12, n = g & (NN - 1);
  const float* p2t = ws + off_p2n;
  const float* x1f = ws + OFF_XYZ1F + b * 3 * NN;
  const uint16_t* idx11 = (const uint16_t*)(ws + off_i11) + (size_t)(b * NN + n) * SS;

  float p1o = p2t[(size_t)(b * NN + n) * 64 + o];
  float qx = x1f[n], qy = x1f[NN + n], qz = x1f[2 * NN + n];
  if (o < 16) {
    int j = (int)idx11[o];
    idxs[w][o] = j;
    float dx = __fsub_rn(qx, x1f[j]);
    float dy = __fsub_rn(qy, x1f[NN + j]);
    float dz = __fsub_rn(qz, x1f[2 * NN + j]);
    xds[w][o * 4 + 0] = dx; xds[w][o * 4 + 1] = dy; xds[w][o * 4 + 2] = dz;
    xds[w][o * 4 + 3] = sqrtf(dx * dx + dy * dy + dz * dz);
  }
  __syncthreads();

  int part = o >> 4;
  // u[o] = (Wk2^T Wq2).pts  via shfl broadcasts of p1o
  float u0 = 0.f, u1 = 0.f, u2 = 0.f, u3 = 0.f;
#pragma unroll
  for (int c = 0; c < 64; c += 4) {
    u0 = fmaf(s_C2[c * 64 + o],       __shfl(p1o, c),     u0);
    u1 = fmaf(s_C2[(c + 1) * 64 + o], __shfl(p1o, c + 1), u1);
    u2 = fmaf(s_C2[(c + 2) * 64 + o], __shfl(p1o, c + 2), u2);
    u3 = fmaf(s_C2[(c + 3) * 64 + o], __shfl(p1o, c + 3), u3);
  }
  float u = (u0 + u1) + (u2 + u3);
  float w4x = u * s_wp2t[o];
  float w4y = u * s_wp2t[64 + o];
  float w4z = u * s_wp2t[128 + o];
  float w4n = u * s_wp2t[192 + o];
  float ubp = u * s_bp2[o];
#pragma unroll
  for (int msk = 1; msk < 64; msk <<= 1) {
    w4x += __shfl_xor(w4x, msk);
    w4y += __shfl_xor(w4y, msk);
    w4z += __shfl_xor(w4z, msk);
    w4n += __shfl_xor(w4n, msk);
    ubp += __shfl_xor(ubp, msk);
  }
  // pre-shuffle u into this lane's c-slice (16 regs, reused all s)
  float u16r[16];
#pragma unroll
  for (int i = 0; i < 16; ++i) u16r[i] = __shfl(u, part * 16 + i);

  float m = -__builtin_inff(), l = 0.f, anb = 0.f;
#pragma unroll 2
  for (int s = 0; s < SS; ++s) {
    int j = idxs[w][s];
    float nb = p2t[(size_t)(b * NN + j) * 64 + o];
    float tp = 0.f;
#pragma unroll
    for (int i = 0; i < 16; ++i) tp = fmaf(u16r[i], __shfl(nb, part * 16 + i), tp);
    tp += __shfl_xor(tp, 16);
    tp += __shfl_xor(tp, 32);   // full dot, all lanes
    float dx = xds[w][s * 4 + 0], dy = xds[w][s * 4 + 1], dz = xds[w][s * 4 + 2], xn = xds[w][s * 4 + 3];
    float logit = tp;
    logit = fmaf(w4x, dx, logit);
    logit = fmaf(w4y, dy, logit);
    logit = fmaf(w4z, dz, logit);
    logit = fmaf(w4n, xn, logit);
    logit = (logit + ubp) * 0.125f;
    float mn = fmaxf(m, logit);
    float sc = __expf(m - mn);
    float e = __expf(logit - mn);
    l = l * sc + e;
    anb = anb * sc + e * nb;
    m = mn;
  }
  anb *= 1.f / l;
  float o0 = 0.f, o1 = 0.f, o2 = 0.f, o3 = 0.f;
#pragma unroll
  for (int c = 0; c < 64; c += 4) {
    o0 = fmaf(s_wv2[c * 64 + o],       __shfl(anb, c),     o0);
    o1 = fmaf(s_wv2[(c + 1) * 64 + o], __shfl(anb, c + 1), o1);
    o2 = fmaf(s_wv2[(c + 2) * 64 + o], __shfl(anb, c + 2), o2);
    o3 = fmaf(s_wv2[(c + 3) * 64 + o], __shfl(anb, c + 3), o3);
  }
  float acc = (o0 + o1) + (o2 + o3);
  float res = acc >= 0.f ? acc : 0.1f * acc;
  souts[w][o] = res;
  __syncthreads();   // cross-wave transpose staging
  int c = tid >> 3, nr = tid & 7;
  int n0 = (blockIdx.x * 8) & (NN - 1);
  int b0 = (blockIdx.x * 8) >> 12;
  size_t oi = (size_t)(b0 * 64 + c) * NN + n0 + nr;
  float ov = souts[nr][c];
  if (f32m) ((float*)outp)[oi] = ov;
  else      ((uint16_t*)outp)[oi] = f2bf(ov);
}

extern "C" void kernel_launch(void* const* d_in, const int* in_sizes, int n_in,
                              void* d_out, int out_size, void* d_ws, size_t ws_size,
                              hipStream_t stream) {
  const void* xyz1 = d_in[0];
  const void* feat1 = d_in[1];
  const void* xyz2 = d_in[2];
  const void* feat2 = d_in[3];
  const void* w_q1 = d_in[4];
  const void* w_k1 = d_in[5];
  const void* w_v1 = d_in[6];
  const void* w_mlp1 = d_in[7];
  const void* w_mlp2 = d_in[8];
  const void* w_pos1 = d_in[9];
  const void* b_pos1 = d_in[10];
  const void* w_q2 = d_in[11];
  const void* w_k2 = d_in[12];
  const void* w_v2 = d_in[13];
  const void* w_pos2 = d_in[14];
  const void* b_pos2 = d_in[15];
  u16p probe = (u16p)d_in[1];
  float* ws = (float*)d_ws;

  if (ws_size < WS_MIN_FLOATS * 4ull) return;

  int big = (ws_size >= 2490368ull * 4ull) ? 1 : 0;
  int f2cap   = big;
  int off_p2n = big ? 1179648 : 655360;
  int off_i12 = big ? 2228224 : 1703936;
  int off_i11 = big ? 2359296 : 1835008;

  hipLaunchKernelGGL(k_prep_xyz, dim3(64), dim3(256), 0, stream, xyz1, xyz2, probe, ws);
  hipLaunchKernelGGL(k_transpose, dim3(256), dim3(256), 0, stream, feat2, probe, ws, f2cap);
  hipLaunchKernelGGL(k_knn, dim3(8192), dim3(256), 0, stream, ws, off_i12, off_i11);
  hipLaunchKernelGGL(k_fold, dim3(66), dim3(256), 0, stream,
                     w_q1, w_k1, w_v1, w_mlp1, w_pos1, b_pos1, w_q2, w_k2, probe, ws, f2cap);
  hipLaunchKernelGGL(k_group1, dim3(2048), dim3(512), 0, stream,
                     feat1, w_v1, w_mlp2, probe, ws, off_p2n, off_i12, f2cap);
  hipLaunchKernelGGL(k_group2, dim3(2048), dim3(512), 0, stream,
                     w_v2, w_pos2, b_pos2, probe, ws, d_out, off_p2n, off_i11);
}

// Round 10
// 549.708 us; speedup vs baseline: 3.1708x; 1.0425x over previous
//
#include <hip/hip_runtime.h>
#include <stdint.h>

#define NN 4096
#define SS 16

// fixed ws float offsets
#define OFF_XYZ1F 0          // 4*3*4096 f32
#define OFF_XYZ2F 49152      // 4*3*4096 f32
#define OFF_N1    98304      // 4*4096 f32 (dead after knn -> nb2 of feat2 points)
#define OFF_N2    114688     // 4*4096 f32 (dead after knn -> folds)
#define OFF_F2T   131072     // feat2 transpose [b][n][c]: u16 (compact) or f32 (big)
#define WS_MIN_FLOATS 1966080ull

// fold outputs (dead-after-knn regions, written by k_fold AFTER k_knn)
#define OFF_NB2 98304    // ||feat2[b][:,n]||^2, 16384 floats (over N1)
#define OFF_A2  114688   // (W1Wq - M*Wva)  [c][h] 1024
#define OFF_G   115712   // (M*Wvb)         [c][h] 1024
#define OFF_P5  116736   // [p][h] 80
#define OFF_MBP 116816   // M*bp1 [h] 16
#define OFF_C2  116832   // Wk2^T*Wq2 [c][o] 4096

typedef const uint16_t* u16p;

__device__ __forceinline__ float bf2f(uint16_t u) {
  return __uint_as_float(((uint32_t)u) << 16);
}
__device__ __forceinline__ uint16_t f2bf(float f) {
  uint32_t x = __float_as_uint(f);
  uint32_t r = (x + 0x7FFFu + ((x >> 16) & 1u)) >> 16;
  return (uint16_t)r;
}
__device__ __forceinline__ float ldi(const void* p, int i, int f32m) {
  return f32m ? ((const float*)p)[i] : bf2f(((const uint16_t*)p)[i]);
}
__device__ __forceinline__ int detect_f32(const uint16_t* probe) {
  int lane = threadIdx.x & 63;
  float a = bf2f(probe[lane]);
  float b = bf2f(probe[lane + 64]);
  int bad = (!(fabsf(a) <= 1e4f)) || (!(fabsf(b) <= 1e4f));
  return __any(bad) ? 1 : 0;
}

// ---------------- prep ----------------
__global__ __launch_bounds__(256) void k_prep_xyz(const void* xyz1, const void* xyz2,
                                                  u16p probe, float* ws) {
  int f32m = detect_f32(probe);
  int t = blockIdx.x * 256 + threadIdx.x;
  int b = t >> 12, n = t & (NN - 1);
  int base = b * 3 * NN + n;
  float x1 = ldi(xyz1, base, f32m), y1 = ldi(xyz1, base + NN, f32m), z1 = ldi(xyz1, base + 2 * NN, f32m);
  float x2 = ldi(xyz2, base, f32m), y2 = ldi(xyz2, base + NN, f32m), z2 = ldi(xyz2, base + 2 * NN, f32m);
  float* x1f = ws + OFF_XYZ1F;
  float* x2f = ws + OFF_XYZ2F;
  x1f[base] = x1; x1f[base + NN] = y1; x1f[base + 2 * NN] = z1;
  x2f[base] = x2; x2f[base + NN] = y2; x2f[base + 2 * NN] = z2;
  ws[OFF_N1 + t] = __fadd_rn(__fadd_rn(__fmul_rn(x1, x1), __fmul_rn(y1, y1)), __fmul_rn(z1, z1));
  ws[OFF_N2 + t] = __fadd_rn(__fadd_rn(__fmul_rn(x2, x2), __fmul_rn(y2, y2)), __fmul_rn(z2, z2));
}

// ---------------- transpose feat2 ----------------
__global__ __launch_bounds__(256) void k_transpose(const void* feat2, u16p probe,
                                                   float* ws, int f2cap) {
  __shared__ float tile[64][65];
  int f32m = detect_f32(probe);
  int b = blockIdx.x >> 6;
  int n0 = (blockIdx.x & 63) * 64;
  int tx = threadIdx.x & 63, ty = threadIdx.x >> 6;
#pragma unroll
  for (int i = 0; i < 16; ++i) {
    int c = i * 4 + ty;
    tile[c][tx] = ldi(feat2, (b * 64 + c) * NN + n0 + tx, f32m);
  }
  __syncthreads();
#pragma unroll
  for (int i = 0; i < 16; ++i) {
    int nl = i * 4 + ty;
    size_t di = (size_t)(b * NN + n0 + nl) * 64 + tx;
    float v = tile[tx][nl];
    if (f2cap) ((float*)(ws + OFF_F2T))[di] = v;
    else       ((uint16_t*)(ws + OFF_F2T))[di] = f2bf(v);
  }
}

// ---------------- KNN: wave-per-query, subsample-threshold filter ----------------
#define KCAP 320
__device__ __forceinline__ float knn_dist(const float* cx, const float* cn,
                                          float qx, float qy, float qz, float q2, int j) {
  float cross = __fadd_rn(__fadd_rn(__fmul_rn(qx, cx[j]), __fmul_rn(qy, cx[NN + j])),
                          __fmul_rn(qz, cx[2 * NN + j]));
  return __fsub_rn(__fadd_rn(q2, cn[j]), __fmul_rn(2.0f, cross));
}

__global__ __launch_bounds__(256) void k_knn(float* ws, int off_i12, int off_i11) {
  __shared__ float sd[4][KCAP];
  __shared__ int   si[4][KCAP];
  __shared__ int   eqbuf[4][16];

  int tid = threadIdx.x;
  int wv = tid >> 6, lane = tid & 63;
  int q = blockIdx.x * 4 + wv;
  int which = q >> 14;
  int b = (q >> 12) & 3;
  int n = q & (NN - 1);

  const float* cx = ws + (which ? OFF_XYZ1F : OFF_XYZ2F) + b * 3 * NN;
  const float* cn = ws + (which ? OFF_N1 : OFF_N2) + b * NN;
  const float* qp = ws + OFF_XYZ1F + b * 3 * NN;
  float qx = qp[n], qy = qp[NN + n], qz = qp[2 * NN + n];
  float q2 = ws[OFF_N1 + b * NN + n];
  const float INF = __builtin_inff();

  float mn = INF;
#pragma unroll 4
  for (int i = 0; i < 16; ++i) {
    float d = knn_dist(cx, cn, qx, qy, qz, q2, i * 64 + lane);
    mn = fminf(mn, d);
  }
  float tau0 = 0.f;
  {
    float h = mn;
#pragma unroll 1
    for (int r = 0; r < 16; ++r) {
      float m = h;
#pragma unroll
      for (int msk = 1; msk < 64; msk <<= 1) m = fminf(m, __shfl_xor(m, msk));
      if (r == 15) tau0 = m;
      unsigned long long win = __ballot(h == m);
      int winner = __ffsll(win) - 1;
      if (lane == winner) h = INF;
    }
  }

  unsigned long long below = (1ull << lane) - 1ull;
  int c = 0;
#pragma unroll 2
  for (int i = 0; i < 64; ++i) {
    int j = i * 64 + lane;
    float d = knn_dist(cx, cn, qx, qy, qz, q2, j);
    bool sel = (d <= tau0);
    unsigned long long msk = __ballot(sel);
    int pos = c + __popcll(msk & below);
    if (sel && pos < KCAP) { sd[wv][pos] = d; si[wv][pos] = j; }
    c += __popcll(msk);
  }
  if (c > KCAP) c = KCAP;   // ~e^-50 event; clamp for safety
  __syncthreads();

  float ch[5];
#pragma unroll
  for (int t = 0; t < 5; ++t) ch[t] = INF;
#pragma unroll
  for (int t = 0; t < 5; ++t) {
    int p = t * 64 + lane;
    float x = (p < c) ? sd[wv][p] : INF;
#pragma unroll
    for (int u = 0; u < 5; ++u) {
      float lo = fminf(ch[u], x);
      x = fmaxf(ch[u], x);
      ch[u] = lo;
    }
  }
  float tau = 0.f;
  {
    float h = ch[0];
#pragma unroll 1
    for (int r = 0; r < 16; ++r) {
      float m = h;
#pragma unroll
      for (int msk = 1; msk < 64; msk <<= 1) m = fminf(m, __shfl_xor(m, msk));
      if (r == 15) tau = m;
      unsigned long long win = __ballot(h == m);
      int winner = __ffsll(win) - 1;
      if (lane == winner) {
        ch[0] = ch[1]; ch[1] = ch[2]; ch[2] = ch[3]; ch[3] = ch[4]; ch[4] = INF;
        h = ch[0];
      }
    }
  }

  uint16_t* outp = (uint16_t*)(ws + (which ? off_i11 : off_i12)) + (size_t)(b * NN + n) * SS;
  int c1 = 0, eqc = 0;
#pragma unroll
  for (int t = 0; t < 5; ++t) {
    int p = t * 64 + lane;
    bool act = (p < c);
    float d = act ? sd[wv][p] : INF;
    int j = act ? si[wv][p] : 0;
    bool lt = act && (d < tau);
    bool eq = act && (d == tau);
    unsigned long long mlt = __ballot(lt);
    unsigned long long meq = __ballot(eq);
    int pl = __popcll(mlt & below);
    if (lt) outp[c1 + pl] = (uint16_t)j;
    int pe = __popcll(meq & below);
    if (eq && (eqc + pe) < 16) eqbuf[wv][eqc + pe] = j;
    c1 += __popcll(mlt);
    eqc += __popcll(meq);
  }
  __syncthreads();
  int need = 16 - c1;
  if (lane < need) outp[c1 + lane] = (uint16_t)eqbuf[wv][lane];
}

// ---------------- fold: algebraic precomputes + feat2 norms (66 blocks) ----------------
__global__ __launch_bounds__(256) void k_fold(
    const void* w_q1, const void* w_k1, const void* w_v1, const void* w_mlp1,
    const void* w_pos1, const void* b_pos1, const void* w_q2, const void* w_k2,
    u16p probe, float* ws, int f2cap) {
  int f32m = detect_f32(probe);
  int tid = threadIdx.x;

  if (blockIdx.x >= 2) {
    int p = (blockIdx.x - 2) * 256 + tid;
    const float* f2f32 = (const float*)(ws + OFF_F2T);
    const uint16_t* f2u16 = (const uint16_t*)(ws + OFF_F2T);
    size_t row = (size_t)p * 64;
    float acc = 0.f;
#pragma unroll 8
    for (int c = 0; c < 64; ++c) {
      float v = f2cap ? f2f32[row + c] : bf2f(f2u16[row + c]);
      acc = fmaf(v, v, acc);
    }
    ws[OFF_NB2 + p] = acc;
    return;
  }

  __shared__ float lA[4096];
  __shared__ float lB[2048];   // lW1[0:1024], lM[1024:2048]
  if (blockIdx.x == 1) {
    __shared__ float lQ[4096];
    for (int i = tid; i < 4096; i += 256) { lA[i] = ldi(w_k2, i, f32m); lQ[i] = ldi(w_q2, i, f32m); }
    __syncthreads();
    for (int i = tid; i < 4096; i += 256) {
      int c = i >> 6, o = i & 63;
      float a0 = 0.f, a1 = 0.f, a2 = 0.f, a3 = 0.f;
      for (int a = 0; a < 64; a += 4) {
        a0 = fmaf(lA[a * 64 + o],       lQ[a * 64 + c],       a0);
        a1 = fmaf(lA[(a + 1) * 64 + o], lQ[(a + 1) * 64 + c], a1);
        a2 = fmaf(lA[(a + 2) * 64 + o], lQ[(a + 2) * 64 + c], a2);
        a3 = fmaf(lA[(a + 3) * 64 + o], lQ[(a + 3) * 64 + c], a3);
      }
      ws[OFF_C2 + i] = (a0 + a1) + (a2 + a3);
    }
    return;
  }

  float* lW1 = lB;
  float* lM  = lB + 1024;
  for (int i = tid; i < 1024; i += 256) lW1[i] = ldi(w_mlp1, i, f32m);   // [h][m]
  for (int i = tid; i < 4096; i += 256) lA[i] = ldi(w_k1, i, f32m);      // [m][o]
  __syncthreads();
  for (int i = tid; i < 1024; i += 256) {       // M[h][o] = W1.Wk
    int hh = i >> 6, o = i & 63;
    float acc = 0.f;
    for (int m = 0; m < 64; ++m) acc = fmaf(lW1[hh * 64 + m], lA[m * 64 + o], acc);
    lM[i] = acc;
  }
  __syncthreads();
  float a2acc[4];
  for (int i = tid; i < 4096; i += 256) lA[i] = ldi(w_q1, i, f32m);      // [o][c]
  __syncthreads();
  for (int k = 0; k < 4; ++k) {
    int i = tid + k * 256;
    int c = i >> 4, hh = i & 15;
    float acc = 0.f;
    for (int o = 0; o < 64; ++o) acc = fmaf(lW1[hh * 64 + o], lA[o * 64 + c], acc);
    a2acc[k] = acc;
  }
  __syncthreads();
  for (int i = tid; i < 4096; i += 256) { int o = i >> 6, c = i & 63; lA[o * 64 + c] = ldi(w_v1, o * 131 + c, f32m); }
  __syncthreads();
  for (int k = 0; k < 4; ++k) {
    int i = tid + k * 256;
    int c = i >> 4, hh = i & 15;
    float acc = 0.f;
    for (int o = 0; o < 64; ++o) acc = fmaf(lM[hh * 64 + o], lA[o * 64 + c], acc);
    ws[OFF_A2 + i] = a2acc[k] - acc;
  }
  __syncthreads();
  for (int i = tid; i < 4096; i += 256) { int o = i >> 6, c = i & 63; lA[o * 64 + c] = ldi(w_v1, o * 131 + 64 + c, f32m); }
  __syncthreads();
  for (int i = tid; i < 1024; i += 256) {       // G[c][h] = M*Wvb
    int c = i >> 4, hh = i & 15;
    float acc = 0.f;
    for (int o = 0; o < 64; ++o) acc = fmaf(lM[hh * 64 + o], lA[o * 64 + c], acc);
    ws[OFF_G + i] = acc;
  }
  if (tid < 16) {
    int hh = tid;
    float p0 = 0.f, p1 = 0.f, p2 = 0.f, p3 = 0.f, p4 = 0.f, pb = 0.f;
    for (int o = 0; o < 64; ++o) {
      float m = lM[hh * 64 + o];
      p0 = fmaf(m, ldi(w_pos1, o * 5 + 0, f32m), p0);
      p1 = fmaf(m, ldi(w_pos1, o * 5 + 1, f32m), p1);
      p2 = fmaf(m, ldi(w_v1, o * 131 + 128, f32m) + ldi(w_pos1, o * 5 + 2, f32m), p2);
      p3 = fmaf(m, ldi(w_v1, o * 131 + 129, f32m) + ldi(w_pos1, o * 5 + 3, f32m), p3);
      p4 = fmaf(m, ldi(w_v1, o * 131 + 130, f32m) + ldi(w_pos1, o * 5 + 4, f32m), p4);
      pb = fmaf(m, ldi(b_pos1, o, f32m), pb);
    }
    ws[OFF_P5 + hh] = p0; ws[OFF_P5 + 16 + hh] = p1; ws[OFF_P5 + 32 + hh] = p2;
    ws[OFF_P5 + 48 + hh] = p3; ws[OFF_P5 + 64 + hh] = p4;
    ws[OFF_MBP + hh] = pb;
  }
}

// ---------------- group1: DS-pipe-lean (reg-hoisted invariants) ----------------
__global__ __launch_bounds__(512) void k_group1(
    const void* feat1, const void* w_v1, const void* w_mlp2,
    u16p probe, float* ws, int off_p2n, int off_i12, int f2cap) {
  __shared__ float s_wva[4096];    // [c][o]
  __shared__ float s_wvb[4096];    // [c][o]
  __shared__ float s_wvx[192];
  __shared__ float s_A2[1088];     // [c*17+h] padded
  __shared__ float s_G[1088];      // [c*17+h] padded
  __shared__ float s_P5[80];
  __shared__ float s_MBP[16];
  __shared__ float s_w2[16];
  __shared__ float f1s[8][64];
  __shared__ float4 xds4[8][16];   // per s: (dx,dy,dz,norm) — b128 broadcast read
  __shared__ float snb2[8][16];
  __shared__ int   idxs[8][16];

  int f32m = detect_f32(probe);
  int tid = threadIdx.x;
  for (int i = tid; i < 4096; i += 512) {
    int c = i >> 6, o = i & 63;
    s_wva[i] = ldi(w_v1, o * 131 + c, f32m);
    s_wvb[i] = ldi(w_v1, o * 131 + 64 + c, f32m);
  }
  if (tid < 192) { int j = tid >> 6, o = tid & 63; s_wvx[tid] = ldi(w_v1, o * 131 + 128 + j, f32m); }
  for (int i = tid; i < 1024; i += 512) {
    int c = i >> 4, h = i & 15;
    s_A2[c * 17 + h] = ws[OFF_A2 + i];
    s_G[c * 17 + h] = ws[OFF_G + i];
  }
  if (tid < 80) s_P5[tid] = ws[OFF_P5 + tid];
  if (tid < 16) { s_MBP[tid] = ws[OFF_MBP + tid]; s_w2[tid] = ldi(w_mlp2, tid, f32m); }

  int w = tid >> 6, o = tid & 63;
  int g = blockIdx.x * 8 + w;
  int b = g >> 12, n = g & (NN - 1);
  const float* x1f = ws + OFF_XYZ1F + b * 3 * NN;
  const float* x2f = ws + OFF_XYZ2F + b * 3 * NN;
  const uint16_t* idx12 = (const uint16_t*)(ws + off_i12) + (size_t)(b * NN + n) * SS;
  const float* f2f32 = (const float*)(ws + OFF_F2T);
  const uint16_t* f2u16 = (const uint16_t*)(ws + OFF_F2T);

  float f1o = ldi(feat1, (b * 64 + o) * NN + n, f32m);
  f1s[w][o] = f1o;
  float qx = x1f[n], qy = x1f[NN + n], qz = x1f[2 * NN + n];
  if (o < 16) {
    int j = (int)idx12[o];
    idxs[w][o] = j;
    float dx = __fsub_rn(qx, x2f[j]);
    float dy = __fsub_rn(qy, x2f[NN + j]);
    float dz = __fsub_rn(qz, x2f[2 * NN + j]);
    xds4[w][o] = make_float4(dx, dy, dz, sqrtf(dx * dx + dy * dy + dz * dz));
    snb2[w][o] = ws[OFF_NB2 + b * NN + j];
  }
  __syncthreads();   // only block barrier; below: regs/shfl/read-only LDS

  int h = o & 15, part = o >> 4;
  // ---- hoist loop-invariant LDS values into registers ----
  float Gr[16], f1r[16];
#pragma unroll
  for (int i = 0; i < 16; ++i) {
    int c = part * 16 + i;
    Gr[i] = s_G[c * 17 + h];
    f1r[i] = f1s[w][c];
  }
  float p5a = s_P5[h], p5b = s_P5[16 + h], p5c = s_P5[32 + h], p5d = s_P5[48 + h], p5e = s_P5[64 + h];
  float w2r = s_w2[h];

  // f1n2 = ||f1||^2
  float f1n2 = f1o * f1o;
#pragma unroll
  for (int msk = 1; msk < 64; msk <<= 1) f1n2 += __shfl_xor(f1n2, msk);
  // vb[o] = Wva.pts
  float v0 = 0.f, v1 = 0.f, v2 = 0.f, v3 = 0.f;
#pragma unroll
  for (int c = 0; c < 64; c += 4) {
    v0 = fmaf(s_wva[c * 64 + o],       f1s[w][c],     v0);
    v1 = fmaf(s_wva[(c + 1) * 64 + o], f1s[w][c + 1], v1);
    v2 = fmaf(s_wva[(c + 2) * 64 + o], f1s[w][c + 2], v2);
    v3 = fmaf(s_wva[(c + 3) * 64 + o], f1s[w][c + 3], v3);
  }
  float vb = (v0 + v1) + (v2 + v3);
  // tb[h] = (A2.pts)[h] - MBP[h]
  float tb = 0.f;
#pragma unroll
  for (int i = 0; i < 16; ++i) {
    int c = part * 16 + i;
    tb = fmaf(s_A2[c * 17 + h], f1s[w][c], tb);
  }
  tb += __shfl_xor(tb, 16);
  tb += __shfl_xor(tb, 32);
  tb -= s_MBP[h];

  // online softmax state; prefetch first neighbor
  float m = -__builtin_inff(), l = 0.f;
  float anb = 0.f, axa = 0.f, aya = 0.f, aza = 0.f;
  size_t fi0 = (size_t)(b * NN + idxs[w][0]) * 64 + o;
  float nb_next = f2cap ? f2f32[fi0] : bf2f(f2u16[fi0]);
#pragma unroll 2
  for (int s = 0; s < SS; ++s) {
    float nb = nb_next;
    if (s < SS - 1) {
      size_t fi = (size_t)(b * NN + idxs[w][s + 1]) * 64 + o;
      nb_next = f2cap ? f2f32[fi] : bf2f(f2u16[fi]);
    }
    float gl = 0.f, dp = 0.f;
#pragma unroll
    for (int i = 0; i < 16; ++i) {
      float nbb = __shfl(nb, part * 16 + i);
      gl = fmaf(Gr[i], nbb, gl);
      dp = fmaf(f1r[i], nbb, dp);
    }
    gl += __shfl_xor(gl, 16); dp += __shfl_xor(dp, 16);
    gl += __shfl_xor(gl, 32); dp += __shfl_xor(dp, 32);
    float ssq = fmaxf(f1n2 - 2.f * dp + snb2[w][s], 0.f);
    float fn = sqrtf(ssq);
    float4 xd = xds4[w][s];
    float p5 = p5a * fn;
    p5 = fmaf(p5b, xd.w, p5);
    p5 = fmaf(p5c, xd.x, p5);
    p5 = fmaf(p5d, xd.y, p5);
    p5 = fmaf(p5e, xd.z, p5);
    float t = tb - gl - p5;
    float r = fmaxf(t, 0.f) * w2r;
    r += __shfl_xor(r, 1);
    r += __shfl_xor(r, 2);
    r += __shfl_xor(r, 4);
    r += __shfl_xor(r, 8);   // logit, identical in all lanes
    float mn = fmaxf(m, r);
    float sc = __expf(m - mn);
    float e = __expf(r - mn);
    l = l * sc + e;
    anb = anb * sc + e * nb;
    axa = axa * sc + e * xd.x;
    aya = aya * sc + e * xd.y;
    aza = aza * sc + e * xd.z;
    m = mn;
  }
  float invl = 1.f / l;
  anb *= invl; axa *= invl; aya *= invl; aza *= invl;
  // out = vb + Wvb.anb + Wvx.(axa,aya,aza)
  float o0 = vb, o1 = 0.f, o2 = 0.f, o3 = 0.f;
#pragma unroll
  for (int c = 0; c < 64; c += 4) {
    o0 = fmaf(s_wvb[c * 64 + o],       __shfl(anb, c),     o0);
    o1 = fmaf(s_wvb[(c + 1) * 64 + o], __shfl(anb, c + 1), o1);
    o2 = fmaf(s_wvb[(c + 2) * 64 + o], __shfl(anb, c + 2), o2);
    o3 = fmaf(s_wvb[(c + 3) * 64 + o], __shfl(anb, c + 3), o3);
  }
  float acc = (o0 + o1) + (o2 + o3);
  acc = fmaf(s_wvx[o], axa, acc);
  acc = fmaf(s_wvx[64 + o], aya, acc);
  acc = fmaf(s_wvx[128 + o], aza, acc);
  float res = acc >= 0.f ? acc : 0.1f * acc;   // leaky 0.1
  ws[off_p2n + (size_t)(b * NN + n) * 64 + o] = res;
}

// ---------------- group2: DS-pipe-lean ----------------
__global__ __launch_bounds__(512) void k_group2(
    const void* w_v2, const void* w_pos2, const void* b_pos2,
    u16p probe, float* ws, void* outp, int off_p2n, int off_i11) {
  __shared__ float s_C2[4096];    // [c][o]
  __shared__ float s_wv2[4096];   // [c][o]
  __shared__ float s_wp2t[256];   // [p][o]
  __shared__ float s_bp2[64];
  __shared__ float4 xds4[8][16];
  __shared__ int   idxs[8][16];
  __shared__ float souts[8][64];

  int f32m = detect_f32(probe);
  int tid = threadIdx.x;
  for (int i = tid; i < 4096; i += 512) {
    int c = i >> 6, o = i & 63;
    s_C2[i] = ws[OFF_C2 + i];
    s_wv2[i] = ldi(w_v2, o * 64 + c, f32m);
  }
  if (tid < 256) { int p = tid >> 6, o = tid & 63; s_wp2t[p * 64 + o] = ldi(w_pos2, o * 4 + p, f32m); }
  if (tid < 64) s_bp2[tid] = ldi(b_pos2, tid, f32m);

  int w = tid >> 6, o = tid & 63;
  int g = blockIdx.x * 8 + w;
  int b = g >> 12, n = g & (NN - 1);
  const float* p2t = ws + off_p2n;
  const float* x1f = ws + OFF_XYZ1F + b * 3 * NN;
  const uint16_t* idx11 = (const uint16_t*)(ws + off_i11) + (size_t)(b * NN + n) * SS;

  float p1o = p2t[(size_t)(b * NN + n) * 64 + o];
  float qx = x1f[n], qy = x1f[NN + n], qz = x1f[2 * NN + n];
  if (o < 16) {
    int j = (int)idx11[o];
    idxs[w][o] = j;
    float dx = __fsub_rn(qx, x1f[j]);
    float dy = __fsub_rn(qy, x1f[NN + j]);
    float dz = __fsub_rn(qz, x1f[2 * NN + j]);
    xds4[w][o] = make_float4(dx, dy, dz, sqrtf(dx * dx + dy * dy + dz * dz));
  }
  __syncthreads();

  int part = o >> 4;
  // u[o] = (Wk2^T Wq2).pts  via shfl broadcasts of p1o
  float u0 = 0.f, u1 = 0.f, u2 = 0.f, u3 = 0.f;
#pragma unroll
  for (int c = 0; c < 64; c += 4) {
    u0 = fmaf(s_C2[c * 64 + o],       __shfl(p1o, c),     u0);
    u1 = fmaf(s_C2[(c + 1) * 64 + o], __shfl(p1o, c + 1), u1);
    u2 = fmaf(s_C2[(c + 2) * 64 + o], __shfl(p1o, c + 2), u2);
    u3 = fmaf(s_C2[(c + 3) * 64 + o], __shfl(p1o, c + 3), u3);
  }
  float u = (u0 + u1) + (u2 + u3);
  float w4x = u * s_wp2t[o];
  float w4y = u * s_wp2t[64 + o];
  float w4z = u * s_wp2t[128 + o];
  float w4n = u * s_wp2t[192 + o];
  float ubp = u * s_bp2[o];
#pragma unroll
  for (int msk = 1; msk < 64; msk <<= 1) {
    w4x += __shfl_xor(w4x, msk);
    w4y += __shfl_xor(w4y, msk);
    w4z += __shfl_xor(w4z, msk);
    w4n += __shfl_xor(w4n, msk);
    ubp += __shfl_xor(ubp, msk);
  }
  float u16r[16];
#pragma unroll
  for (int i = 0; i < 16; ++i) u16r[i] = __shfl(u, part * 16 + i);

  float m = -__builtin_inff(), l = 0.f, anb = 0.f;
  float nb_next = p2t[(size_t)(b * NN + idxs[w][0]) * 64 + o];
#pragma unroll 2
  for (int s = 0; s < SS; ++s) {
    float nb = nb_next;
    if (s < SS - 1) nb_next = p2t[(size_t)(b * NN + idxs[w][s + 1]) * 64 + o];
    float tp = 0.f;
#pragma unroll
    for (int i = 0; i < 16; ++i) tp = fmaf(u16r[i], __shfl(nb, part * 16 + i), tp);
    tp += __shfl_xor(tp, 16);
    tp += __shfl_xor(tp, 32);   // full dot, all lanes
    float4 xd = xds4[w][s];
    float logit = tp;
    logit = fmaf(w4x, xd.x, logit);
    logit = fmaf(w4y, xd.y, logit);
    logit = fmaf(w4z, xd.z, logit);
    logit = fmaf(w4n, xd.w, logit);
    logit = (logit + ubp) * 0.125f;
    float mn = fmaxf(m, logit);
    float sc = __expf(m - mn);
    float e = __expf(logit - mn);
    l = l * sc + e;
    anb = anb * sc + e * nb;
    m = mn;
  }
  anb *= 1.f / l;
  float o0 = 0.f, o1 = 0.f, o2 = 0.f, o3 = 0.f;
#pragma unroll
  for (int c = 0; c < 64; c += 4) {
    o0 = fmaf(s_wv2[c * 64 + o],       __shfl(anb, c),     o0);
    o1 = fmaf(s_wv2[(c + 1) * 64 + o], __shfl(anb, c + 1), o1);
    o2 = fmaf(s_wv2[(c + 2) * 64 + o], __shfl(anb, c + 2), o2);
    o3 = fmaf(s_wv2[(c + 3) * 64 + o], __shfl(anb, c + 3), o3);
  }
  float acc = (o0 + o1) + (o2 + o3);
  float res = acc >= 0.f ? acc : 0.1f * acc;
  souts[w][o] = res;
  __syncthreads();   // cross-wave transpose staging
  int c = tid >> 3, nr = tid & 7;
  int n0 = (blockIdx.x * 8) & (NN - 1);
  int b0 = (blockIdx.x * 8) >> 12;
  size_t oi = (size_t)(b0 * 64 + c) * NN + n0 + nr;
  float ov = souts[nr][c];
  if (f32m) ((float*)outp)[oi] = ov;
  else      ((uint16_t*)outp)[oi] = f2bf(ov);
}

extern "C" void kernel_launch(void* const* d_in, const int* in_sizes, int n_in,
                              void* d_out, int out_size, void* d_ws, size_t ws_size,
                              hipStream_t stream) {
  const void* xyz1 = d_in[0];
  const void* feat1 = d_in[1];
  const void* xyz2 = d_in[2];
  const void* feat2 = d_in[3];
  const void* w_q1 = d_in[4];
  const void* w_k1 = d_in[5];
  const void* w_v1 = d_in[6];
  const void* w_mlp1 = d_in[7];
  const void* w_mlp2 = d_in[8];
  const void* w_pos1 = d_in[9];
  const void* b_pos1 = d_in[10];
  const void* w_q2 = d_in[11];
  const void* w_k2 = d_in[12];
  const void* w_v2 = d_in[13];
  const void* w_pos2 = d_in[14];
  const void* b_pos2 = d_in[15];
  u16p probe = (u16p)d_in[1];
  float* ws = (float*)d_ws;

  if (ws_size < WS_MIN_FLOATS * 4ull) return;

  int big = (ws_size >= 2490368ull * 4ull) ? 1 : 0;
  int f2cap   = big;
  int off_p2n = big ? 1179648 : 655360;
  int off_i12 = big ? 2228224 : 1703936;
  int off_i11 = big ? 2359296 : 1835008;

  hipLaunchKernelGGL(k_prep_xyz, dim3(64), dim3(256), 0, stream, xyz1, xyz2, probe, ws);
  hipLaunchKernelGGL(k_transpose, dim3(256), dim3(256), 0, stream, feat2, probe, ws, f2cap);
  hipLaunchKernelGGL(k_knn, dim3(8192), dim3(256), 0, stream, ws, off_i12, off_i11);
  hipLaunchKernelGGL(k_fold, dim3(66), dim3(256), 0, stream,
                     w_q1, w_k1, w_v1, w_mlp1, w_pos1, b_pos1, w_q2, w_k2, probe, ws, f2cap);
  hipLaunchKernelGGL(k_group1, dim3(2048), dim3(512), 0, stream,
                     feat1, w_v1, w_mlp2, probe, ws, off_p2n, off_i12, f2cap);
  hipLaunchKernelGGL(k_group2, dim3(2048), dim3(512), 0, stream,
                     w_v2, w_pos2, b_pos2, probe, ws, d_out, off_p2n, off_i11);
}

// Round 11
// 528.000 us; speedup vs baseline: 3.3011x; 1.0411x over previous
//
#include <hip/hip_runtime.h>
#include <stdint.h>

#define NN 4096
#define SS 16

// fixed ws float offsets
#define OFF_XYZ1F 0          // 4*3*4096 f32
#define OFF_XYZ2F 49152      // 4*3*4096 f32
#define OFF_N1    98304      // 4*4096 f32 (dead after knn -> nb2 of feat2 points)
#define OFF_N2    114688     // 4*4096 f32 (dead after knn -> folds)
#define OFF_F2T   131072     // feat2 transpose [b][n][c]: u16 (compact) or f32 (big)
#define WS_MIN_FLOATS 1966080ull

// fold outputs (dead-after-knn regions, written by k_fold AFTER k_knn)
#define OFF_NB2 98304    // ||feat2[b][:,n]||^2, 16384 floats (over N1)
#define OFF_A2  114688   // (W1Wq - M*Wva)  [c][h] 1024
#define OFF_G   115712   // (M*Wvb)         [c][h] 1024
#define OFF_P5  116736   // [p][h] 80
#define OFF_MBP 116816   // M*bp1 [h] 16
#define OFF_C2  116832   // Wk2^T*Wq2 [c][o] 4096
// AoS candidate arrays (x,y,z,norm) live in the P2N region: written by k_prep,
// consumed by k_knn, then overwritten by k_group1's P2N output (stream-ordered).

typedef const uint16_t* u16p;

__device__ __forceinline__ float bf2f(uint16_t u) {
  return __uint_as_float(((uint32_t)u) << 16);
}
__device__ __forceinline__ uint16_t f2bf(float f) {
  uint32_t x = __float_as_uint(f);
  uint32_t r = (x + 0x7FFFu + ((x >> 16) & 1u)) >> 16;
  return (uint16_t)r;
}
__device__ __forceinline__ float ldi(const void* p, int i, int f32m) {
  return f32m ? ((const float*)p)[i] : bf2f(((const uint16_t*)p)[i]);
}
__device__ __forceinline__ int detect_f32(const uint16_t* probe) {
  int lane = threadIdx.x & 63;
  float a = bf2f(probe[lane]);
  float b = bf2f(probe[lane + 64]);
  int bad = (!(fabsf(a) <= 1e4f)) || (!(fabsf(b) <= 1e4f));
  return __any(bad) ? 1 : 0;
}

// ---------------- prep: SoA xyz + norms + AoS candidate float4s ----------------
__global__ __launch_bounds__(256) void k_prep_xyz(const void* xyz1, const void* xyz2,
                                                  u16p probe, float* ws, int off_aos) {
  int f32m = detect_f32(probe);
  int t = blockIdx.x * 256 + threadIdx.x;
  int b = t >> 12, n = t & (NN - 1);
  int base = b * 3 * NN + n;
  float x1 = ldi(xyz1, base, f32m), y1 = ldi(xyz1, base + NN, f32m), z1 = ldi(xyz1, base + 2 * NN, f32m);
  float x2 = ldi(xyz2, base, f32m), y2 = ldi(xyz2, base + NN, f32m), z2 = ldi(xyz2, base + 2 * NN, f32m);
  float* x1f = ws + OFF_XYZ1F;
  float* x2f = ws + OFF_XYZ2F;
  x1f[base] = x1; x1f[base + NN] = y1; x1f[base + 2 * NN] = z1;
  x2f[base] = x2; x2f[base + NN] = y2; x2f[base + 2 * NN] = z2;
  float n1v = __fadd_rn(__fadd_rn(__fmul_rn(x1, x1), __fmul_rn(y1, y1)), __fmul_rn(z1, z1));
  float n2v = __fadd_rn(__fadd_rn(__fmul_rn(x2, x2), __fmul_rn(y2, y2)), __fmul_rn(z2, z2));
  ws[OFF_N1 + t] = n1v;
  ws[OFF_N2 + t] = n2v;
  // AoS: one dwordx4 per candidate in knn
  ((float4*)(ws + off_aos))[t]          = make_float4(x2, y2, z2, n2v);  // which=0 cands
  ((float4*)(ws + off_aos + 65536))[t]  = make_float4(x1, y1, z1, n1v);  // which=1 cands
}

// ---------------- transpose feat2 ----------------
__global__ __launch_bounds__(256) void k_transpose(const void* feat2, u16p probe,
                                                   float* ws, int f2cap) {
  __shared__ float tile[64][65];
  int f32m = detect_f32(probe);
  int b = blockIdx.x >> 6;
  int n0 = (blockIdx.x & 63) * 64;
  int tx = threadIdx.x & 63, ty = threadIdx.x >> 6;
#pragma unroll
  for (int i = 0; i < 16; ++i) {
    int c = i * 4 + ty;
    tile[c][tx] = ldi(feat2, (b * 64 + c) * NN + n0 + tx, f32m);
  }
  __syncthreads();
#pragma unroll
  for (int i = 0; i < 16; ++i) {
    int nl = i * 4 + ty;
    size_t di = (size_t)(b * NN + n0 + nl) * 64 + tx;
    float v = tile[tx][nl];
    if (f2cap) ((float*)(ws + OFF_F2T))[di] = v;
    else       ((uint16_t*)(ws + OFF_F2T))[di] = f2bf(v);
  }
}

// ---------------- KNN: wave-per-query, AoS loads, subsample-threshold ----------------
#define KCAP 320
__device__ __forceinline__ float knn_dist4(float4 cc, float qx, float qy, float qz, float q2) {
  float cross = __fadd_rn(__fadd_rn(__fmul_rn(qx, cc.x), __fmul_rn(qy, cc.y)),
                          __fmul_rn(qz, cc.z));
  return __fsub_rn(__fadd_rn(q2, cc.w), __fmul_rn(2.0f, cross));
}

__global__ __launch_bounds__(256) void k_knn(float* ws, int off_i12, int off_i11, int off_aos) {
  __shared__ float sd[4][KCAP];
  __shared__ int   si[4][KCAP];
  __shared__ int   eqbuf[4][16];

  int tid = threadIdx.x;
  int wv = tid >> 6, lane = tid & 63;
  int q = blockIdx.x * 4 + wv;
  int which = q >> 14;
  int b = (q >> 12) & 3;
  int n = q & (NN - 1);

  const float4* cnd = (const float4*)(ws + off_aos + (which ? 65536 : 0)) + b * NN;
  const float* qp = ws + OFF_XYZ1F + b * 3 * NN;
  float qx = qp[n], qy = qp[NN + n], qz = qp[2 * NN + n];
  float q2 = ws[OFF_N1 + b * NN + n];
  const float INF = __builtin_inff();

  // ---- phase 1: per-lane min over first 1024 (subsample) ----
  float mn = INF;
#pragma unroll 4
  for (int i = 0; i < 16; ++i) {
    float d = knn_dist4(cnd[i * 64 + lane], qx, qy, qz, q2);
    mn = fminf(mn, d);
  }
  // tau0 = 16th smallest of the 64 lane minima (16 distinct candidates <= tau0
  // => true 16th <= tau0). Full 64-lane bitonic sort, then take lane 15.
  float v = mn;
#pragma unroll
  for (int k = 2; k <= 64; k <<= 1) {
#pragma unroll
    for (int j = k >> 1; j > 0; j >>= 1) {
      float other = __shfl_xor(v, j);
      bool up = ((lane & k) == 0);
      bool lower = ((lane & j) == 0);
      v = (up == lower) ? fminf(v, other) : fmaxf(v, other);
    }
  }
  float tau0 = __shfl(v, 15);

  // ---- phase 2: full scan, survivors d <= tau0, j-ascending ----
  unsigned long long below = (1ull << lane) - 1ull;
  int c = 0;
#pragma unroll 2
  for (int i = 0; i < 64; ++i) {
    int j = i * 64 + lane;
    float d = knn_dist4(cnd[j], qx, qy, qz, q2);
    bool sel = (d <= tau0);
    unsigned long long msk = __ballot(sel);
    int pos = c + __popcll(msk & below);
    if (sel && pos < KCAP) { sd[wv][pos] = d; si[wv][pos] = j; }
    c += __popcll(msk);
  }
  if (c > KCAP) c = KCAP;   // ~e^-50 event; clamp for safety
  __syncthreads();

  // ---- phase 3: exact tau = 16th smallest among survivors ----
  float ch[5];
#pragma unroll
  for (int t = 0; t < 5; ++t) ch[t] = INF;
#pragma unroll
  for (int t = 0; t < 5; ++t) {
    int p = t * 64 + lane;
    float x = (p < c) ? sd[wv][p] : INF;
#pragma unroll
    for (int u = 0; u < 5; ++u) {
      float lo = fminf(ch[u], x);
      x = fmaxf(ch[u], x);
      ch[u] = lo;
    }
  }
  float tau = 0.f;
  {
    float h = ch[0];
#pragma unroll 1
    for (int r = 0; r < 16; ++r) {
      float m = h;
#pragma unroll
      for (int msk = 1; msk < 64; msk <<= 1) m = fminf(m, __shfl_xor(m, msk));
      if (r == 15) tau = m;
      unsigned long long win = __ballot(h == m);
      int winner = __ffsll(win) - 1;
      if (lane == winner) {
        ch[0] = ch[1]; ch[1] = ch[2]; ch[2] = ch[3]; ch[3] = ch[4]; ch[4] = INF;
        h = ch[0];
      }
    }
  }

  // ---- phase 4: {d<tau} + earliest equals ----
  uint16_t* outp = (uint16_t*)(ws + (which ? off_i11 : off_i12)) + (size_t)(b * NN + n) * SS;
  int c1 = 0, eqc = 0;
#pragma unroll
  for (int t = 0; t < 5; ++t) {
    int p = t * 64 + lane;
    bool act = (p < c);
    float d = act ? sd[wv][p] : INF;
    int j = act ? si[wv][p] : 0;
    bool lt = act && (d < tau);
    bool eq = act && (d == tau);
    unsigned long long mlt = __ballot(lt);
    unsigned long long meq = __ballot(eq);
    int pl = __popcll(mlt & below);
    if (lt) outp[c1 + pl] = (uint16_t)j;
    int pe = __popcll(meq & below);
    if (eq && (eqc + pe) < 16) eqbuf[wv][eqc + pe] = j;
    c1 += __popcll(mlt);
    eqc += __popcll(meq);
  }
  __syncthreads();
  int need = 16 - c1;
  if (lane < need) outp[c1 + lane] = (uint16_t)eqbuf[wv][lane];
}

// ---------------- fold: algebraic precomputes + feat2 norms (66 blocks) ----------------
__global__ __launch_bounds__(256) void k_fold(
    const void* w_q1, const void* w_k1, const void* w_v1, const void* w_mlp1,
    const void* w_pos1, const void* b_pos1, const void* w_q2, const void* w_k2,
    u16p probe, float* ws, int f2cap) {
  int f32m = detect_f32(probe);
  int tid = threadIdx.x;

  if (blockIdx.x >= 2) {
    int p = (blockIdx.x - 2) * 256 + tid;
    const float* f2f32 = (const float*)(ws + OFF_F2T);
    const uint16_t* f2u16 = (const uint16_t*)(ws + OFF_F2T);
    size_t row = (size_t)p * 64;
    float acc = 0.f;
#pragma unroll 8
    for (int c = 0; c < 64; ++c) {
      float v = f2cap ? f2f32[row + c] : bf2f(f2u16[row + c]);
      acc = fmaf(v, v, acc);
    }
    ws[OFF_NB2 + p] = acc;
    return;
  }

  __shared__ float lA[4096];
  __shared__ float lB[2048];   // lW1[0:1024], lM[1024:2048]
  if (blockIdx.x == 1) {
    __shared__ float lQ[4096];
    for (int i = tid; i < 4096; i += 256) { lA[i] = ldi(w_k2, i, f32m); lQ[i] = ldi(w_q2, i, f32m); }
    __syncthreads();
    for (int i = tid; i < 4096; i += 256) {
      int c = i >> 6, o = i & 63;
      float a0 = 0.f, a1 = 0.f, a2 = 0.f, a3 = 0.f;
      for (int a = 0; a < 64; a += 4) {
        a0 = fmaf(lA[a * 64 + o],       lQ[a * 64 + c],       a0);
        a1 = fmaf(lA[(a + 1) * 64 + o], lQ[(a + 1) * 64 + c], a1);
        a2 = fmaf(lA[(a + 2) * 64 + o], lQ[(a + 2) * 64 + c], a2);
        a3 = fmaf(lA[(a + 3) * 64 + o], lQ[(a + 3) * 64 + c], a3);
      }
      ws[OFF_C2 + i] = (a0 + a1) + (a2 + a3);
    }
    return;
  }

  float* lW1 = lB;
  float* lM  = lB + 1024;
  for (int i = tid; i < 1024; i += 256) lW1[i] = ldi(w_mlp1, i, f32m);   // [h][m]
  for (int i = tid; i < 4096; i += 256) lA[i] = ldi(w_k1, i, f32m);      // [m][o]
  __syncthreads();
  for (int i = tid; i < 1024; i += 256) {       // M[h][o] = W1.Wk
    int hh = i >> 6, o = i & 63;
    float acc = 0.f;
    for (int m = 0; m < 64; ++m) acc = fmaf(lW1[hh * 64 + m], lA[m * 64 + o], acc);
    lM[i] = acc;
  }
  __syncthreads();
  float a2acc[4];
  for (int i = tid; i < 4096; i += 256) lA[i] = ldi(w_q1, i, f32m);      // [o][c]
  __syncthreads();
  for (int k = 0; k < 4; ++k) {
    int i = tid + k * 256;
    int c = i >> 4, hh = i & 15;
    float acc = 0.f;
    for (int o = 0; o < 64; ++o) acc = fmaf(lW1[hh * 64 + o], lA[o * 64 + c], acc);
    a2acc[k] = acc;
  }
  __syncthreads();
  for (int i = tid; i < 4096; i += 256) { int o = i >> 6, c = i & 63; lA[o * 64 + c] = ldi(w_v1, o * 131 + c, f32m); }
  __syncthreads();
  for (int k = 0; k < 4; ++k) {
    int i = tid + k * 256;
    int c = i >> 4, hh = i & 15;
    float acc = 0.f;
    for (int o = 0; o < 64; ++o) acc = fmaf(lM[hh * 64 + o], lA[o * 64 + c], acc);
    ws[OFF_A2 + i] = a2acc[k] - acc;
  }
  __syncthreads();
  for (int i = tid; i < 4096; i += 256) { int o = i >> 6, c = i & 63; lA[o * 64 + c] = ldi(w_v1, o * 131 + 64 + c, f32m); }
  __syncthreads();
  for (int i = tid; i < 1024; i += 256) {       // G[c][h] = M*Wvb
    int c = i >> 4, hh = i & 15;
    float acc = 0.f;
    for (int o = 0; o < 64; ++o) acc = fmaf(lM[hh * 64 + o], lA[o * 64 + c], acc);
    ws[OFF_G + i] = acc;
  }
  if (tid < 16) {
    int hh = tid;
    float p0 = 0.f, p1 = 0.f, p2 = 0.f, p3 = 0.f, p4 = 0.f, pb = 0.f;
    for (int o = 0; o < 64; ++o) {
      float m = lM[hh * 64 + o];
      p0 = fmaf(m, ldi(w_pos1, o * 5 + 0, f32m), p0);
      p1 = fmaf(m, ldi(w_pos1, o * 5 + 1, f32m), p1);
      p2 = fmaf(m, ldi(w_v1, o * 131 + 128, f32m) + ldi(w_pos1, o * 5 + 2, f32m), p2);
      p3 = fmaf(m, ldi(w_v1, o * 131 + 129, f32m) + ldi(w_pos1, o * 5 + 3, f32m), p3);
      p4 = fmaf(m, ldi(w_v1, o * 131 + 130, f32m) + ldi(w_pos1, o * 5 + 4, f32m), p4);
      pb = fmaf(m, ldi(b_pos1, o, f32m), pb);
    }
    ws[OFF_P5 + hh] = p0; ws[OFF_P5 + 16 + hh] = p1; ws[OFF_P5 + 32 + hh] = p2;
    ws[OFF_P5 + 48 + hh] = p3; ws[OFF_P5 + 64 + hh] = p4;
    ws[OFF_MBP + hh] = pb;
  }
}

// ---------------- group1: DS-pipe-lean (reg-hoisted invariants) ----------------
__global__ __launch_bounds__(512) void k_group1(
    const void* feat1, const void* w_v1, const void* w_mlp2,
    u16p probe, float* ws, int off_p2n, int off_i12, int f2cap) {
  __shared__ float s_wva[4096];    // [c][o]
  __shared__ float s_wvb[4096];    // [c][o]
  __shared__ float s_wvx[192];
  __shared__ float s_A2[1088];     // [c*17+h] padded
  __shared__ float s_G[1088];      // [c*17+h] padded
  __shared__ float s_P5[80];
  __shared__ float s_MBP[16];
  __shared__ float s_w2[16];
  __shared__ float f1s[8][64];
  __shared__ float4 xds4[8][16];   // per s: (dx,dy,dz,norm)
  __shared__ float snb2[8][16];
  __shared__ int   idxs[8][16];

  int f32m = detect_f32(probe);
  int tid = threadIdx.x;
  for (int i = tid; i < 4096; i += 512) {
    int c = i >> 6, o = i & 63;
    s_wva[i] = ldi(w_v1, o * 131 + c, f32m);
    s_wvb[i] = ldi(w_v1, o * 131 + 64 + c, f32m);
  }
  if (tid < 192) { int j = tid >> 6, o = tid & 63; s_wvx[tid] = ldi(w_v1, o * 131 + 128 + j, f32m); }
  for (int i = tid; i < 1024; i += 512) {
    int c = i >> 4, h = i & 15;
    s_A2[c * 17 + h] = ws[OFF_A2 + i];
    s_G[c * 17 + h] = ws[OFF_G + i];
  }
  if (tid < 80) s_P5[tid] = ws[OFF_P5 + tid];
  if (tid < 16) { s_MBP[tid] = ws[OFF_MBP + tid]; s_w2[tid] = ldi(w_mlp2, tid, f32m); }

  int w = tid >> 6, o = tid & 63;
  int g = blockIdx.x * 8 + w;
  int b = g >> 12, n = g & (NN - 1);
  const float* x1f = ws + OFF_XYZ1F + b * 3 * NN;
  const float* x2f = ws + OFF_XYZ2F + b * 3 * NN;
  const uint16_t* idx12 = (const uint16_t*)(ws + off_i12) + (size_t)(b * NN + n) * SS;
  const float* f2f32 = (const float*)(ws + OFF_F2T);
  const uint16_t* f2u16 = (const uint16_t*)(ws + OFF_F2T);

  float f1o = ldi(feat1, (b * 64 + o) * NN + n, f32m);
  f1s[w][o] = f1o;
  float qx = x1f[n], qy = x1f[NN + n], qz = x1f[2 * NN + n];
  if (o < 16) {
    int j = (int)idx12[o];
    idxs[w][o] = j;
    float dx = __fsub_rn(qx, x2f[j]);
    float dy = __fsub_rn(qy, x2f[NN + j]);
    float dz = __fsub_rn(qz, x2f[2 * NN + j]);
    xds4[w][o] = make_float4(dx, dy, dz, sqrtf(dx * dx + dy * dy + dz * dz));
    snb2[w][o] = ws[OFF_NB2 + b * NN + j];
  }
  __syncthreads();   // only block barrier; below: regs/shfl/read-only LDS

  int h = o & 15, part = o >> 4;
  // ---- hoist loop-invariant LDS values into registers ----
  float Gr[16], f1r[16];
#pragma unroll
  for (int i = 0; i < 16; ++i) {
    int c = part * 16 + i;
    Gr[i] = s_G[c * 17 + h];
    f1r[i] = f1s[w][c];
  }
  float p5a = s_P5[h], p5b = s_P5[16 + h], p5c = s_P5[32 + h], p5d = s_P5[48 + h], p5e = s_P5[64 + h];
  float w2r = s_w2[h];

  // f1n2 = ||f1||^2
  float f1n2 = f1o * f1o;
#pragma unroll
  for (int msk = 1; msk < 64; msk <<= 1) f1n2 += __shfl_xor(f1n2, msk);
  // vb[o] = Wva.pts
  float v0 = 0.f, v1 = 0.f, v2 = 0.f, v3 = 0.f;
#pragma unroll
  for (int c = 0; c < 64; c += 4) {
    v0 = fmaf(s_wva[c * 64 + o],       f1s[w][c],     v0);
    v1 = fmaf(s_wva[(c + 1) * 64 + o], f1s[w][c + 1], v1);
    v2 = fmaf(s_wva[(c + 2) * 64 + o], f1s[w][c + 2], v2);
    v3 = fmaf(s_wva[(c + 3) * 64 + o], f1s[w][c + 3], v3);
  }
  float vb = (v0 + v1) + (v2 + v3);
  // tb[h] = (A2.pts)[h] - MBP[h]
  float tb = 0.f;
#pragma unroll
  for (int i = 0; i < 16; ++i) {
    int c = part * 16 + i;
    tb = fmaf(s_A2[c * 17 + h], f1s[w][c], tb);
  }
  tb += __shfl_xor(tb, 16);
  tb += __shfl_xor(tb, 32);
  tb -= s_MBP[h];

  // online softmax; prefetch first neighbor
  float m = -__builtin_inff(), l = 0.f;
  float anb = 0.f, axa = 0.f, aya = 0.f, aza = 0.f;
  size_t fi0 = (size_t)(b * NN + idxs[w][0]) * 64 + o;
  float nb_next = f2cap ? f2f32[fi0] : bf2f(f2u16[fi0]);
#pragma unroll 2
  for (int s = 0; s < SS; ++s) {
    float nb = nb_next;
    if (s < SS - 1) {
      size_t fi = (size_t)(b * NN + idxs[w][s + 1]) * 64 + o;
      nb_next = f2cap ? f2f32[fi] : bf2f(f2u16[fi]);
    }
    float gl = 0.f, dp = 0.f;
#pragma unroll
    for (int i = 0; i < 16; ++i) {
      float nbb = __shfl(nb, part * 16 + i);
      gl = fmaf(Gr[i], nbb, gl);
      dp = fmaf(f1r[i], nbb, dp);
    }
    gl += __shfl_xor(gl, 16); dp += __shfl_xor(dp, 16);
    gl += __shfl_xor(gl, 32); dp += __shfl_xor(dp, 32);
    float ssq = fmaxf(f1n2 - 2.f * dp + snb2[w][s], 0.f);
    float fn = sqrtf(ssq);
    float4 xd = xds4[w][s];
    float p5 = p5a * fn;
    p5 = fmaf(p5b, xd.w, p5);
    p5 = fmaf(p5c, xd.x, p5);
    p5 = fmaf(p5d, xd.y, p5);
    p5 = fmaf(p5e, xd.z, p5);
    float t = tb - gl - p5;
    float r = fmaxf(t, 0.f) * w2r;
    r += __shfl_xor(r, 1);
    r += __shfl_xor(r, 2);
    r += __shfl_xor(r, 4);
    r += __shfl_xor(r, 8);   // logit, identical in all lanes
    float mn = fmaxf(m, r);
    float sc = __expf(m - mn);
    float e = __expf(r - mn);
    l = l * sc + e;
    anb = anb * sc + e * nb;
    axa = axa * sc + e * xd.x;
    aya = aya * sc + e * xd.y;
    aza = aza * sc + e * xd.z;
    m = mn;
  }
  float invl = 1.f / l;
  anb *= invl; axa *= invl; aya *= invl; aza *= invl;
  // out = vb + Wvb.anb + Wvx.(axa,aya,aza)
  float o0 = vb, o1 = 0.f, o2 = 0.f, o3 = 0.f;
#pragma unroll
  for (int c = 0; c < 64; c += 4) {
    o0 = fmaf(s_wvb[c * 64 + o],       __shfl(anb, c),     o0);
    o1 = fmaf(s_wvb[(c + 1) * 64 + o], __shfl(anb, c + 1), o1);
    o2 = fmaf(s_wvb[(c + 2) * 64 + o], __shfl(anb, c + 2), o2);
    o3 = fmaf(s_wvb[(c + 3) * 64 + o], __shfl(anb, c + 3), o3);
  }
  float acc = (o0 + o1) + (o2 + o3);
  acc = fmaf(s_wvx[o], axa, acc);
  acc = fmaf(s_wvx[64 + o], aya, acc);
  acc = fmaf(s_wvx[128 + o], aza, acc);
  float res = acc >= 0.f ? acc : 0.1f * acc;   // leaky 0.1
  ws[off_p2n + (size_t)(b * NN + n) * 64 + o] = res;
}

// ---------------- group2: DS-pipe-lean ----------------
__global__ __launch_bounds__(512) void k_group2(
    const void* w_v2, const void* w_pos2, const void* b_pos2,
    u16p probe, float* ws, void* outp, int off_p2n, int off_i11) {
  __shared__ float s_C2[4096];    // [c][o]
  __shared__ float s_wv2[4096];   // [c][o]
  __shared__ float s_wp2t[256];   // [p][o]
  __shared__ float s_bp2[64];
  __shared__ float4 xds4[8][16];
  __shared__ int   idxs[8][16];
  __shared__ float souts[8][64];

  int f32m = detect_f32(probe);
  int tid = threadIdx.x;
  for (int i = tid; i < 4096; i += 512) {
    int c = i >> 6, o = i & 63;
    s_C2[i] = ws[OFF_C2 + i];
    s_wv2[i] = ldi(w_v2, o * 64 + c, f32m);
  }
  if (tid < 256) { int p = tid >> 6, o = tid & 63; s_wp2t[p * 64 + o] = ldi(w_pos2, o * 4 + p, f32m); }
  if (tid < 64) s_bp2[tid] = ldi(b_pos2, tid, f32m);

  int w = tid >> 6, o = tid & 63;
  int g = blockIdx.x * 8 + w;
  int b = g >> 12, n = g & (NN - 1);
  const float* p2t = ws + off_p2n;
  const float* x1f = ws + OFF_XYZ1F + b * 3 * NN;
  const uint16_t* idx11 = (const uint16_t*)(ws + off_i11) + (size_t)(b * NN + n) * SS;

  float p1o = p2t[(size_t)(b * NN + n) * 64 + o];
  float qx = x1f[n], qy = x1f[NN + n], qz = x1f[2 * NN + n];
  if (o < 16) {
    int j = (int)idx11[o];
    idxs[w][o] = j;
    float dx = __fsub_rn(qx, x1f[j]);
    float dy = __fsub_rn(qy, x1f[NN + j]);
    float dz = __fsub_rn(qz, x1f[2 * NN + j]);
    xds4[w][o] = make_float4(dx, dy, dz, sqrtf(dx * dx + dy * dy + dz * dz));
  }
  __syncthreads();

  int part = o >> 4;
  // u[o] = (Wk2^T Wq2).pts  via shfl broadcasts of p1o
  float u0 = 0.f, u1 = 0.f, u2 = 0.f, u3 = 0.f;
#pragma unroll
  for (int c = 0; c < 64; c += 4) {
    u0 = fmaf(s_C2[c * 64 + o],       __shfl(p1o, c),     u0);
    u1 = fmaf(s_C2[(c + 1) * 64 + o], __shfl(p1o, c + 1), u1);
    u2 = fmaf(s_C2[(c + 2) * 64 + o], __shfl(p1o, c + 2), u2);
    u3 = fmaf(s_C2[(c + 3) * 64 + o], __shfl(p1o, c + 3), u3);
  }
  float u = (u0 + u1) + (u2 + u3);
  float w4x = u * s_wp2t[o];
  float w4y = u * s_wp2t[64 + o];
  float w4z = u * s_wp2t[128 + o];
  float w4n = u * s_wp2t[192 + o];
  float ubp = u * s_bp2[o];
#pragma unroll
  for (int msk = 1; msk < 64; msk <<= 1) {
    w4x += __shfl_xor(w4x, msk);
    w4y += __shfl_xor(w4y, msk);
    w4z += __shfl_xor(w4z, msk);
    w4n += __shfl_xor(w4n, msk);
    ubp += __shfl_xor(ubp, msk);
  }
  float u16r[16];
#pragma unroll
  for (int i = 0; i < 16; ++i) u16r[i] = __shfl(u, part * 16 + i);

  float m = -__builtin_inff(), l = 0.f, anb = 0.f;
  float nb_next = p2t[(size_t)(b * NN + idxs[w][0]) * 64 + o];
#pragma unroll 2
  for (int s = 0; s < SS; ++s) {
    float nb = nb_next;
    if (s < SS - 1) nb_next = p2t[(size_t)(b * NN + idxs[w][s + 1]) * 64 + o];
    float tp = 0.f;
#pragma unroll
    for (int i = 0; i < 16; ++i) tp = fmaf(u16r[i], __shfl(nb, part * 16 + i), tp);
    tp += __shfl_xor(tp, 16);
    tp += __shfl_xor(tp, 32);   // full dot, all lanes
    float4 xd = xds4[w][s];
    float logit = tp;
    logit = fmaf(w4x, xd.x, logit);
    logit = fmaf(w4y, xd.y, logit);
    logit = fmaf(w4z, xd.z, logit);
    logit = fmaf(w4n, xd.w, logit);
    logit = (logit + ubp) * 0.125f;
    float mn = fmaxf(m, logit);
    float sc = __expf(m - mn);
    float e = __expf(logit - mn);
    l = l * sc + e;
    anb = anb * sc + e * nb;
    m = mn;
  }
  anb *= 1.f / l;
  float o0 = 0.f, o1 = 0.f, o2 = 0.f, o3 = 0.f;
#pragma unroll
  for (int c = 0; c < 64; c += 4) {
    o0 = fmaf(s_wv2[c * 64 + o],       __shfl(anb, c),     o0);
    o1 = fmaf(s_wv2[(c + 1) * 64 + o], __shfl(anb, c + 1), o1);
    o2 = fmaf(s_wv2[(c + 2) * 64 + o], __shfl(anb, c + 2), o2);
    o3 = fmaf(s_wv2[(c + 3) * 64 + o], __shfl(anb, c + 3), o3);
  }
  float acc = (o0 + o1) + (o2 + o3);
  float res = acc >= 0.f ? acc : 0.1f * acc;
  souts[w][o] = res;
  __syncthreads();   // cross-wave transpose staging
  int c = tid >> 3, nr = tid & 7;
  int n0 = (blockIdx.x * 8) & (NN - 1);
  int b0 = (blockIdx.x * 8) >> 12;
  size_t oi = (size_t)(b0 * 64 + c) * NN + n0 + nr;
  float ov = souts[nr][c];
  if (f32m) ((float*)outp)[oi] = ov;
  else      ((uint16_t*)outp)[oi] = f2bf(ov);
}

extern "C" void kernel_launch(void* const* d_in, const int* in_sizes, int n_in,
                              void* d_out, int out_size, void* d_ws, size_t ws_size,
                              hipStream_t stream) {
  const void* xyz1 = d_in[0];
  const void* feat1 = d_in[1];
  const void* xyz2 = d_in[2];
  const void* feat2 = d_in[3];
  const void* w_q1 = d_in[4];
  const void* w_k1 = d_in[5];
  const void* w_v1 = d_in[6];
  const void* w_mlp1 = d_in[7];
  const void* w_mlp2 = d_in[8];
  const void* w_pos1 = d_in[9];
  const void* b_pos1 = d_in[10];
  const void* w_q2 = d_in[11];
  const void* w_k2 = d_in[12];
  const void* w_v2 = d_in[13];
  const void* w_pos2 = d_in[14];
  const void* b_pos2 = d_in[15];
  u16p probe = (u16p)d_in[1];
  float* ws = (float*)d_ws;

  if (ws_size < WS_MIN_FLOATS * 4ull) return;

  int big = (ws_size >= 2490368ull * 4ull) ? 1 : 0;
  int f2cap   = big;
  int off_p2n = big ? 1179648 : 655360;
  int off_i12 = big ? 2228224 : 1703936;
  int off_i11 = big ? 2359296 : 1835008;
  int off_aos = off_p2n;   // AoS candidates live in (pre-group1) P2N region

  hipLaunchKernelGGL(k_prep_xyz, dim3(64), dim3(256), 0, stream, xyz1, xyz2, probe, ws, off_aos);
  hipLaunchKernelGGL(k_transpose, dim3(256), dim3(256), 0, stream, feat2, probe, ws, f2cap);
  hipLaunchKernelGGL(k_knn, dim3(8192), dim3(256), 0, stream, ws, off_i12, off_i11, off_aos);
  hipLaunchKernelGGL(k_fold, dim3(66), dim3(256), 0, stream,
                     w_q1, w_k1, w_v1, w_mlp1, w_pos1, b_pos1, w_q2, w_k2, probe, ws, f2cap);
  hipLaunchKernelGGL(k_group1, dim3(2048), dim3(512), 0, stream,
                     feat1, w_v1, w_mlp2, probe, ws, off_p2n, off_i12, f2cap);
  hipLaunchKernelGGL(k_group2, dim3(2048), dim3(512), 0, stream,
                     w_v2, w_pos2, b_pos2, probe, ws, d_out, off_p2n, off_i11);
}

// Round 12
// 500.624 us; speedup vs baseline: 3.4817x; 1.0547x over previous
//
#include <hip/hip_runtime.h>
#include <stdint.h>

#define NN 4096
#define SS 16

// fixed ws float offsets
#define OFF_XYZ1F 0          // 4*3*4096 f32
#define OFF_XYZ2F 49152      // 4*3*4096 f32
#define OFF_N1    98304      // 4*4096 f32 (dead after knn -> nb2 of feat2 points)
#define OFF_N2    114688     // 4*4096 f32 (dead after knn -> folds)
#define OFF_F2T   131072     // feat2 transpose [b][n][c]: u16 (compact) or f32 (big)
#define WS_MIN_FLOATS 1966080ull

// fold outputs (dead-after-knn regions, written by k_fold AFTER k_knn)
#define OFF_NB2 98304    // ||feat2[b][:,n]||^2, 16384 floats (over N1)
#define OFF_A2  114688   // (W1Wq - M*Wva)  [c][h] 1024
#define OFF_G   115712   // (M*Wvb)         [c][h] 1024
#define OFF_P5  116736   // [p][h] 80
#define OFF_MBP 116816   // M*bp1 [h] 16
#define OFF_C2  116832   // Wk2^T*Wq2 [c][o] 4096
// AoS candidate arrays (x,y,z,norm) live in the P2N region: written by k_prep,
// consumed by k_knn, then overwritten by k_group1's P2N output (stream-ordered).

typedef const uint16_t* u16p;

__device__ __forceinline__ float bf2f(uint16_t u) {
  return __uint_as_float(((uint32_t)u) << 16);
}
__device__ __forceinline__ uint16_t f2bf(float f) {
  uint32_t x = __float_as_uint(f);
  uint32_t r = (x + 0x7FFFu + ((x >> 16) & 1u)) >> 16;
  return (uint16_t)r;
}
__device__ __forceinline__ float ldi(const void* p, int i, int f32m) {
  return f32m ? ((const float*)p)[i] : bf2f(((const uint16_t*)p)[i]);
}
__device__ __forceinline__ int detect_f32(const uint16_t* probe) {
  int lane = threadIdx.x & 63;
  float a = bf2f(probe[lane]);
  float b = bf2f(probe[lane + 64]);
  int bad = (!(fabsf(a) <= 1e4f)) || (!(fabsf(b) <= 1e4f));
  return __any(bad) ? 1 : 0;
}

// ---------------- prep: SoA xyz + norms + AoS candidate float4s ----------------
__global__ __launch_bounds__(256) void k_prep_xyz(const void* xyz1, const void* xyz2,
                                                  u16p probe, float* ws, int off_aos) {
  int f32m = detect_f32(probe);
  int t = blockIdx.x * 256 + threadIdx.x;
  int b = t >> 12, n = t & (NN - 1);
  int base = b * 3 * NN + n;
  float x1 = ldi(xyz1, base, f32m), y1 = ldi(xyz1, base + NN, f32m), z1 = ldi(xyz1, base + 2 * NN, f32m);
  float x2 = ldi(xyz2, base, f32m), y2 = ldi(xyz2, base + NN, f32m), z2 = ldi(xyz2, base + 2 * NN, f32m);
  float* x1f = ws + OFF_XYZ1F;
  float* x2f = ws + OFF_XYZ2F;
  x1f[base] = x1; x1f[base + NN] = y1; x1f[base + 2 * NN] = z1;
  x2f[base] = x2; x2f[base + NN] = y2; x2f[base + 2 * NN] = z2;
  float n1v = __fadd_rn(__fadd_rn(__fmul_rn(x1, x1), __fmul_rn(y1, y1)), __fmul_rn(z1, z1));
  float n2v = __fadd_rn(__fadd_rn(__fmul_rn(x2, x2), __fmul_rn(y2, y2)), __fmul_rn(z2, z2));
  ws[OFF_N1 + t] = n1v;
  ws[OFF_N2 + t] = n2v;
  ((float4*)(ws + off_aos))[t]          = make_float4(x2, y2, z2, n2v);  // which=0 cands
  ((float4*)(ws + off_aos + 65536))[t]  = make_float4(x1, y1, z1, n1v);  // which=1 cands
}

// ---------------- transpose feat2 ----------------
__global__ __launch_bounds__(256) void k_transpose(const void* feat2, u16p probe,
                                                   float* ws, int f2cap) {
  __shared__ float tile[64][65];
  int f32m = detect_f32(probe);
  int b = blockIdx.x >> 6;
  int n0 = (blockIdx.x & 63) * 64;
  int tx = threadIdx.x & 63, ty = threadIdx.x >> 6;
#pragma unroll
  for (int i = 0; i < 16; ++i) {
    int c = i * 4 + ty;
    tile[c][tx] = ldi(feat2, (b * 64 + c) * NN + n0 + tx, f32m);
  }
  __syncthreads();
#pragma unroll
  for (int i = 0; i < 16; ++i) {
    int nl = i * 4 + ty;
    size_t di = (size_t)(b * NN + n0 + nl) * 64 + tx;
    float v = tile[tx][nl];
    if (f2cap) ((float*)(ws + OFF_F2T))[di] = v;
    else       ((uint16_t*)(ws + OFF_F2T))[di] = f2bf(v);
  }
}

// ---------------- KNN: wave-per-query, AoS loads, subsample-threshold ----------------
#define KCAP 320
__device__ __forceinline__ float knn_dist4(float4 cc, float qx, float qy, float qz, float q2) {
  float cross = __fadd_rn(__fadd_rn(__fmul_rn(qx, cc.x), __fmul_rn(qy, cc.y)),
                          __fmul_rn(qz, cc.z));
  return __fsub_rn(__fadd_rn(q2, cc.w), __fmul_rn(2.0f, cross));
}

__global__ __launch_bounds__(256) void k_knn(float* ws, int off_i12, int off_i11, int off_aos) {
  __shared__ float sd[4][KCAP];
  __shared__ int   si[4][KCAP];
  __shared__ int   eqbuf[4][16];

  int tid = threadIdx.x;
  int wv = tid >> 6, lane = tid & 63;
  int q = blockIdx.x * 4 + wv;
  int which = q >> 14;
  int b = (q >> 12) & 3;
  int n = q & (NN - 1);

  const float4* cnd = (const float4*)(ws + off_aos + (which ? 65536 : 0)) + b * NN;
  const float* qp = ws + OFF_XYZ1F + b * 3 * NN;
  float qx = qp[n], qy = qp[NN + n], qz = qp[2 * NN + n];
  float q2 = ws[OFF_N1 + b * NN + n];
  const float INF = __builtin_inff();

  float mn = INF;
#pragma unroll 4
  for (int i = 0; i < 16; ++i) {
    float d = knn_dist4(cnd[i * 64 + lane], qx, qy, qz, q2);
    mn = fminf(mn, d);
  }
  // tau0 = 16th smallest of 64 lane minima via full bitonic sort, take lane 15
  float v = mn;
#pragma unroll
  for (int k = 2; k <= 64; k <<= 1) {
#pragma unroll
    for (int j = k >> 1; j > 0; j >>= 1) {
      float other = __shfl_xor(v, j);
      bool up = ((lane & k) == 0);
      bool lower = ((lane & j) == 0);
      v = (up == lower) ? fminf(v, other) : fmaxf(v, other);
    }
  }
  float tau0 = __shfl(v, 15);

  unsigned long long below = (1ull << lane) - 1ull;
  int c = 0;
#pragma unroll 2
  for (int i = 0; i < 64; ++i) {
    int j = i * 64 + lane;
    float d = knn_dist4(cnd[j], qx, qy, qz, q2);
    bool sel = (d <= tau0);
    unsigned long long msk = __ballot(sel);
    int pos = c + __popcll(msk & below);
    if (sel && pos < KCAP) { sd[wv][pos] = d; si[wv][pos] = j; }
    c += __popcll(msk);
  }
  if (c > KCAP) c = KCAP;   // ~e^-50 event; clamp for safety
  __syncthreads();

  float ch[5];
#pragma unroll
  for (int t = 0; t < 5; ++t) ch[t] = INF;
#pragma unroll
  for (int t = 0; t < 5; ++t) {
    int p = t * 64 + lane;
    float x = (p < c) ? sd[wv][p] : INF;
#pragma unroll
    for (int u = 0; u < 5; ++u) {
      float lo = fminf(ch[u], x);
      x = fmaxf(ch[u], x);
      ch[u] = lo;
    }
  }
  float tau = 0.f;
  {
    float h = ch[0];
#pragma unroll 1
    for (int r = 0; r < 16; ++r) {
      float m = h;
#pragma unroll
      for (int msk = 1; msk < 64; msk <<= 1) m = fminf(m, __shfl_xor(m, msk));
      if (r == 15) tau = m;
      unsigned long long win = __ballot(h == m);
      int winner = __ffsll(win) - 1;
      if (lane == winner) {
        ch[0] = ch[1]; ch[1] = ch[2]; ch[2] = ch[3]; ch[3] = ch[4]; ch[4] = INF;
        h = ch[0];
      }
    }
  }

  uint16_t* outp = (uint16_t*)(ws + (which ? off_i11 : off_i12)) + (size_t)(b * NN + n) * SS;
  int c1 = 0, eqc = 0;
#pragma unroll
  for (int t = 0; t < 5; ++t) {
    int p = t * 64 + lane;
    bool act = (p < c);
    float d = act ? sd[wv][p] : INF;
    int j = act ? si[wv][p] : 0;
    bool lt = act && (d < tau);
    bool eq = act && (d == tau);
    unsigned long long mlt = __ballot(lt);
    unsigned long long meq = __ballot(eq);
    int pl = __popcll(mlt & below);
    if (lt) outp[c1 + pl] = (uint16_t)j;
    int pe = __popcll(meq & below);
    if (eq && (eqc + pe) < 16) eqbuf[wv][eqc + pe] = j;
    c1 += __popcll(mlt);
    eqc += __popcll(meq);
  }
  __syncthreads();
  int need = 16 - c1;
  if (lane < need) outp[c1 + lane] = (uint16_t)eqbuf[wv][lane];
}

// ---------------- fold: algebraic precomputes + feat2 norms (66 blocks) ----------------
__global__ __launch_bounds__(256) void k_fold(
    const void* w_q1, const void* w_k1, const void* w_v1, const void* w_mlp1,
    const void* w_pos1, const void* b_pos1, const void* w_q2, const void* w_k2,
    u16p probe, float* ws, int f2cap) {
  int f32m = detect_f32(probe);
  int tid = threadIdx.x;

  if (blockIdx.x >= 2) {
    int p = (blockIdx.x - 2) * 256 + tid;
    const float* f2f32 = (const float*)(ws + OFF_F2T);
    const uint16_t* f2u16 = (const uint16_t*)(ws + OFF_F2T);
    size_t row = (size_t)p * 64;
    float acc = 0.f;
#pragma unroll 8
    for (int c = 0; c < 64; ++c) {
      float v = f2cap ? f2f32[row + c] : bf2f(f2u16[row + c]);
      acc = fmaf(v, v, acc);
    }
    ws[OFF_NB2 + p] = acc;
    return;
  }

  __shared__ float lA[4096];
  __shared__ float lB[2048];   // lW1[0:1024], lM[1024:2048]
  if (blockIdx.x == 1) {
    __shared__ float lQ[4096];
    for (int i = tid; i < 4096; i += 256) { lA[i] = ldi(w_k2, i, f32m); lQ[i] = ldi(w_q2, i, f32m); }
    __syncthreads();
    for (int i = tid; i < 4096; i += 256) {
      int c = i >> 6, o = i & 63;
      float a0 = 0.f, a1 = 0.f, a2 = 0.f, a3 = 0.f;
      for (int a = 0; a < 64; a += 4) {
        a0 = fmaf(lA[a * 64 + o],       lQ[a * 64 + c],       a0);
        a1 = fmaf(lA[(a + 1) * 64 + o], lQ[(a + 1) * 64 + c], a1);
        a2 = fmaf(lA[(a + 2) * 64 + o], lQ[(a + 2) * 64 + c], a2);
        a3 = fmaf(lA[(a + 3) * 64 + o], lQ[(a + 3) * 64 + c], a3);
      }
      ws[OFF_C2 + i] = (a0 + a1) + (a2 + a3);
    }
    return;
  }

  float* lW1 = lB;
  float* lM  = lB + 1024;
  for (int i = tid; i < 1024; i += 256) lW1[i] = ldi(w_mlp1, i, f32m);   // [h][m]
  for (int i = tid; i < 4096; i += 256) lA[i] = ldi(w_k1, i, f32m);      // [m][o]
  __syncthreads();
  for (int i = tid; i < 1024; i += 256) {       // M[h][o] = W1.Wk
    int hh = i >> 6, o = i & 63;
    float acc = 0.f;
    for (int m = 0; m < 64; ++m) acc = fmaf(lW1[hh * 64 + m], lA[m * 64 + o], acc);
    lM[i] = acc;
  }
  __syncthreads();
  float a2acc[4];
  for (int i = tid; i < 4096; i += 256) lA[i] = ldi(w_q1, i, f32m);      // [o][c]
  __syncthreads();
  for (int k = 0; k < 4; ++k) {
    int i = tid + k * 256;
    int c = i >> 4, hh = i & 15;
    float acc = 0.f;
    for (int o = 0; o < 64; ++o) acc = fmaf(lW1[hh * 64 + o], lA[o * 64 + c], acc);
    a2acc[k] = acc;
  }
  __syncthreads();
  for (int i = tid; i < 4096; i += 256) { int o = i >> 6, c = i & 63; lA[o * 64 + c] = ldi(w_v1, o * 131 + c, f32m); }
  __syncthreads();
  for (int k = 0; k < 4; ++k) {
    int i = tid + k * 256;
    int c = i >> 4, hh = i & 15;
    float acc = 0.f;
    for (int o = 0; o < 64; ++o) acc = fmaf(lM[hh * 64 + o], lA[o * 64 + c], acc);
    ws[OFF_A2 + i] = a2acc[k] - acc;
  }
  __syncthreads();
  for (int i = tid; i < 4096; i += 256) { int o = i >> 6, c = i & 63; lA[o * 64 + c] = ldi(w_v1, o * 131 + 64 + c, f32m); }
  __syncthreads();
  for (int i = tid; i < 1024; i += 256) {       // G[c][h] = M*Wvb
    int c = i >> 4, hh = i & 15;
    float acc = 0.f;
    for (int o = 0; o < 64; ++o) acc = fmaf(lM[hh * 64 + o], lA[o * 64 + c], acc);
    ws[OFF_G + i] = acc;
  }
  if (tid < 16) {
    int hh = tid;
    float p0 = 0.f, p1 = 0.f, p2 = 0.f, p3 = 0.f, p4 = 0.f, pb = 0.f;
    for (int o = 0; o < 64; ++o) {
      float m = lM[hh * 64 + o];
      p0 = fmaf(m, ldi(w_pos1, o * 5 + 0, f32m), p0);
      p1 = fmaf(m, ldi(w_pos1, o * 5 + 1, f32m), p1);
      p2 = fmaf(m, ldi(w_v1, o * 131 + 128, f32m) + ldi(w_pos1, o * 5 + 2, f32m), p2);
      p3 = fmaf(m, ldi(w_v1, o * 131 + 129, f32m) + ldi(w_pos1, o * 5 + 3, f32m), p3);
      p4 = fmaf(m, ldi(w_v1, o * 131 + 130, f32m) + ldi(w_pos1, o * 5 + 4, f32m), p4);
      pb = fmaf(m, ldi(b_pos1, o, f32m), pb);
    }
    ws[OFF_P5 + hh] = p0; ws[OFF_P5 + 16 + hh] = p1; ws[OFF_P5 + 32 + hh] = p2;
    ws[OFF_P5 + 48 + hh] = p3; ws[OFF_P5 + 64 + hh] = p4;
    ws[OFF_MBP + hh] = pb;
  }
}

// ---------------- group1: per-lane slice loads (no per-s broadcasts) ----------------
// launch_bounds (512,2): 2 BLOCKS/CU (CUDA semantics, r8 post-mortem) => 128-VGPR cap.
__global__ __launch_bounds__(512, 2) void k_group1(
    const void* feat1, const void* w_v1, const void* w_mlp2,
    u16p probe, float* ws, int off_p2n, int off_i12, int f2cap) {
  __shared__ float s_wva[4096];    // [c][o]
  __shared__ float s_wvb[4096];    // [c][o]
  __shared__ float s_wvx[192];
  __shared__ float s_A2[1088];     // [c*17+h] padded
  __shared__ float s_G[1088];      // [c*17+h] padded
  __shared__ float s_P5[80];
  __shared__ float s_MBP[16];
  __shared__ float s_w2[16];
  __shared__ float f1s[8][64];
  __shared__ float4 xds4[8][16];   // per s: (dx,dy,dz,norm)
  __shared__ float snb2[8][16];
  __shared__ int   idxs[8][16];

  int f32m = detect_f32(probe);
  int tid = threadIdx.x;
  for (int i = tid; i < 4096; i += 512) {
    int c = i >> 6, o = i & 63;
    s_wva[i] = ldi(w_v1, o * 131 + c, f32m);
    s_wvb[i] = ldi(w_v1, o * 131 + 64 + c, f32m);
  }
  if (tid < 192) { int j = tid >> 6, o = tid & 63; s_wvx[tid] = ldi(w_v1, o * 131 + 128 + j, f32m); }
  for (int i = tid; i < 1024; i += 512) {
    int c = i >> 4, h = i & 15;
    s_A2[c * 17 + h] = ws[OFF_A2 + i];
    s_G[c * 17 + h] = ws[OFF_G + i];
  }
  if (tid < 80) s_P5[tid] = ws[OFF_P5 + tid];
  if (tid < 16) { s_MBP[tid] = ws[OFF_MBP + tid]; s_w2[tid] = ldi(w_mlp2, tid, f32m); }

  int w = tid >> 6, o = tid & 63;
  int g = blockIdx.x * 8 + w;
  int b = g >> 12, n = g & (NN - 1);
  const float* x1f = ws + OFF_XYZ1F + b * 3 * NN;
  const float* x2f = ws + OFF_XYZ2F + b * 3 * NN;
  const uint16_t* idx12 = (const uint16_t*)(ws + off_i12) + (size_t)(b * NN + n) * SS;
  const float* f2f32 = (const float*)(ws + OFF_F2T);
  const uint16_t* f2u16 = (const uint16_t*)(ws + OFF_F2T);

  float f1o = ldi(feat1, (b * 64 + o) * NN + n, f32m);
  f1s[w][o] = f1o;
  float qx = x1f[n], qy = x1f[NN + n], qz = x1f[2 * NN + n];
  if (o < 16) {
    int j = (int)idx12[o];
    idxs[w][o] = j;
    float dx = __fsub_rn(qx, x2f[j]);
    float dy = __fsub_rn(qy, x2f[NN + j]);
    float dz = __fsub_rn(qz, x2f[2 * NN + j]);
    xds4[w][o] = make_float4(dx, dy, dz, sqrtf(dx * dx + dy * dy + dz * dz));
    snb2[w][o] = ws[OFF_NB2 + b * NN + j];
  }
  __syncthreads();   // only block barrier; below: regs/shfl/read-only LDS

  int h = o & 15, part = o >> 4;
  float Gr[16], f1r[16];
#pragma unroll
  for (int i = 0; i < 16; ++i) {
    int c = part * 16 + i;
    Gr[i] = s_G[c * 17 + h];
    f1r[i] = f1s[w][c];
  }
  float p5a = s_P5[h], p5b = s_P5[16 + h], p5c = s_P5[32 + h], p5d = s_P5[48 + h], p5e = s_P5[64 + h];
  float w2r = s_w2[h];

  float f1n2 = f1o * f1o;
#pragma unroll
  for (int msk = 1; msk < 64; msk <<= 1) f1n2 += __shfl_xor(f1n2, msk);
  float v0 = 0.f, v1 = 0.f, v2 = 0.f, v3 = 0.f;
#pragma unroll
  for (int c = 0; c < 64; c += 4) {
    v0 = fmaf(s_wva[c * 64 + o],       f1s[w][c],     v0);
    v1 = fmaf(s_wva[(c + 1) * 64 + o], f1s[w][c + 1], v1);
    v2 = fmaf(s_wva[(c + 2) * 64 + o], f1s[w][c + 2], v2);
    v3 = fmaf(s_wva[(c + 3) * 64 + o], f1s[w][c + 3], v3);
  }
  float vb = (v0 + v1) + (v2 + v3);
  float tb = 0.f;
#pragma unroll
  for (int i = 0; i < 16; ++i) {
    int c = part * 16 + i;
    tb = fmaf(s_A2[c * 17 + h], f1s[w][c], tb);
  }
  tb += __shfl_xor(tb, 16);
  tb += __shfl_xor(tb, 32);
  tb -= s_MBP[h];

  float m = -__builtin_inff(), l = 0.f;
  float anb = 0.f, axa = 0.f, aya = 0.f, aza = 0.f;
  int jcur = idxs[w][0];
#pragma unroll 1
  for (int s = 0; s < SS; ++s) {
    size_t row = (size_t)(b * NN + jcur) * 64;
    float nb, nbsl[16];
    if (f2cap) {
      const float4* r4 = (const float4*)(f2f32 + row) + part * 4;
      float4 A0 = r4[0], A1 = r4[1], A2v = r4[2], A3 = r4[3];
      nb = f2f32[row + o];
      nbsl[0] = A0.x; nbsl[1] = A0.y; nbsl[2] = A0.z; nbsl[3] = A0.w;
      nbsl[4] = A1.x; nbsl[5] = A1.y; nbsl[6] = A1.z; nbsl[7] = A1.w;
      nbsl[8] = A2v.x; nbsl[9] = A2v.y; nbsl[10] = A2v.z; nbsl[11] = A2v.w;
      nbsl[12] = A3.x; nbsl[13] = A3.y; nbsl[14] = A3.z; nbsl[15] = A3.w;
    } else {
      const uint4* r4 = (const uint4*)(f2u16 + row) + part * 2;
      uint4 U0 = r4[0], U1 = r4[1];
      nb = bf2f(f2u16[row + o]);
      nbsl[0] = bf2f((uint16_t)(U0.x & 0xFFFF)); nbsl[1] = bf2f((uint16_t)(U0.x >> 16));
      nbsl[2] = bf2f((uint16_t)(U0.y & 0xFFFF)); nbsl[3] = bf2f((uint16_t)(U0.y >> 16));
      nbsl[4] = bf2f((uint16_t)(U0.z & 0xFFFF)); nbsl[5] = bf2f((uint16_t)(U0.z >> 16));
      nbsl[6] = bf2f((uint16_t)(U0.w & 0xFFFF)); nbsl[7] = bf2f((uint16_t)(U0.w >> 16));
      nbsl[8] = bf2f((uint16_t)(U1.x & 0xFFFF)); nbsl[9] = bf2f((uint16_t)(U1.x >> 16));
      nbsl[10] = bf2f((uint16_t)(U1.y & 0xFFFF)); nbsl[11] = bf2f((uint16_t)(U1.y >> 16));
      nbsl[12] = bf2f((uint16_t)(U1.z & 0xFFFF)); nbsl[13] = bf2f((uint16_t)(U1.z >> 16));
      nbsl[14] = bf2f((uint16_t)(U1.w & 0xFFFF)); nbsl[15] = bf2f((uint16_t)(U1.w >> 16));
    }
    if (s < SS - 1) jcur = idxs[w][s + 1];
    float gl = 0.f, dp = 0.f;
#pragma unroll
    for (int i = 0; i < 16; ++i) {
      gl = fmaf(Gr[i], nbsl[i], gl);
      dp = fmaf(f1r[i], nbsl[i], dp);
    }
    gl += __shfl_xor(gl, 16); dp += __shfl_xor(dp, 16);
    gl += __shfl_xor(gl, 32); dp += __shfl_xor(dp, 32);
    float ssq = fmaxf(f1n2 - 2.f * dp + snb2[w][s], 0.f);
    float fn = sqrtf(ssq);
    float4 xd = xds4[w][s];
    float p5 = p5a * fn;
    p5 = fmaf(p5b, xd.w, p5);
    p5 = fmaf(p5c, xd.x, p5);
    p5 = fmaf(p5d, xd.y, p5);
    p5 = fmaf(p5e, xd.z, p5);
    float t = tb - gl - p5;
    float r = fmaxf(t, 0.f) * w2r;
    r += __shfl_xor(r, 1);
    r += __shfl_xor(r, 2);
    r += __shfl_xor(r, 4);
    r += __shfl_xor(r, 8);   // logit, identical in all lanes
    float mn = fmaxf(m, r);
    float sc = __expf(m - mn);
    float e = __expf(r - mn);
    l = l * sc + e;
    anb = anb * sc + e * nb;
    axa = axa * sc + e * xd.x;
    aya = aya * sc + e * xd.y;
    aza = aza * sc + e * xd.z;
    m = mn;
  }
  float invl = 1.f / l;
  anb *= invl; axa *= invl; aya *= invl; aza *= invl;
  float o0 = vb, o1 = 0.f, o2 = 0.f, o3 = 0.f;
#pragma unroll
  for (int c = 0; c < 64; c += 4) {
    o0 = fmaf(s_wvb[c * 64 + o],       __shfl(anb, c),     o0);
    o1 = fmaf(s_wvb[(c + 1) * 64 + o], __shfl(anb, c + 1), o1);
    o2 = fmaf(s_wvb[(c + 2) * 64 + o], __shfl(anb, c + 2), o2);
    o3 = fmaf(s_wvb[(c + 3) * 64 + o], __shfl(anb, c + 3), o3);
  }
  float acc = (o0 + o1) + (o2 + o3);
  acc = fmaf(s_wvx[o], axa, acc);
  acc = fmaf(s_wvx[64 + o], aya, acc);
  acc = fmaf(s_wvx[128 + o], aza, acc);
  float res = acc >= 0.f ? acc : 0.1f * acc;   // leaky 0.1
  ws[off_p2n + (size_t)(b * NN + n) * 64 + o] = res;
}

// ---------------- group2: per-lane slice loads ----------------
__global__ __launch_bounds__(512, 2) void k_group2(
    const void* w_v2, const void* w_pos2, const void* b_pos2,
    u16p probe, float* ws, void* outp, int off_p2n, int off_i11) {
  __shared__ float s_C2[4096];    // [c][o]
  __shared__ float s_wv2[4096];   // [c][o]
  __shared__ float s_wp2t[256];   // [p][o]
  __shared__ float s_bp2[64];
  __shared__ float4 xds4[8][16];
  __shared__ int   idxs[8][16];
  __shared__ float souts[8][64];

  int f32m = detect_f32(probe);
  int tid = threadIdx.x;
  for (int i = tid; i < 4096; i += 512) {
    int c = i >> 6, o = i & 63;
    s_C2[i] = ws[OFF_C2 + i];
    s_wv2[i] = ldi(w_v2, o * 64 + c, f32m);
  }
  if (tid < 256) { int p = tid >> 6, o = tid & 63; s_wp2t[p * 64 + o] = ldi(w_pos2, o * 4 + p, f32m); }
  if (tid < 64) s_bp2[tid] = ldi(b_pos2, tid, f32m);

  int w = tid >> 6, o = tid & 63;
  int g = blockIdx.x * 8 + w;
  int b = g >> 12, n = g & (NN - 1);
  const float* p2t = ws + off_p2n;
  const float* x1f = ws + OFF_XYZ1F + b * 3 * NN;
  const uint16_t* idx11 = (const uint16_t*)(ws + off_i11) + (size_t)(b * NN + n) * SS;

  float p1o = p2t[(size_t)(b * NN + n) * 64 + o];
  float qx = x1f[n], qy = x1f[NN + n], qz = x1f[2 * NN + n];
  if (o < 16) {
    int j = (int)idx11[o];
    idxs[w][o] = j;
    float dx = __fsub_rn(qx, x1f[j]);
    float dy = __fsub_rn(qy, x1f[NN + j]);
    float dz = __fsub_rn(qz, x1f[2 * NN + j]);
    xds4[w][o] = make_float4(dx, dy, dz, sqrtf(dx * dx + dy * dy + dz * dz));
  }
  __syncthreads();

  int part = o >> 4;
  // u[o] = (Wk2^T Wq2).pts  via shfl broadcasts of p1o (once per wave)
  float u0 = 0.f, u1 = 0.f, u2 = 0.f, u3 = 0.f;
#pragma unroll
  for (int c = 0; c < 64; c += 4) {
    u0 = fmaf(s_C2[c * 64 + o],       __shfl(p1o, c),     u0);
    u1 = fmaf(s_C2[(c + 1) * 64 + o], __shfl(p1o, c + 1), u1);
    u2 = fmaf(s_C2[(c + 2) * 64 + o], __shfl(p1o, c + 2), u2);
    u3 = fmaf(s_C2[(c + 3) * 64 + o], __shfl(p1o, c + 3), u3);
  }
  float u = (u0 + u1) + (u2 + u3);
  float w4x = u * s_wp2t[o];
  float w4y = u * s_wp2t[64 + o];
  float w4z = u * s_wp2t[128 + o];
  float w4n = u * s_wp2t[192 + o];
  float ubp = u * s_bp2[o];
#pragma unroll
  for (int msk = 1; msk < 64; msk <<= 1) {
    w4x += __shfl_xor(w4x, msk);
    w4y += __shfl_xor(w4y, msk);
    w4z += __shfl_xor(w4z, msk);
    w4n += __shfl_xor(w4n, msk);
    ubp += __shfl_xor(ubp, msk);
  }
  float u16r[16];
#pragma unroll
  for (int i = 0; i < 16; ++i) u16r[i] = __shfl(u, part * 16 + i);

  float m = -__builtin_inff(), l = 0.f, anb = 0.f;
  int jcur = idxs[w][0];
#pragma unroll 1
  for (int s = 0; s < SS; ++s) {
    size_t row = (size_t)(b * NN + jcur) * 64;
    const float4* r4 = (const float4*)(p2t + row) + part * 4;
    float4 A0 = r4[0], A1 = r4[1], A2v = r4[2], A3 = r4[3];
    float nb = p2t[row + o];
    if (s < SS - 1) jcur = idxs[w][s + 1];
    float tp = 0.f;
    tp = fmaf(u16r[0], A0.x, tp);  tp = fmaf(u16r[1], A0.y, tp);
    tp = fmaf(u16r[2], A0.z, tp);  tp = fmaf(u16r[3], A0.w, tp);
    tp = fmaf(u16r[4], A1.x, tp);  tp = fmaf(u16r[5], A1.y, tp);
    tp = fmaf(u16r[6], A1.z, tp);  tp = fmaf(u16r[7], A1.w, tp);
    tp = fmaf(u16r[8], A2v.x, tp); tp = fmaf(u16r[9], A2v.y, tp);
    tp = fmaf(u16r[10], A2v.z, tp); tp = fmaf(u16r[11], A2v.w, tp);
    tp = fmaf(u16r[12], A3.x, tp); tp = fmaf(u16r[13], A3.y, tp);
    tp = fmaf(u16r[14], A3.z, tp); tp = fmaf(u16r[15], A3.w, tp);
    tp += __shfl_xor(tp, 16);
    tp += __shfl_xor(tp, 32);   // full dot, all lanes
    float4 xd = xds4[w][s];
    float logit = tp;
    logit = fmaf(w4x, xd.x, logit);
    logit = fmaf(w4y, xd.y, logit);
    logit = fmaf(w4z, xd.z, logit);
    logit = fmaf(w4n, xd.w, logit);
    logit = (logit + ubp) * 0.125f;
    float mn = fmaxf(m, logit);
    float sc = __expf(m - mn);
    float e = __expf(logit - mn);
    l = l * sc + e;
    anb = anb * sc + e * nb;
    m = mn;
  }
  anb *= 1.f / l;
  float o0 = 0.f, o1 = 0.f, o2 = 0.f, o3 = 0.f;
#pragma unroll
  for (int c = 0; c < 64; c += 4) {
    o0 = fmaf(s_wv2[c * 64 + o],       __shfl(anb, c),     o0);
    o1 = fmaf(s_wv2[(c + 1) * 64 + o], __shfl(anb, c + 1), o1);
    o2 = fmaf(s_wv2[(c + 2) * 64 + o], __shfl(anb, c + 2), o2);
    o3 = fmaf(s_wv2[(c + 3) * 64 + o], __shfl(anb, c + 3), o3);
  }
  float acc = (o0 + o1) + (o2 + o3);
  float res = acc >= 0.f ? acc : 0.1f * acc;
  souts[w][o] = res;
  __syncthreads();   // cross-wave transpose staging
  int c = tid >> 3, nr = tid & 7;
  int n0 = (blockIdx.x * 8) & (NN - 1);
  int b0 = (blockIdx.x * 8) >> 12;
  size_t oi = (size_t)(b0 * 64 + c) * NN + n0 + nr;
  float ov = souts[nr][c];
  if (f32m) ((float*)outp)[oi] = ov;
  else      ((uint16_t*)outp)[oi] = f2bf(ov);
}

extern "C" void kernel_launch(void* const* d_in, const int* in_sizes, int n_in,
                              void* d_out, int out_size, void* d_ws, size_t ws_size,
                              hipStream_t stream) {
  const void* xyz1 = d_in[0];
  const void* feat1 = d_in[1];
  const void* xyz2 = d_in[2];
  const void* feat2 = d_in[3];
  const void* w_q1 = d_in[4];
  const void* w_k1 = d_in[5];
  const void* w_v1 = d_in[6];
  const void* w_mlp1 = d_in[7];
  const void* w_mlp2 = d_in[8];
  const void* w_pos1 = d_in[9];
  const void* b_pos1 = d_in[10];
  const void* w_q2 = d_in[11];
  const void* w_k2 = d_in[12];
  const void* w_v2 = d_in[13];
  const void* w_pos2 = d_in[14];
  const void* b_pos2 = d_in[15];
  u16p probe = (u16p)d_in[1];
  float* ws = (float*)d_ws;

  if (ws_size < WS_MIN_FLOATS * 4ull) return;

  int big = (ws_size >= 2490368ull * 4ull) ? 1 : 0;
  int f2cap   = big;
  int off_p2n = big ? 1179648 : 655360;
  int off_i12 = big ? 2228224 : 1703936;
  int off_i11 = big ? 2359296 : 1835008;
  int off_aos = off_p2n;   // AoS candidates live in (pre-group1) P2N region

  hipLaunchKernelGGL(k_prep_xyz, dim3(64), dim3(256), 0, stream, xyz1, xyz2, probe, ws, off_aos);
  hipLaunchKernelGGL(k_transpose, dim3(256), dim3(256), 0, stream, feat2, probe, ws, f2cap);
  hipLaunchKernelGGL(k_knn, dim3(8192), dim3(256), 0, stream, ws, off_i12, off_i11, off_aos);
  hipLaunchKernelGGL(k_fold, dim3(66), dim3(256), 0, stream,
                     w_q1, w_k1, w_v1, w_mlp1, w_pos1, b_pos1, w_q2, w_k2, probe, ws, f2cap);
  hipLaunchKernelGGL(k_group1, dim3(2048), dim3(512), 0, stream,
                     feat1, w_v1, w_mlp2, probe, ws, off_p2n, off_i12, f2cap);
  hipLaunchKernelGGL(k_group2, dim3(2048), dim3(512), 0, stream,
                     w_v2, w_pos2, b_pos2, probe, ws, d_out, off_p2n, off_i11);
}